// Round 2
// baseline (3226.502 us; speedup 1.0000x reference)
//
#include <hip/hip_runtime.h>
#include <math.h>

#define BB 8
#define HH 64
#define WW 64
#define CIN 192
#define INNER 384
#define LL 4096          // HH*WW
#define NSTATE 32
#define PDIM 64
#define NHK 6            // INNER/PDIM
#define NHEADS 12        // 2*NHK
#define HID 768
#define CPROJ 70         // 2*NSTATE + NHK

// workspace layout (bytes)
#define WS_XL    0u                   // (B,L,384) 50331648 B ; later reused for z, then h1
#define WS_XC    50331648u            // (B,L,384) 50331648 B
#define WS_BCDT  100663296u           // (B,L,2,70) 18350080 B
#define WS_DTV   119013376u           // (B,L,12) 1572864 B
#define WS_DAV   120586240u           // (B,L,12) 1572864 B
#define WS_YSUM  122159104u           // (B,L,384) 50331648 B
#define WS_REQ   172490752u

__device__ __forceinline__ float silu_f(float x) { return x / (1.f + __expf(-x)); }

// ---------------------------------------------------------------------------
// Generic GEMM: C[m,n] = sum_k A[m,k] * Wt[n,k]   (A: MxK row-major, Wt: NxK row-major)
// EPI: 0 = none; 1 = silu(acc+bias); 2 = acc+bias+res; 3 = acc+res
// BLK 64x64x16, 256 threads, 4x4 micro-tile.
// ---------------------------------------------------------------------------
template<int EPI>
__global__ __launch_bounds__(256)
void gemm_nt(const float* __restrict__ A, const float* __restrict__ Wt,
             const float* __restrict__ bias, const float* __restrict__ res,
             float* __restrict__ C, int M, int N, int Kd)
{
    __shared__ __align__(16) float As[16][72];
    __shared__ __align__(16) float Bs[16][72];
    const int tid = threadIdx.x;
    const int m0 = blockIdx.x * 64;
    const int n0 = blockIdx.y * 64;
    const int tx = tid & 15;
    const int ty = tid >> 4;
    const int lr = tid >> 2;          // 0..63 tile row
    const int lc = (tid & 3) << 2;    // 0,4,8,12 k offset
    float acc[4][4] = {{0.f,0.f,0.f,0.f},{0.f,0.f,0.f,0.f},{0.f,0.f,0.f,0.f},{0.f,0.f,0.f,0.f}};
    const float* Aptr = A  + (size_t)(m0 + lr) * Kd + lc;
    const float* Bptr = Wt + (size_t)(n0 + lr) * Kd + lc;
    for (int k0 = 0; k0 < Kd; k0 += 16) {
        float4 av = *(const float4*)(Aptr + k0);
        float4 bv = *(const float4*)(Bptr + k0);
        __syncthreads();
        As[lc+0][lr]=av.x; As[lc+1][lr]=av.y; As[lc+2][lr]=av.z; As[lc+3][lr]=av.w;
        Bs[lc+0][lr]=bv.x; Bs[lc+1][lr]=bv.y; Bs[lc+2][lr]=bv.z; Bs[lc+3][lr]=bv.w;
        __syncthreads();
        #pragma unroll
        for (int kk = 0; kk < 16; ++kk) {
            float a0[4], b0[4];
            #pragma unroll
            for (int i = 0; i < 4; ++i) a0[i] = As[kk][ty*4+i];
            #pragma unroll
            for (int j = 0; j < 4; ++j) b0[j] = Bs[kk][tx*4+j];
            #pragma unroll
            for (int i = 0; i < 4; ++i)
                #pragma unroll
                for (int j = 0; j < 4; ++j)
                    acc[i][j] = fmaf(a0[i], b0[j], acc[i][j]);
        }
    }
    #pragma unroll
    for (int i = 0; i < 4; ++i) {
        const int m = m0 + ty*4 + i;
        #pragma unroll
        for (int j = 0; j < 4; ++j) {
            const int n = n0 + tx*4 + j;
            float v = acc[i][j];
            if (EPI == 1) v = silu_f(v + bias[n]);
            else if (EPI == 2) v = v + bias[n] + res[(size_t)m * N + n];
            else if (EPI == 3) v = v + res[(size_t)m * N + n];
            C[(size_t)m * N + n] = v;
        }
    }
}

// ---------------------------------------------------------------------------
// Depthwise 3x3 conv (SAME, groups=INNER) + bias + SiLU.
// Input: xl (B,L,384). Output xc (B,L,384).
// ---------------------------------------------------------------------------
__global__ __launch_bounds__(256)
void conv_dw_kernel(const float* __restrict__ xl, const float* __restrict__ cw,
                    const float* __restrict__ cb, float* __restrict__ xc)
{
    const size_t e = (size_t)blockIdx.x * 256 + threadIdx.x;
    if (e >= (size_t)BB * LL * INNER) return;
    const int d = (int)(e % INNER);
    const size_t m = e / INNER;
    const int b = (int)(m >> 12);
    const int r = (int)(m & 4095);
    const int i = r >> 6;
    const int j = r & 63;
    const float* wd = cw + d * 9;
    float s = 0.f;
    #pragma unroll
    for (int di = 0; di < 3; ++di) {
        const int ii = i + di - 1;
        if (ii < 0 || ii >= HH) continue;
        #pragma unroll
        for (int dj = 0; dj < 3; ++dj) {
            const int jj = j + dj - 1;
            if (jj < 0 || jj >= WW) continue;
            s = fmaf(xl[(((size_t)b << 12) + (size_t)(ii * 64 + jj)) * INNER + d], wd[di*3+dj], s);
        }
    }
    s += cb[d];
    xc[e] = silu_f(s);
}

// ---------------------------------------------------------------------------
// BCdt[b,l,k,c] = sum_d xc[b,pos_k(l),d] * xpw[k,c,d]     (c < 70)
// pos_0(l)=l (row scan), pos_1(l)=(l%64)*64 + l/64 (column scan).
// ---------------------------------------------------------------------------
__global__ __launch_bounds__(256)
void proj_bcdt_kernel(const float* __restrict__ xc, const float* __restrict__ xpw,
                      float* __restrict__ BCdt)
{
    __shared__ __align__(16) float Xs[32][INNER];
    const int lt = blockIdx.x;   // 0..127
    const int k  = blockIdx.y;   // 0..1
    const int b  = blockIdx.z;   // 0..7
    const int l0 = lt * 32;
    for (int idx = threadIdx.x; idx < 32 * INNER; idx += 256) {
        const int llx = idx / INNER;
        const int d = idx - llx * INNER;
        const int l = l0 + llx;
        const int pos = (k == 0) ? l : ((l & 63) * 64 + (l >> 6));
        Xs[llx][d] = xc[((size_t)b * LL + pos) * INNER + d];
    }
    __syncthreads();
    const float* Wk = xpw + (size_t)k * CPROJ * INNER;
    for (int idx = threadIdx.x; idx < 32 * CPROJ; idx += 256) {
        const int llx = idx / CPROJ;
        const int c = idx - llx * CPROJ;
        const float4* w4 = (const float4*)(Wk + (size_t)c * INNER);
        const float4* x4 = (const float4*)(&Xs[llx][0]);
        float s = 0.f;
        #pragma unroll 4
        for (int d4 = 0; d4 < INNER/4; ++d4) {
            const float4 wv = w4[d4];
            const float4 xv = x4[d4];
            s = fmaf(wv.x, xv.x, s);
            s = fmaf(wv.y, xv.y, s);
            s = fmaf(wv.z, xv.z, s);
            s = fmaf(wv.w, xv.w, s);
        }
        BCdt[(((size_t)b * LL + (size_t)(l0 + llx)) * 2 + k) * CPROJ + c] = s;
    }
}

// ---------------------------------------------------------------------------
// dtv = softplus(dt_raw + dt_bias[h]);  dav = exp(-exp(A_logs[h]) * dtv)
// ---------------------------------------------------------------------------
__global__ __launch_bounds__(256)
void dtda_kernel(const float* __restrict__ BCdt, const float* __restrict__ dt_bias,
                 const float* __restrict__ A_logs,
                 float* __restrict__ dtv, float* __restrict__ dav)
{
    const int e = blockIdx.x * 256 + threadIdx.x;
    if (e >= BB * LL * NHEADS) return;
    const int h = e % NHEADS;
    const size_t bl = (size_t)(e / NHEADS);
    const float dtraw = BCdt[(bl * 2 + (h / NHK)) * CPROJ + 2*NSTATE + (h % NHK)];
    const float xx = dtraw + dt_bias[h];
    const float sp = (xx > 20.f) ? xx : log1pf(expf(xx));
    dtv[e] = sp;
    dav[e] = expf(-expf(A_logs[h]) * sp);
}

// ---------------------------------------------------------------------------
// Sequential selective scan. One block per (b, head). 256 thr = 64 p x 4 n-groups.
// Both directions accumulate (atomicAdd) into ysum at ROW-major position pos,
// so no separate y1 buffer and no transpose pass. ysum pre-zeroed; exactly two
// commutative float adds per element -> deterministic.
// ---------------------------------------------------------------------------
__global__ __launch_bounds__(256)
void scan_kernel(const float* __restrict__ xc, const float* __restrict__ BCdt,
                 const float* __restrict__ dtv, const float* __restrict__ dav,
                 const float* __restrict__ Ds, const float* __restrict__ init_states,
                 float* __restrict__ ysum)
{
    const int blk = blockIdx.x;
    const int b = blk / NHEADS;
    const int h = blk % NHEADS;
    const int k = h / NHK;
    const int tid = threadIdx.x;
    const int p = tid >> 2;
    const int ng = tid & 3;
    const int nb = ng * 8;
    float st[8];
    {
        const float* is = init_states + ((size_t)h * PDIM + p) * NSTATE + nb;
        #pragma unroll
        for (int i = 0; i < 8; ++i) st[i] = is[i];
    }
    const int dch = (h % NHK) * PDIM + p;
    const float Dh = Ds[h];
    const float* bc0 = BCdt + ((size_t)b * LL * 2 + k) * CPROJ;
    const float* dt0 = dtv + (size_t)b * LL * NHEADS + h;
    const float* da0 = dav + (size_t)b * LL * NHEADS + h;
    const float* xcb = xc + (size_t)b * LL * INNER;
    float* yb = ysum + (size_t)b * LL * INNER + dch;
    for (int l = 0; l < LL; ++l) {
        const int pos = (k == 0) ? l : ((l & 63) * 64 + (l >> 6));
        const float xh = xcb[(size_t)pos * INNER + dch];
        const float da_t = da0[(size_t)l * NHEADS];
        const float dt_t = dt0[(size_t)l * NHEADS];
        const float* bc = bc0 + (size_t)l * (2 * CPROJ);
        float Bv[8], Cv[8];
        *(float2*)(Bv)   = *(const float2*)(bc + nb);
        *(float2*)(Bv+2) = *(const float2*)(bc + nb + 2);
        *(float2*)(Bv+4) = *(const float2*)(bc + nb + 4);
        *(float2*)(Bv+6) = *(const float2*)(bc + nb + 6);
        *(float2*)(Cv)   = *(const float2*)(bc + NSTATE + nb);
        *(float2*)(Cv+2) = *(const float2*)(bc + NSTATE + nb + 2);
        *(float2*)(Cv+4) = *(const float2*)(bc + NSTATE + nb + 4);
        *(float2*)(Cv+6) = *(const float2*)(bc + NSTATE + nb + 6);
        const float coef = dt_t * xh;
        float ys = 0.f;
        #pragma unroll
        for (int i = 0; i < 8; ++i) {
            st[i] = fmaf(da_t, st[i], coef * Bv[i]);
            ys = fmaf(st[i], Cv[i], ys);
        }
        ys += __shfl_xor(ys, 1);
        ys += __shfl_xor(ys, 2);
        if (ng == 0) atomicAdd(&yb[(size_t)pos * INNER], ys + Dh * xh);
    }
}

// ---------------------------------------------------------------------------
// In-place gate: ysum[m,d] *= silu(z[m,d])
// ---------------------------------------------------------------------------
__global__ __launch_bounds__(256)
void gate_kernel(float* __restrict__ ysum, const float* __restrict__ z)
{
    const size_t e = (size_t)blockIdx.x * 256 + threadIdx.x;
    if (e >= (size_t)BB * LL * INNER) return;
    ysum[e] = ysum[e] * silu_f(z[e]);
}

// ---------------------------------------------------------------------------
// Fallback: report ws_size (in MiB) via d_out so the next round can read it
// from the absmax value instead of crashing on an OOB workspace write.
// ---------------------------------------------------------------------------
__global__ __launch_bounds__(256)
void report_ws_kernel(float* __restrict__ out, int n, float val)
{
    const int e = blockIdx.x * 256 + threadIdx.x;
    if (e < n) out[e] = val;
}

// ---------------------------------------------------------------------------
extern "C" void kernel_launch(void* const* d_in, const int* in_sizes, int n_in,
                              void* d_out, int out_size, void* d_ws, size_t ws_size,
                              hipStream_t stream)
{
    const float* x          = (const float*)d_in[0];
    const float* W_in       = (const float*)d_in[1];
    const float* conv_w     = (const float*)d_in[2];
    const float* conv_b     = (const float*)d_in[3];
    const float* xpw        = (const float*)d_in[4];
    const float* A_logs     = (const float*)d_in[5];
    const float* Ds         = (const float*)d_in[6];
    const float* dt_bias    = (const float*)d_in[7];
    const float* init_states= (const float*)d_in[8];
    const float* W_out      = (const float*)d_in[9];
    const float* W1         = (const float*)d_in[10];
    const float* b1         = (const float*)d_in[11];
    const float* W2         = (const float*)d_in[12];
    const float* b2         = (const float*)d_in[13];
    float* out = (float*)d_out;

    if (ws_size < (size_t)WS_REQ) {
        // Not enough scratch: encode ws_size in MiB into the output.
        const float mib = (float)((double)ws_size / 1048576.0);
        report_ws_kernel<<<(out_size + 255) / 256, 256, 0, stream>>>(out, out_size, mib);
        return;
    }

    char* ws = (char*)d_ws;
    float* xl   = (float*)(ws + WS_XL);    // then z, then h1 (with xc)
    float* xc   = (float*)(ws + WS_XC);
    float* BCdt = (float*)(ws + WS_BCDT);
    float* dtv  = (float*)(ws + WS_DTV);
    float* dav  = (float*)(ws + WS_DAV);
    float* ysum = (float*)(ws + WS_YSUM);
    float* z    = xl;                      // overlay: xl dead after conv
    float* h1   = xl;                      // overlay: spans xl+xc after gate/out-proj

    const int M = BB * LL;  // 32768

    // 1) xl = x @ W_in[0:384]^T   (M x 384 x 192)
    gemm_nt<0><<<dim3(M/64, INNER/64), 256, 0, stream>>>(x, W_in, nullptr, nullptr, xl, M, INNER, CIN);

    // 2) depthwise conv + bias + SiLU -> xc
    conv_dw_kernel<<<(M * INNER) / 256, 256, 0, stream>>>(xl, conv_w, conv_b, xc);

    // 3) BCdt projection (both scan directions)
    proj_bcdt_kernel<<<dim3(LL/32, 2, BB), 256, 0, stream>>>(xc, xpw, BCdt);

    // 3b) dt softplus / da = exp(A*dt)
    dtda_kernel<<<(M * NHEADS) / 256, 256, 0, stream>>>(BCdt, dt_bias, A_logs, dtv, dav);

    // 4) zero ysum, then selective scan (96 blocks, atomicAdd both directions)
    hipMemsetAsync(ysum, 0, (size_t)M * INNER * sizeof(float), stream);
    scan_kernel<<<BB * NHEADS, 256, 0, stream>>>(xc, BCdt, dtv, dav, Ds, init_states, ysum);

    // 5) z = x @ W_in[384:768]^T into xl region (xl dead after conv)
    gemm_nt<0><<<dim3(M/64, INNER/64), 256, 0, stream>>>(x, W_in + (size_t)INNER * CIN, nullptr, nullptr, z, M, INNER, CIN);

    // 5a) gate in-place: ysum *= silu(z)
    gate_kernel<<<(M * INNER) / 256, 256, 0, stream>>>(ysum, z);

    // 5b) out = x + ysum @ W_out^T   (M x 192 x 384)
    gemm_nt<3><<<dim3(M/64, CIN/64), 256, 0, stream>>>(ysum, W_out, nullptr, x, out, M, CIN, INNER);

    // 6a) h1 = silu(out @ W1^T + b1)   (M x 768 x 192) — overlays xl+xc
    gemm_nt<1><<<dim3(M/64, HID/64), 256, 0, stream>>>(out, W1, b1, nullptr, h1, M, HID, CIN);

    // 6b) out += h1 @ W2^T + b2   (M x 192 x 768)
    gemm_nt<2><<<dim3(M/64, CIN/64), 256, 0, stream>>>(h1, W2, b2, out, out, M, CIN, HID);
}

// Round 3
// 1744.916 us; speedup vs baseline: 1.8491x; 1.8491x over previous
//
#include <hip/hip_runtime.h>
#include <math.h>

#define BB 8
#define HH 64
#define WW 64
#define CIN 192
#define INNER 384
#define LL 4096          // HH*WW
#define NSTATE 32
#define PDIM 64
#define NHK 6            // INNER/PDIM
#define NHEADS 12        // 2*NHK
#define HID 768
#define CPROJ 70         // 2*NSTATE + NHK
#define QC 64            // chunk length
#define NC 64            // LL/QC chunks

// workspace layout (bytes)
#define WS_XL    0u                   // (B,L,384) 50331648 B ; SH overlays this; later z, then h1
#define WS_XC    50331648u            // (B,L,384) 50331648 B
#define WS_BCDT  100663296u           // (B,L,2,70) 18350080 B
#define WS_DTV   119013376u           // (B,L,12) 1572864 B
#define WS_CUMS  120586240u           // (B,L,12) 1572864 B
#define WS_YSUM  122159104u           // (B,L,384) 50331648 B
#define WS_REQ   172490752u

__device__ __forceinline__ float silu_f(float x) { return x / (1.f + __expf(-x)); }

// ---------------------------------------------------------------------------
// Generic GEMM: C[m,n] = sum_k A[m,k] * Wt[n,k]
// EPI: 0 = none; 1 = silu(acc+bias); 2 = acc+bias+res; 3 = acc+res
// ---------------------------------------------------------------------------
template<int EPI>
__global__ __launch_bounds__(256)
void gemm_nt(const float* __restrict__ A, const float* __restrict__ Wt,
             const float* __restrict__ bias, const float* __restrict__ res,
             float* __restrict__ C, int M, int N, int Kd)
{
    __shared__ __align__(16) float As[16][72];
    __shared__ __align__(16) float Bs[16][72];
    const int tid = threadIdx.x;
    const int m0 = blockIdx.x * 64;
    const int n0 = blockIdx.y * 64;
    const int tx = tid & 15;
    const int ty = tid >> 4;
    const int lr = tid >> 2;
    const int lc = (tid & 3) << 2;
    float acc[4][4] = {{0.f,0.f,0.f,0.f},{0.f,0.f,0.f,0.f},{0.f,0.f,0.f,0.f},{0.f,0.f,0.f,0.f}};
    const float* Aptr = A  + (size_t)(m0 + lr) * Kd + lc;
    const float* Bptr = Wt + (size_t)(n0 + lr) * Kd + lc;
    for (int k0 = 0; k0 < Kd; k0 += 16) {
        float4 av = *(const float4*)(Aptr + k0);
        float4 bv = *(const float4*)(Bptr + k0);
        __syncthreads();
        As[lc+0][lr]=av.x; As[lc+1][lr]=av.y; As[lc+2][lr]=av.z; As[lc+3][lr]=av.w;
        Bs[lc+0][lr]=bv.x; Bs[lc+1][lr]=bv.y; Bs[lc+2][lr]=bv.z; Bs[lc+3][lr]=bv.w;
        __syncthreads();
        #pragma unroll
        for (int kk = 0; kk < 16; ++kk) {
            float a0[4], b0[4];
            #pragma unroll
            for (int i = 0; i < 4; ++i) a0[i] = As[kk][ty*4+i];
            #pragma unroll
            for (int j = 0; j < 4; ++j) b0[j] = Bs[kk][tx*4+j];
            #pragma unroll
            for (int i = 0; i < 4; ++i)
                #pragma unroll
                for (int j = 0; j < 4; ++j)
                    acc[i][j] = fmaf(a0[i], b0[j], acc[i][j]);
        }
    }
    #pragma unroll
    for (int i = 0; i < 4; ++i) {
        const int m = m0 + ty*4 + i;
        #pragma unroll
        for (int j = 0; j < 4; ++j) {
            const int n = n0 + tx*4 + j;
            float v = acc[i][j];
            if (EPI == 1) v = silu_f(v + bias[n]);
            else if (EPI == 2) v = v + bias[n] + res[(size_t)m * N + n];
            else if (EPI == 3) v = v + res[(size_t)m * N + n];
            C[(size_t)m * N + n] = v;
        }
    }
}

// ---------------------------------------------------------------------------
// Depthwise 3x3 conv + bias + SiLU.  xl (B,L,384) -> xc (B,L,384)
// ---------------------------------------------------------------------------
__global__ __launch_bounds__(256)
void conv_dw_kernel(const float* __restrict__ xl, const float* __restrict__ cw,
                    const float* __restrict__ cb, float* __restrict__ xc)
{
    const size_t e = (size_t)blockIdx.x * 256 + threadIdx.x;
    if (e >= (size_t)BB * LL * INNER) return;
    const int d = (int)(e % INNER);
    const size_t m = e / INNER;
    const int b = (int)(m >> 12);
    const int r = (int)(m & 4095);
    const int i = r >> 6;
    const int j = r & 63;
    const float* wd = cw + d * 9;
    float s = 0.f;
    #pragma unroll
    for (int di = 0; di < 3; ++di) {
        const int ii = i + di - 1;
        if (ii < 0 || ii >= HH) continue;
        #pragma unroll
        for (int dj = 0; dj < 3; ++dj) {
            const int jj = j + dj - 1;
            if (jj < 0 || jj >= WW) continue;
            s = fmaf(xl[(((size_t)b << 12) + (size_t)(ii * 64 + jj)) * INNER + d], wd[di*3+dj], s);
        }
    }
    s += cb[d];
    xc[e] = silu_f(s);
}

// ---------------------------------------------------------------------------
// BCdt[b,l,k,c] = sum_d xc[b,pos_k(l),d] * xpw[k,c,d]
// ---------------------------------------------------------------------------
__global__ __launch_bounds__(256)
void proj_bcdt_kernel(const float* __restrict__ xc, const float* __restrict__ xpw,
                      float* __restrict__ BCdt)
{
    __shared__ __align__(16) float Xs[32][INNER];
    const int lt = blockIdx.x;
    const int k  = blockIdx.y;
    const int b  = blockIdx.z;
    const int l0 = lt * 32;
    for (int idx = threadIdx.x; idx < 32 * INNER; idx += 256) {
        const int llx = idx / INNER;
        const int d = idx - llx * INNER;
        const int l = l0 + llx;
        const int pos = (k == 0) ? l : ((l & 63) * 64 + (l >> 6));
        Xs[llx][d] = xc[((size_t)b * LL + pos) * INNER + d];
    }
    __syncthreads();
    const float* Wk = xpw + (size_t)k * CPROJ * INNER;
    for (int idx = threadIdx.x; idx < 32 * CPROJ; idx += 256) {
        const int llx = idx / CPROJ;
        const int c = idx - llx * CPROJ;
        const float4* w4 = (const float4*)(Wk + (size_t)c * INNER);
        const float4* x4 = (const float4*)(&Xs[llx][0]);
        float s = 0.f;
        #pragma unroll 4
        for (int d4 = 0; d4 < INNER/4; ++d4) {
            const float4 wv = w4[d4];
            const float4 xv = x4[d4];
            s = fmaf(wv.x, xv.x, s);
            s = fmaf(wv.y, xv.y, s);
            s = fmaf(wv.z, xv.z, s);
            s = fmaf(wv.w, xv.w, s);
        }
        BCdt[(((size_t)b * LL + (size_t)(l0 + llx)) * 2 + k) * CPROJ + c] = s;
    }
}

// ---------------------------------------------------------------------------
// dtv = softplus(dt_raw + dt_bias[h]); cums = per-chunk inclusive prefix sum of
// dtA = -exp(A_logs[h]) * dtv.   One wave per (b,h,chunk); lane = position.
// ---------------------------------------------------------------------------
__global__ __launch_bounds__(256)
void dtcums_kernel(const float* __restrict__ BCdt, const float* __restrict__ dt_bias,
                   const float* __restrict__ A_logs,
                   float* __restrict__ dtv, float* __restrict__ cums)
{
    const int w = blockIdx.x * 4 + (threadIdx.x >> 6);
    const int lane = threadIdx.x & 63;
    const int b = w / (NHEADS * NC);
    const int rem = w - b * (NHEADS * NC);
    const int h = rem / NC;
    const int c = rem - h * NC;
    const int k = h / NHK;
    const int hq = h - k * NHK;
    const int l = c * QC + lane;
    const float dtraw = BCdt[(((size_t)b * LL + l) * 2 + k) * CPROJ + 2*NSTATE + hq];
    const float xx = dtraw + dt_bias[h];
    const float sp = (xx > 20.f) ? xx : log1pf(expf(xx));
    float s = -expf(A_logs[h]) * sp;
    #pragma unroll
    for (int d = 1; d < 64; d <<= 1) {
        const float o = __shfl_up(s, d);
        if (lane >= d) s += o;
    }
    dtv[((size_t)b * LL + l) * NHEADS + h] = sp;
    cums[((size_t)b * LL + l) * NHEADS + h] = s;
}

// ---------------------------------------------------------------------------
// Chunk states: S_c[p,n] = sum_m dt[m]*exp(cu[63]-cu[m]) * x[m][p] * B[m][n]
// grid (NC, NHEADS, BB). SH layout: [b,h,c,p,n] (p*32+n).
// ---------------------------------------------------------------------------
__global__ __launch_bounds__(256)
void chunk_state_kernel(const float* __restrict__ xc, const float* __restrict__ BCdt,
                        const float* __restrict__ dtv, const float* __restrict__ cums,
                        float* __restrict__ SH)
{
    __shared__ float Xs[QC][64];
    __shared__ float Bs[QC][33];
    __shared__ float cuS[QC];
    __shared__ float rs[QC];
    const int c = blockIdx.x, h = blockIdx.y, b = blockIdx.z;
    const int k = h / NHK;
    const int dch0 = (h - k * NHK) * PDIM;
    const int tid = threadIdx.x;
    // load x chunk (64 x 64)
    #pragma unroll
    for (int r = 0; r < 16; ++r) {
        const int idx = tid + r * 256;
        const int i = idx >> 6, p = idx & 63;
        const int pos = (k == 0) ? (c * QC + i) : (i * QC + c);
        Xs[i][p] = xc[(((size_t)b << 12) + pos) * INNER + dch0 + p];
    }
    // load B chunk (64 x 32)
    #pragma unroll
    for (int r = 0; r < 8; ++r) {
        const int idx = tid + r * 256;
        const int i = idx >> 5, n = idx & 31;
        Bs[i][n] = BCdt[(((size_t)b * LL + c * QC + i) * 2 + k) * CPROJ + n];
    }
    if (tid < QC)
        cuS[tid] = cums[((size_t)b * LL + c * QC + tid) * NHEADS + h];
    __syncthreads();
    if (tid < QC)
        rs[tid] = dtv[((size_t)b * LL + c * QC + tid) * NHEADS + h] * __expf(cuS[QC-1] - cuS[tid]);
    __syncthreads();
    const int p = tid & 63;
    const int n0 = (tid >> 6) * 8;
    float s[8] = {0.f,0.f,0.f,0.f,0.f,0.f,0.f,0.f};
    #pragma unroll 8
    for (int m = 0; m < QC; ++m) {
        const float rx = rs[m] * Xs[m][p];
        #pragma unroll
        for (int j = 0; j < 8; ++j) s[j] = fmaf(rx, Bs[m][n0 + j], s[j]);
    }
    float* dst = SH + ((((size_t)b * NHEADS + h) * NC + c) * PDIM + p) * NSTATE + n0;
    *(float4*)(dst)     = make_float4(s[0], s[1], s[2], s[3]);
    *(float4*)(dst + 4) = make_float4(s[4], s[5], s[6], s[7]);
}

// ---------------------------------------------------------------------------
// Sequential scan over chunks (in place): slot c gets H_c = state at START of
// chunk c; h <- decay_c * h + S_c.  96 blocks, 64 iterations.
// ---------------------------------------------------------------------------
__global__ __launch_bounds__(256)
void state_scan_kernel(float* __restrict__ SH, const float* __restrict__ cums,
                       const float* __restrict__ init_states)
{
    __shared__ float decays[NC];
    const int b = blockIdx.x / NHEADS;
    const int h = blockIdx.x % NHEADS;
    const int tid = threadIdx.x;
    if (tid < NC)
        decays[tid] = __expf(cums[((size_t)b * LL + tid * QC + QC - 1) * NHEADS + h]);
    __syncthreads();
    const int p = tid >> 2;
    const int nb = (tid & 3) * 8;
    float hs[8];
    {
        const float* is = init_states + ((size_t)h * PDIM + p) * NSTATE + nb;
        #pragma unroll
        for (int i = 0; i < 8; ++i) hs[i] = is[i];
    }
    float* base = SH + (((size_t)b * NHEADS + h) * NC) * (PDIM * NSTATE) + p * NSTATE + nb;
    for (int c = 0; c < NC; ++c) {
        float* slot = base + (size_t)c * (PDIM * NSTATE);
        float4 s0 = *(float4*)(slot);
        float4 s1 = *(float4*)(slot + 4);
        *(float4*)(slot)     = make_float4(hs[0], hs[1], hs[2], hs[3]);
        *(float4*)(slot + 4) = make_float4(hs[4], hs[5], hs[6], hs[7]);
        const float dc = decays[c];
        hs[0] = fmaf(dc, hs[0], s0.x); hs[1] = fmaf(dc, hs[1], s0.y);
        hs[2] = fmaf(dc, hs[2], s0.z); hs[3] = fmaf(dc, hs[3], s0.w);
        hs[4] = fmaf(dc, hs[4], s1.x); hs[5] = fmaf(dc, hs[5], s1.y);
        hs[6] = fmaf(dc, hs[6], s1.z); hs[7] = fmaf(dc, hs[7], s1.w);
    }
}

// ---------------------------------------------------------------------------
// Intra-chunk + inter-chunk + D term.  grid (NC, NHEADS, BB).
// G[i][m] = (m<=i) ? exp(cu[i]-cu[m])*dt[m]*(C_i·B_m) : 0
// y[i][p] = sum_m G[i][m] x[m][p] + exp(cu[i]) * (C_i · H[p,:]) + D*x[i][p]
// atomicAdd into ysum at row-major pos (2 commutative adds/elt).
// ---------------------------------------------------------------------------
__global__ __launch_bounds__(256)
void intra_kernel(const float* __restrict__ xc, const float* __restrict__ BCdt,
                  const float* __restrict__ dtv, const float* __restrict__ cums,
                  const float* __restrict__ SH, const float* __restrict__ Ds,
                  float* __restrict__ ysum)
{
    __shared__ float Xs[QC][64];
    __shared__ float Bs[QC][33];
    __shared__ float Cs[QC][33];
    __shared__ float Hs[PDIM][33];
    __shared__ float Gs[QC][65];
    __shared__ float cuS[QC], dtS[QC], Ei[QC];
    const int c = blockIdx.x, h = blockIdx.y, b = blockIdx.z;
    const int k = h / NHK;
    const int dch0 = (h - k * NHK) * PDIM;
    const int tid = threadIdx.x;
    #pragma unroll
    for (int r = 0; r < 16; ++r) {
        const int idx = tid + r * 256;
        const int i = idx >> 6, p = idx & 63;
        const int pos = (k == 0) ? (c * QC + i) : (i * QC + c);
        Xs[i][p] = xc[(((size_t)b << 12) + pos) * INNER + dch0 + p];
    }
    #pragma unroll
    for (int r = 0; r < 16; ++r) {
        const int idx = tid + r * 256;
        const int i = idx >> 6, q = idx & 63;
        const float v = BCdt[(((size_t)b * LL + c * QC + i) * 2 + k) * CPROJ + q];
        if (q < NSTATE) Bs[i][q] = v; else Cs[i][q - NSTATE] = v;
    }
    #pragma unroll
    for (int r = 0; r < 8; ++r) {
        const int idx = tid + r * 256;
        const int p = idx >> 5, n = idx & 31;
        Hs[p][n] = SH[((((size_t)b * NHEADS + h) * NC + c) * PDIM + p) * NSTATE + n];
    }
    if (tid < QC) {
        const size_t o = ((size_t)b * LL + c * QC + tid) * NHEADS + h;
        const float cu = cums[o];
        cuS[tid] = cu;
        dtS[tid] = dtv[o];
        Ei[tid]  = __expf(cu);
    }
    __syncthreads();
    // stage 1: G
    {
        const int m = tid & 63;
        const int ig = tid >> 6;
        #pragma unroll
        for (int ii = 0; ii < 16; ++ii) {
            const int i = ig * 16 + ii;
            float acc = 0.f;
            #pragma unroll
            for (int n = 0; n < NSTATE; ++n) acc = fmaf(Cs[i][n], Bs[m][n], acc);
            float wexp = fminf(cuS[i] - cuS[m], 0.f);
            Gs[i][m] = (m <= i) ? __expf(wexp) * dtS[m] * acc : 0.f;
        }
    }
    __syncthreads();
    // stage 2: y
    const float Dh = Ds[h];
    const int p = tid & 63;
    const int ig = tid >> 6;
    #pragma unroll
    for (int ii = 0; ii < 16; ++ii) {
        const int i = ig * 16 + ii;
        float acc = Dh * Xs[i][p];
        float accI = 0.f;
        #pragma unroll
        for (int n = 0; n < NSTATE; ++n) accI = fmaf(Cs[i][n], Hs[p][n], accI);
        acc = fmaf(Ei[i], accI, acc);
        #pragma unroll 16
        for (int m = 0; m < QC; ++m) acc = fmaf(Gs[i][m], Xs[m][p], acc);
        const int pos = (k == 0) ? (c * QC + i) : (i * QC + c);
        atomicAdd(&ysum[(((size_t)b << 12) + pos) * INNER + dch0 + p], acc);
    }
}

// ---------------------------------------------------------------------------
__global__ __launch_bounds__(256)
void gate_kernel(float* __restrict__ ysum, const float* __restrict__ z)
{
    const size_t e = (size_t)blockIdx.x * 256 + threadIdx.x;
    if (e >= (size_t)BB * LL * INNER) return;
    ysum[e] = ysum[e] * silu_f(z[e]);
}

__global__ __launch_bounds__(256)
void report_ws_kernel(float* __restrict__ out, int n, float val)
{
    const int e = blockIdx.x * 256 + threadIdx.x;
    if (e < n) out[e] = val;
}

// ---------------------------------------------------------------------------
extern "C" void kernel_launch(void* const* d_in, const int* in_sizes, int n_in,
                              void* d_out, int out_size, void* d_ws, size_t ws_size,
                              hipStream_t stream)
{
    const float* x          = (const float*)d_in[0];
    const float* W_in       = (const float*)d_in[1];
    const float* conv_w     = (const float*)d_in[2];
    const float* conv_b     = (const float*)d_in[3];
    const float* xpw        = (const float*)d_in[4];
    const float* A_logs     = (const float*)d_in[5];
    const float* Ds         = (const float*)d_in[6];
    const float* dt_bias    = (const float*)d_in[7];
    const float* init_states= (const float*)d_in[8];
    const float* W_out      = (const float*)d_in[9];
    const float* W1         = (const float*)d_in[10];
    const float* b1         = (const float*)d_in[11];
    const float* W2         = (const float*)d_in[12];
    const float* b2         = (const float*)d_in[13];
    float* out = (float*)d_out;

    if (ws_size < (size_t)WS_REQ) {
        const float mib = (float)((double)ws_size / 1048576.0);
        report_ws_kernel<<<(out_size + 255) / 256, 256, 0, stream>>>(out, out_size, mib);
        return;
    }

    char* ws = (char*)d_ws;
    float* xl   = (float*)(ws + WS_XL);
    float* xc   = (float*)(ws + WS_XC);
    float* BCdt = (float*)(ws + WS_BCDT);
    float* dtv  = (float*)(ws + WS_DTV);
    float* cums = (float*)(ws + WS_CUMS);
    float* ysum = (float*)(ws + WS_YSUM);
    float* SH   = xl;   // overlay: xl dead after conv, SH dead before z-GEMM
    float* z    = xl;
    float* h1   = xl;

    const int M = BB * LL;  // 32768

    // 1) xl = x @ W_in[0:384]^T
    gemm_nt<0><<<dim3(M/64, INNER/64), 256, 0, stream>>>(x, W_in, nullptr, nullptr, xl, M, INNER, CIN);

    // 2) depthwise conv + bias + SiLU -> xc   (xl dead after this)
    conv_dw_kernel<<<(M * INNER) / 256, 256, 0, stream>>>(xl, conv_w, conv_b, xc);

    // 3) BCdt projection + dt/cumsum
    proj_bcdt_kernel<<<dim3(LL/32, 2, BB), 256, 0, stream>>>(xc, xpw, BCdt);
    dtcums_kernel<<<(BB * NHEADS * NC) / 4, 256, 0, stream>>>(BCdt, dt_bias, A_logs, dtv, cums);

    // 4) chunked scan
    chunk_state_kernel<<<dim3(NC, NHEADS, BB), 256, 0, stream>>>(xc, BCdt, dtv, cums, SH);
    state_scan_kernel<<<BB * NHEADS, 256, 0, stream>>>(SH, cums, init_states);
    hipMemsetAsync(ysum, 0, (size_t)M * INNER * sizeof(float), stream);
    intra_kernel<<<dim3(NC, NHEADS, BB), 256, 0, stream>>>(xc, BCdt, dtv, cums, SH, Ds, ysum);

    // 5) z = x @ W_in[384:768]^T  (SH dead now)
    gemm_nt<0><<<dim3(M/64, INNER/64), 256, 0, stream>>>(x, W_in + (size_t)INNER * CIN, nullptr, nullptr, z, M, INNER, CIN);
    gate_kernel<<<(M * INNER) / 256, 256, 0, stream>>>(ysum, z);

    // 5b) out = x + ysum @ W_out^T
    gemm_nt<3><<<dim3(M/64, CIN/64), 256, 0, stream>>>(ysum, W_out, nullptr, x, out, M, CIN, INNER);

    // 6) MLP
    gemm_nt<1><<<dim3(M/64, HID/64), 256, 0, stream>>>(out, W1, b1, nullptr, h1, M, HID, CIN);
    gemm_nt<2><<<dim3(M/64, CIN/64), 256, 0, stream>>>(h1, W2, b2, out, out, M, CIN, HID);
}

// Round 5
// 1133.472 us; speedup vs baseline: 2.8466x; 1.5394x over previous
//
#include <hip/hip_runtime.h>
#include <math.h>

#define BB 8
#define HH 64
#define WW 64
#define CIN 192
#define INNER 384
#define LL 4096          // HH*WW
#define NSTATE 32
#define PDIM 64
#define NHK 6            // INNER/PDIM
#define NHEADS 12        // 2*NHK
#define HID 768
#define CPROJ 70         // 2*NSTATE + NHK
#define QC 64            // chunk length
#define NC 64            // LL/QC chunks

// workspace layout (bytes)
#define WS_XL    0u                   // (B,L,384) 50331648 B ; SH overlays this; later z, then h1
#define WS_XC    50331648u            // (B,L,384) 50331648 B
#define WS_BCDT  100663296u           // (B,L,2,70) 18350080 B
#define WS_DTV   119013376u           // (B,L,12) 1572864 B
#define WS_CUMS  120586240u           // (B,L,12) 1572864 B
#define WS_YSUM  122159104u           // (B,L,384) 50331648 B ; wpad overlays head pre-memset
#define WS_REQ   172490752u

__device__ __forceinline__ float silu_f(float x) { return x / (1.f + __expf(-x)); }

// ---------------------------------------------------------------------------
// Generic GEMM: C[m,n] = sum_k A[m,k] * Wt[n,k]
// EPI: 0 = none; 1 = silu(acc+bias); 2 = acc+bias+res; 3 = acc+res
// TRANSA: A row index remapped through the column-scan permutation
//         (row-major <-> column-major spatial transpose within each image).
// ldc: C (and res) leading dim; nmax: store only n < nmax.
// ---------------------------------------------------------------------------
template<int EPI, int TRANSA>
__global__ __launch_bounds__(256)
void gemm_nt(const float* __restrict__ A, const float* __restrict__ Wt,
             const float* __restrict__ bias, const float* __restrict__ res,
             float* __restrict__ C, int M, int N, int Kd, int ldc, int nmax)
{
    __shared__ __align__(16) float As[16][72];
    __shared__ __align__(16) float Bs[16][72];
    const int tid = threadIdx.x;
    const int m0 = blockIdx.x * 64;
    const int n0 = blockIdx.y * 64;
    const int tx = tid & 15;
    const int ty = tid >> 4;
    const int lr = tid >> 2;
    const int lc = (tid & 3) << 2;
    float acc[4][4] = {{0.f,0.f,0.f,0.f},{0.f,0.f,0.f,0.f},{0.f,0.f,0.f,0.f},{0.f,0.f,0.f,0.f}};
    size_t arow;
    if (TRANSA) {
        const int mm = m0 + lr;
        const int bq = mm >> 12;
        const int lq = mm & 4095;
        arow = ((size_t)bq << 12) + (size_t)(((lq & 63) << 6) + (lq >> 6));
    } else {
        arow = (size_t)(m0 + lr);
    }
    const float* Aptr = A  + arow * Kd + lc;
    const float* Bptr = Wt + (size_t)(n0 + lr) * Kd + lc;
    for (int k0 = 0; k0 < Kd; k0 += 16) {
        float4 av = *(const float4*)(Aptr + k0);
        float4 bv = *(const float4*)(Bptr + k0);
        __syncthreads();
        As[lc+0][lr]=av.x; As[lc+1][lr]=av.y; As[lc+2][lr]=av.z; As[lc+3][lr]=av.w;
        Bs[lc+0][lr]=bv.x; Bs[lc+1][lr]=bv.y; Bs[lc+2][lr]=bv.z; Bs[lc+3][lr]=bv.w;
        __syncthreads();
        #pragma unroll
        for (int kk = 0; kk < 16; ++kk) {
            float a0[4], b0[4];
            #pragma unroll
            for (int i = 0; i < 4; ++i) a0[i] = As[kk][ty*4+i];
            #pragma unroll
            for (int j = 0; j < 4; ++j) b0[j] = Bs[kk][tx*4+j];
            #pragma unroll
            for (int i = 0; i < 4; ++i)
                #pragma unroll
                for (int j = 0; j < 4; ++j)
                    acc[i][j] = fmaf(a0[i], b0[j], acc[i][j]);
        }
    }
    #pragma unroll
    for (int i = 0; i < 4; ++i) {
        const int m = m0 + ty*4 + i;
        #pragma unroll
        for (int j = 0; j < 4; ++j) {
            const int n = n0 + tx*4 + j;
            if (n >= nmax) continue;
            float v = acc[i][j];
            if (EPI == 1) v = silu_f(v + bias[n]);
            else if (EPI == 2) v = v + bias[n] + res[(size_t)m * ldc + n];
            else if (EPI == 3) v = v + res[(size_t)m * ldc + n];
            C[(size_t)m * ldc + n] = v;
        }
    }
}

// ---------------------------------------------------------------------------
// Pad x_proj_weight (2,70,384) -> wpad (2,128,384), zeros beyond row 69.
// ---------------------------------------------------------------------------
__global__ __launch_bounds__(256)
void pad_w_kernel(const float* __restrict__ xpw, float* __restrict__ wpad)
{
    const int idx = blockIdx.x * 256 + threadIdx.x;
    if (idx >= 2 * 128 * INNER) return;
    const int d = idx % INNER;
    const int r = (idx / INNER) & 127;
    const int k = idx / (128 * INNER);
    wpad[idx] = (r < CPROJ) ? xpw[((size_t)k * CPROJ + r) * INNER + d] : 0.f;
}

// ---------------------------------------------------------------------------
// Depthwise 3x3 conv + bias + SiLU.  xl (B,L,384) -> xc (B,L,384)
// ---------------------------------------------------------------------------
__global__ __launch_bounds__(256)
void conv_dw_kernel(const float* __restrict__ xl, const float* __restrict__ cw,
                    const float* __restrict__ cb, float* __restrict__ xc)
{
    const size_t e = (size_t)blockIdx.x * 256 + threadIdx.x;
    if (e >= (size_t)BB * LL * INNER) return;
    const int d = (int)(e % INNER);
    const size_t m = e / INNER;
    const int b = (int)(m >> 12);
    const int r = (int)(m & 4095);
    const int i = r >> 6;
    const int j = r & 63;
    const float* wd = cw + d * 9;
    float s = 0.f;
    #pragma unroll
    for (int di = 0; di < 3; ++di) {
        const int ii = i + di - 1;
        if (ii < 0 || ii >= HH) continue;
        #pragma unroll
        for (int dj = 0; dj < 3; ++dj) {
            const int jj = j + dj - 1;
            if (jj < 0 || jj >= WW) continue;
            s = fmaf(xl[(((size_t)b << 12) + (size_t)(ii * 64 + jj)) * INNER + d], wd[di*3+dj], s);
        }
    }
    s += cb[d];
    xc[e] = silu_f(s);
}

// ---------------------------------------------------------------------------
// dtv = softplus(dt_raw + dt_bias[h]); cums = per-chunk inclusive prefix sum of
// dtA = -exp(A_logs[h]) * dtv.   One wave per (b,h,chunk); lane = position.
// ---------------------------------------------------------------------------
__global__ __launch_bounds__(256)
void dtcums_kernel(const float* __restrict__ BCdt, const float* __restrict__ dt_bias,
                   const float* __restrict__ A_logs,
                   float* __restrict__ dtv, float* __restrict__ cums)
{
    const int w = blockIdx.x * 4 + (threadIdx.x >> 6);
    const int lane = threadIdx.x & 63;
    const int b = w / (NHEADS * NC);
    const int rem = w - b * (NHEADS * NC);
    const int h = rem / NC;
    const int c = rem - h * NC;
    const int k = h / NHK;
    const int hq = h - k * NHK;
    const int l = c * QC + lane;
    const float dtraw = BCdt[(((size_t)b * LL + l) * 2 + k) * CPROJ + 2*NSTATE + hq];
    const float xx = dtraw + dt_bias[h];
    const float sp = (xx > 20.f) ? xx : log1pf(expf(xx));
    float s = -expf(A_logs[h]) * sp;
    #pragma unroll
    for (int d = 1; d < 64; d <<= 1) {
        const float o = __shfl_up(s, d);
        if (lane >= d) s += o;
    }
    dtv[((size_t)b * LL + l) * NHEADS + h] = sp;
    cums[((size_t)b * LL + l) * NHEADS + h] = s;
}

// ---------------------------------------------------------------------------
// Chunk states: S_c[p,n] = sum_m dt[m]*exp(cu[63]-cu[m]) * x[m][p] * B[m][n]
// grid (NC, NHEADS, BB). SH layout: [b,h,c,p,n] (p*32+n).
// ---------------------------------------------------------------------------
__global__ __launch_bounds__(256)
void chunk_state_kernel(const float* __restrict__ xc, const float* __restrict__ BCdt,
                        const float* __restrict__ dtv, const float* __restrict__ cums,
                        float* __restrict__ SH)
{
    __shared__ float Xs[QC][64];
    __shared__ float Bs[QC][33];
    __shared__ float cuS[QC];
    __shared__ float rs[QC];
    const int c = blockIdx.x, h = blockIdx.y, b = blockIdx.z;
    const int k = h / NHK;
    const int dch0 = (h - k * NHK) * PDIM;
    const int tid = threadIdx.x;
    #pragma unroll
    for (int r = 0; r < 16; ++r) {
        const int idx = tid + r * 256;
        const int i = idx >> 6, p = idx & 63;
        const int pos = (k == 0) ? (c * QC + i) : (i * QC + c);
        Xs[i][p] = xc[(((size_t)b << 12) + pos) * INNER + dch0 + p];
    }
    #pragma unroll
    for (int r = 0; r < 8; ++r) {
        const int idx = tid + r * 256;
        const int i = idx >> 5, n = idx & 31;
        Bs[i][n] = BCdt[(((size_t)b * LL + c * QC + i) * 2 + k) * CPROJ + n];
    }
    if (tid < QC)
        cuS[tid] = cums[((size_t)b * LL + c * QC + tid) * NHEADS + h];
    __syncthreads();
    if (tid < QC)
        rs[tid] = dtv[((size_t)b * LL + c * QC + tid) * NHEADS + h] * __expf(cuS[QC-1] - cuS[tid]);
    __syncthreads();
    const int p = tid & 63;
    const int n0 = (tid >> 6) * 8;
    float s[8] = {0.f,0.f,0.f,0.f,0.f,0.f,0.f,0.f};
    #pragma unroll 8
    for (int m = 0; m < QC; ++m) {
        const float rx = rs[m] * Xs[m][p];
        #pragma unroll
        for (int j = 0; j < 8; ++j) s[j] = fmaf(rx, Bs[m][n0 + j], s[j]);
    }
    float* dst = SH + ((((size_t)b * NHEADS + h) * NC + c) * PDIM + p) * NSTATE + n0;
    *(float4*)(dst)     = make_float4(s[0], s[1], s[2], s[3]);
    *(float4*)(dst + 4) = make_float4(s[4], s[5], s[6], s[7]);
}

// ---------------------------------------------------------------------------
// Sequential scan over chunks (in place): slot c gets H_c = state at START of
// chunk c; h <- decay_c * h + S_c.  96 blocks, 64 iterations.
// ---------------------------------------------------------------------------
__global__ __launch_bounds__(256)
void state_scan_kernel(float* __restrict__ SH, const float* __restrict__ cums,
                       const float* __restrict__ init_states)
{
    __shared__ float decays[NC];
    const int b = blockIdx.x / NHEADS;
    const int h = blockIdx.x % NHEADS;
    const int tid = threadIdx.x;
    if (tid < NC)
        decays[tid] = __expf(cums[((size_t)b * LL + tid * QC + QC - 1) * NHEADS + h]);
    __syncthreads();
    const int p = tid >> 2;
    const int nb = (tid & 3) * 8;
    float hs[8];
    {
        const float* is = init_states + ((size_t)h * PDIM + p) * NSTATE + nb;
        #pragma unroll
        for (int i = 0; i < 8; ++i) hs[i] = is[i];
    }
    float* base = SH + (((size_t)b * NHEADS + h) * NC) * (PDIM * NSTATE) + p * NSTATE + nb;
    for (int c = 0; c < NC; ++c) {
        float* slot = base + (size_t)c * (PDIM * NSTATE);
        float4 s0 = *(float4*)(slot);
        float4 s1 = *(float4*)(slot + 4);
        *(float4*)(slot)     = make_float4(hs[0], hs[1], hs[2], hs[3]);
        *(float4*)(slot + 4) = make_float4(hs[4], hs[5], hs[6], hs[7]);
        const float dc = decays[c];
        hs[0] = fmaf(dc, hs[0], s0.x); hs[1] = fmaf(dc, hs[1], s0.y);
        hs[2] = fmaf(dc, hs[2], s0.z); hs[3] = fmaf(dc, hs[3], s0.w);
        hs[4] = fmaf(dc, hs[4], s1.x); hs[5] = fmaf(dc, hs[5], s1.y);
        hs[6] = fmaf(dc, hs[6], s1.z); hs[7] = fmaf(dc, hs[7], s1.w);
    }
}

// ---------------------------------------------------------------------------
// Intra-chunk + inter-chunk + D term.  grid (NC, NHEADS, BB).
// ---------------------------------------------------------------------------
__global__ __launch_bounds__(256)
void intra_kernel(const float* __restrict__ xc, const float* __restrict__ BCdt,
                  const float* __restrict__ dtv, const float* __restrict__ cums,
                  const float* __restrict__ SH, const float* __restrict__ Ds,
                  float* __restrict__ ysum)
{
    __shared__ float Xs[QC][64];
    __shared__ float Bs[QC][33];
    __shared__ float Cs[QC][33];
    __shared__ float Hs[PDIM][33];
    __shared__ float Gs[QC][65];
    __shared__ float cuS[QC], dtS[QC], Ei[QC];
    const int c = blockIdx.x, h = blockIdx.y, b = blockIdx.z;
    const int k = h / NHK;
    const int dch0 = (h - k * NHK) * PDIM;
    const int tid = threadIdx.x;
    #pragma unroll
    for (int r = 0; r < 16; ++r) {
        const int idx = tid + r * 256;
        const int i = idx >> 6, p = idx & 63;
        const int pos = (k == 0) ? (c * QC + i) : (i * QC + c);
        Xs[i][p] = xc[(((size_t)b << 12) + pos) * INNER + dch0 + p];
    }
    #pragma unroll
    for (int r = 0; r < 16; ++r) {
        const int idx = tid + r * 256;
        const int i = idx >> 6, q = idx & 63;
        const float v = BCdt[(((size_t)b * LL + c * QC + i) * 2 + k) * CPROJ + q];
        if (q < NSTATE) Bs[i][q] = v; else Cs[i][q - NSTATE] = v;
    }
    #pragma unroll
    for (int r = 0; r < 8; ++r) {
        const int idx = tid + r * 256;
        const int p = idx >> 5, n = idx & 31;
        Hs[p][n] = SH[((((size_t)b * NHEADS + h) * NC + c) * PDIM + p) * NSTATE + n];
    }
    if (tid < QC) {
        const size_t o = ((size_t)b * LL + c * QC + tid) * NHEADS + h;
        const float cu = cums[o];
        cuS[tid] = cu;
        dtS[tid] = dtv[o];
        Ei[tid]  = __expf(cu);
    }
    __syncthreads();
    {
        const int m = tid & 63;
        const int ig = tid >> 6;
        #pragma unroll
        for (int ii = 0; ii < 16; ++ii) {
            const int i = ig * 16 + ii;
            float acc = 0.f;
            #pragma unroll
            for (int n = 0; n < NSTATE; ++n) acc = fmaf(Cs[i][n], Bs[m][n], acc);
            float wexp = fminf(cuS[i] - cuS[m], 0.f);
            Gs[i][m] = (m <= i) ? __expf(wexp) * dtS[m] * acc : 0.f;
        }
    }
    __syncthreads();
    const float Dh = Ds[h];
    const int p = tid & 63;
    const int ig = tid >> 6;
    #pragma unroll
    for (int ii = 0; ii < 16; ++ii) {
        const int i = ig * 16 + ii;
        float acc = Dh * Xs[i][p];
        float accI = 0.f;
        #pragma unroll
        for (int n = 0; n < NSTATE; ++n) accI = fmaf(Cs[i][n], Hs[p][n], accI);
        acc = fmaf(Ei[i], accI, acc);
        #pragma unroll 16
        for (int m = 0; m < QC; ++m) acc = fmaf(Gs[i][m], Xs[m][p], acc);
        const int pos = (k == 0) ? (c * QC + i) : (i * QC + c);
        atomicAdd(&ysum[(((size_t)b << 12) + pos) * INNER + dch0 + p], acc);
    }
}

// ---------------------------------------------------------------------------
__global__ __launch_bounds__(256)
void gate_kernel(float* __restrict__ ysum, const float* __restrict__ z)
{
    const size_t e = (size_t)blockIdx.x * 256 + threadIdx.x;
    if (e >= (size_t)BB * LL * INNER) return;
    ysum[e] = ysum[e] * silu_f(z[e]);
}

__global__ __launch_bounds__(256)
void report_ws_kernel(float* __restrict__ out, int n, float val)
{
    const int e = blockIdx.x * 256 + threadIdx.x;
    if (e < n) out[e] = val;
}

// ---------------------------------------------------------------------------
extern "C" void kernel_launch(void* const* d_in, const int* in_sizes, int n_in,
                              void* d_out, int out_size, void* d_ws, size_t ws_size,
                              hipStream_t stream)
{
    const float* x          = (const float*)d_in[0];
    const float* W_in       = (const float*)d_in[1];
    const float* conv_w     = (const float*)d_in[2];
    const float* conv_b     = (const float*)d_in[3];
    const float* xpw        = (const float*)d_in[4];
    const float* A_logs     = (const float*)d_in[5];
    const float* Ds         = (const float*)d_in[6];
    const float* dt_bias    = (const float*)d_in[7];
    const float* init_states= (const float*)d_in[8];
    const float* W_out      = (const float*)d_in[9];
    const float* W1         = (const float*)d_in[10];
    const float* b1         = (const float*)d_in[11];
    const float* W2         = (const float*)d_in[12];
    const float* b2         = (const float*)d_in[13];
    float* out = (float*)d_out;

    if (ws_size < (size_t)WS_REQ) {
        const float mib = (float)((double)ws_size / 1048576.0);
        report_ws_kernel<<<(out_size + 255) / 256, 256, 0, stream>>>(out, out_size, mib);
        return;
    }

    char* ws = (char*)d_ws;
    float* xl   = (float*)(ws + WS_XL);
    float* xc   = (float*)(ws + WS_XC);
    float* BCdt = (float*)(ws + WS_BCDT);
    float* dtv  = (float*)(ws + WS_DTV);
    float* cums = (float*)(ws + WS_CUMS);
    float* ysum = (float*)(ws + WS_YSUM);
    float* wpad = (float*)(ws + WS_YSUM);  // overlay: dead before ysum memset
    float* SH   = xl;   // overlay: xl dead after conv, SH dead before z-GEMM
    float* z    = xl;
    float* h1   = xl;

    const int M = BB * LL;  // 32768

    // 1) xl = x @ W_in[0:384]^T
    gemm_nt<0,0><<<dim3(M/64, INNER/64), 256, 0, stream>>>(x, W_in, nullptr, nullptr, xl, M, INNER, CIN, INNER, INNER);

    // 2) depthwise conv + bias + SiLU -> xc   (xl dead after this)
    conv_dw_kernel<<<(M * INNER) / 256, 256, 0, stream>>>(xl, conv_w, conv_b, xc);

    // 3) BCdt projection as two GEMMs (padded N=128, interleaved k-stride-140 output)
    pad_w_kernel<<<(2 * 128 * INNER) / 256, 256, 0, stream>>>(xpw, wpad);
    gemm_nt<0,0><<<dim3(M/64, 2), 256, 0, stream>>>(xc, wpad, nullptr, nullptr,
                                                    BCdt, M, 128, INNER, 2*CPROJ, CPROJ);
    gemm_nt<0,1><<<dim3(M/64, 2), 256, 0, stream>>>(xc, wpad + 128 * INNER, nullptr, nullptr,
                                                    BCdt + CPROJ, M, 128, INNER, 2*CPROJ, CPROJ);

    // 3b) dt softplus + per-chunk cumsum
    dtcums_kernel<<<(BB * NHEADS * NC) / 4, 256, 0, stream>>>(BCdt, dt_bias, A_logs, dtv, cums);

    // 4) chunked scan
    chunk_state_kernel<<<dim3(NC, NHEADS, BB), 256, 0, stream>>>(xc, BCdt, dtv, cums, SH);
    state_scan_kernel<<<BB * NHEADS, 256, 0, stream>>>(SH, cums, init_states);
    hipMemsetAsync(ysum, 0, (size_t)M * INNER * sizeof(float), stream);
    intra_kernel<<<dim3(NC, NHEADS, BB), 256, 0, stream>>>(xc, BCdt, dtv, cums, SH, Ds, ysum);

    // 5) z = x @ W_in[384:768]^T  (SH dead now)
    gemm_nt<0,0><<<dim3(M/64, INNER/64), 256, 0, stream>>>(x, W_in + (size_t)INNER * CIN, nullptr, nullptr, z, M, INNER, CIN, INNER, INNER);
    gate_kernel<<<(M * INNER) / 256, 256, 0, stream>>>(ysum, z);

    // 5b) out = x + ysum @ W_out^T
    gemm_nt<3,0><<<dim3(M/64, CIN/64), 256, 0, stream>>>(ysum, W_out, nullptr, x, out, M, CIN, INNER, CIN, CIN);

    // 6) MLP
    gemm_nt<1,0><<<dim3(M/64, HID/64), 256, 0, stream>>>(out, W1, b1, nullptr, h1, M, HID, CIN, HID, HID);
    gemm_nt<2,0><<<dim3(M/64, CIN/64), 256, 0, stream>>>(h1, W2, b2, out, out, M, CIN, HID, CIN, CIN);
}

// Round 6
// 667.500 us; speedup vs baseline: 4.8337x; 1.6981x over previous
//
#include <hip/hip_runtime.h>
#include <math.h>

#define BB 8
#define HH 64
#define WW 64
#define CIN 192
#define INNER 384
#define LL 4096          // HH*WW
#define NSTATE 32
#define PDIM 64
#define NHK 6            // INNER/PDIM
#define NHEADS 12        // 2*NHK
#define HID 768
#define CPROJ 70         // 2*NSTATE + NHK
#define QC 64            // chunk length
#define NC 64            // LL/QC chunks

// workspace layout (bytes)
#define WS_XL    0u                   // (B,L,384) f32 50331648 ; SH overlay; z overlay; h1_bf overlay
#define WS_XC    50331648u            // (B,L,384) f32 50331648 ; yg_bf overlay after intra
#define WS_BCDT  100663296u           // (B,L,2,70) f32 18350080 ; out_bf overlay after intra
#define WS_DTV   119013376u           // (B,L,12) f32 1572864
#define WS_CUMS  120586240u           // (B,L,12) f32 1572864
#define WS_YSUM  122159104u           // (B,L,384) f32 50331648 ; xc_bf overlay pre-memset
#define WS_XBF   172490752u           // (M,192) bf16 12582912
#define WS_WINB  185073664u           // W_in bf16 768x192      294912
#define WS_WPADB 185368576u           // xpw padded bf16 2x128x384 196608
#define WS_WOUTB 185565184u           // W_out padded bf16 256x384 196608
#define WS_W1B   185761792u           // W1 bf16 768x192        294912
#define WS_W2B   186056704u           // W2 padded bf16 256x768 393216
#define WS_REQ   186449920u

typedef __attribute__((ext_vector_type(8))) short short8;
typedef __attribute__((ext_vector_type(4))) float f32x4;

__device__ __forceinline__ float silu_f(float x) { return x / (1.f + __expf(-x)); }

__device__ __forceinline__ unsigned short f2bf(float f) {
    unsigned u = __float_as_uint(f);
    u += 0x7fffu + ((u >> 16) & 1u);
    return (unsigned short)(u >> 16);
}

// ---------------------------------------------------------------------------
// bf16 MFMA GEMM: C[m,n] = sum_k A[m,k]*Wt[n,k].  A,Wt bf16; acc f32.
// 128x128 tile, BK=64, 4 waves x (64x64), mfma_f32_16x16x32_bf16.
// LDS XOR-swizzle: 16B-block index ^= row&7  (conflict-free b128 read/write).
// EPI: 0 = Cf=acc; 1 = Cb=bf16(silu(acc+bias)); 2 = Cf=acc+bias+res;
//      3 = Cf=acc+res and Cb=bf16(same).
// TRANSA: A row remapped through column-scan permutation.
// ---------------------------------------------------------------------------
template<int EPI, int TRANSA>
__global__ __launch_bounds__(256)
void gemm_bf16(const unsigned short* __restrict__ A, const unsigned short* __restrict__ Wt,
               const float* __restrict__ bias, const float* __restrict__ res,
               float* __restrict__ Cf, unsigned short* __restrict__ Cb,
               int Kd, int ldc, int nmax)
{
    __shared__ __align__(16) short Als[128 * 64];
    __shared__ __align__(16) short Bls[128 * 64];
    const int tid = threadIdx.x;
    const int m0 = blockIdx.x * 128;
    const int n0 = blockIdx.y * 128;
    const int lane = tid & 63;
    const int wv = tid >> 6;
    const int wm = (wv >> 1) << 6;
    const int wn = (wv & 1) << 6;

    const unsigned short* gA[4];
    const unsigned short* gB[4];
    int lw[4];
    #pragma unroll
    for (int c = 0; c < 4; ++c) {
        const int idx = c * 256 + tid;
        const int row = idx >> 3;       // 0..127
        const int kb  = idx & 7;        // global 16B block (8 bf16)
        const int sb  = kb ^ (row & 7); // swizzled LDS slot
        lw[c] = row * 64 + sb * 8;
        size_t arow;
        const int mm = m0 + row;
        if (TRANSA) {
            const int bq = mm >> 12, lq = mm & 4095;
            arow = ((size_t)bq << 12) + (size_t)(((lq & 63) << 6) + (lq >> 6));
        } else {
            arow = (size_t)mm;
        }
        gA[c] = A + arow * Kd + kb * 8;
        gB[c] = Wt + (size_t)(n0 + row) * Kd + kb * 8;
    }

    f32x4 acc[4][4];
    #pragma unroll
    for (int i = 0; i < 4; ++i)
        #pragma unroll
        for (int j = 0; j < 4; ++j) acc[i][j] = (f32x4){0.f, 0.f, 0.f, 0.f};

    const int NT = Kd >> 6;
    short8 pA[4], pB[4];
    #pragma unroll
    for (int c = 0; c < 4; ++c) {
        pA[c] = *(const short8*)(gA[c]);
        pB[c] = *(const short8*)(gB[c]);
    }
    for (int kt = 0; kt < NT; ++kt) {
        __syncthreads();
        #pragma unroll
        for (int c = 0; c < 4; ++c) {
            *(short8*)&Als[lw[c]] = pA[c];
            *(short8*)&Bls[lw[c]] = pB[c];
        }
        __syncthreads();
        if (kt + 1 < NT) {
            #pragma unroll
            for (int c = 0; c < 4; ++c) {
                pA[c] = *(const short8*)(gA[c] + (kt + 1) * 64);
                pB[c] = *(const short8*)(gB[c] + (kt + 1) * 64);
            }
        }
        #pragma unroll
        for (int ks = 0; ks < 2; ++ks) {
            short8 af[4], bfr[4];
            #pragma unroll
            for (int r = 0; r < 4; ++r) {
                const int rowa = wm + r * 16 + (lane & 15);
                const int rowb = wn + r * 16 + (lane & 15);
                const int kb = ks * 4 + (lane >> 4);
                af[r]  = *(const short8*)&Als[rowa * 64 + ((kb ^ (rowa & 7)) << 3)];
                bfr[r] = *(const short8*)&Bls[rowb * 64 + ((kb ^ (rowb & 7)) << 3)];
            }
            #pragma unroll
            for (int mr = 0; mr < 4; ++mr)
                #pragma unroll
                for (int nr = 0; nr < 4; ++nr)
                    acc[mr][nr] = __builtin_amdgcn_mfma_f32_16x16x32_bf16(af[mr], bfr[nr], acc[mr][nr], 0, 0, 0);
        }
    }
    #pragma unroll
    for (int mr = 0; mr < 4; ++mr) {
        #pragma unroll
        for (int nr = 0; nr < 4; ++nr) {
            const int n = n0 + wn + nr * 16 + (lane & 15);
            if (n >= nmax) continue;
            const int mb = m0 + wm + mr * 16 + ((lane >> 4) << 2);
            #pragma unroll
            for (int q = 0; q < 4; ++q) {
                const size_t off = (size_t)(mb + q) * ldc + n;
                float v = acc[mr][nr][q];
                if (EPI == 0) { Cf[off] = v; }
                else if (EPI == 1) { v = silu_f(v + bias[n]); Cb[off] = f2bf(v); }
                else if (EPI == 2) { v += bias[n] + res[off]; Cf[off] = v; }
                else if (EPI == 3) { v += res[off]; Cf[off] = v; Cb[off] = f2bf(v); }
            }
        }
    }
}

// ---------------------------------------------------------------------------
// f32 -> bf16 converters (flat / row-padded with zeros)
// ---------------------------------------------------------------------------
__global__ __launch_bounds__(256)
void cvt_kernel(const float* __restrict__ src, unsigned short* __restrict__ dst, int n)
{
    const int i = blockIdx.x * 256 + threadIdx.x;
    if (i < n) dst[i] = f2bf(src[i]);
}

__global__ __launch_bounds__(256)
void cvt_pad_kernel(const float* __restrict__ src, unsigned short* __restrict__ dst,
                    int srcRows, int total, int cols)
{
    const int i = blockIdx.x * 256 + threadIdx.x;
    if (i >= total) return;
    const int r = i / cols;
    dst[i] = (r < srcRows) ? f2bf(src[i]) : (unsigned short)0;
}

// ---------------------------------------------------------------------------
// Depthwise 3x3 conv + bias + SiLU.  xl (B,L,384) -> xc f32 + xc_bf bf16
// ---------------------------------------------------------------------------
__global__ __launch_bounds__(256)
void conv_dw_kernel(const float* __restrict__ xl, const float* __restrict__ cw,
                    const float* __restrict__ cb, float* __restrict__ xc,
                    unsigned short* __restrict__ xcbf)
{
    const size_t e = (size_t)blockIdx.x * 256 + threadIdx.x;
    if (e >= (size_t)BB * LL * INNER) return;
    const int d = (int)(e % INNER);
    const size_t m = e / INNER;
    const int b = (int)(m >> 12);
    const int r = (int)(m & 4095);
    const int i = r >> 6;
    const int j = r & 63;
    const float* wd = cw + d * 9;
    float s = 0.f;
    #pragma unroll
    for (int di = 0; di < 3; ++di) {
        const int ii = i + di - 1;
        if (ii < 0 || ii >= HH) continue;
        #pragma unroll
        for (int dj = 0; dj < 3; ++dj) {
            const int jj = j + dj - 1;
            if (jj < 0 || jj >= WW) continue;
            s = fmaf(xl[(((size_t)b << 12) + (size_t)(ii * 64 + jj)) * INNER + d], wd[di*3+dj], s);
        }
    }
    s += cb[d];
    const float v = silu_f(s);
    xc[e] = v;
    xcbf[e] = f2bf(v);
}

// ---------------------------------------------------------------------------
// dtv = softplus(dt_raw + dt_bias[h]); cums = per-chunk inclusive prefix sum of
// dtA = -exp(A_logs[h]) * dtv.   One wave per (b,h,chunk); lane = position.
// ---------------------------------------------------------------------------
__global__ __launch_bounds__(256)
void dtcums_kernel(const float* __restrict__ BCdt, const float* __restrict__ dt_bias,
                   const float* __restrict__ A_logs,
                   float* __restrict__ dtv, float* __restrict__ cums)
{
    const int w = blockIdx.x * 4 + (threadIdx.x >> 6);
    const int lane = threadIdx.x & 63;
    const int b = w / (NHEADS * NC);
    const int rem = w - b * (NHEADS * NC);
    const int h = rem / NC;
    const int c = rem - h * NC;
    const int k = h / NHK;
    const int hq = h - k * NHK;
    const int l = c * QC + lane;
    const float dtraw = BCdt[(((size_t)b * LL + l) * 2 + k) * CPROJ + 2*NSTATE + hq];
    const float xx = dtraw + dt_bias[h];
    const float sp = (xx > 20.f) ? xx : log1pf(expf(xx));
    float s = -expf(A_logs[h]) * sp;
    #pragma unroll
    for (int d = 1; d < 64; d <<= 1) {
        const float o = __shfl_up(s, d);
        if (lane >= d) s += o;
    }
    dtv[((size_t)b * LL + l) * NHEADS + h] = sp;
    cums[((size_t)b * LL + l) * NHEADS + h] = s;
}

// ---------------------------------------------------------------------------
// Chunk states: S_c[p,n] = sum_m dt[m]*exp(cu[63]-cu[m]) * x[m][p] * B[m][n]
// ---------------------------------------------------------------------------
__global__ __launch_bounds__(256)
void chunk_state_kernel(const float* __restrict__ xc, const float* __restrict__ BCdt,
                        const float* __restrict__ dtv, const float* __restrict__ cums,
                        float* __restrict__ SH)
{
    __shared__ float Xs[QC][64];
    __shared__ float Bs[QC][33];
    __shared__ float cuS[QC];
    __shared__ float rs[QC];
    const int c = blockIdx.x, h = blockIdx.y, b = blockIdx.z;
    const int k = h / NHK;
    const int dch0 = (h - k * NHK) * PDIM;
    const int tid = threadIdx.x;
    #pragma unroll
    for (int r = 0; r < 16; ++r) {
        const int idx = tid + r * 256;
        const int i = idx >> 6, p = idx & 63;
        const int pos = (k == 0) ? (c * QC + i) : (i * QC + c);
        Xs[i][p] = xc[(((size_t)b << 12) + pos) * INNER + dch0 + p];
    }
    #pragma unroll
    for (int r = 0; r < 8; ++r) {
        const int idx = tid + r * 256;
        const int i = idx >> 5, n = idx & 31;
        Bs[i][n] = BCdt[(((size_t)b * LL + c * QC + i) * 2 + k) * CPROJ + n];
    }
    if (tid < QC)
        cuS[tid] = cums[((size_t)b * LL + c * QC + tid) * NHEADS + h];
    __syncthreads();
    if (tid < QC)
        rs[tid] = dtv[((size_t)b * LL + c * QC + tid) * NHEADS + h] * __expf(cuS[QC-1] - cuS[tid]);
    __syncthreads();
    const int p = tid & 63;
    const int n0 = (tid >> 6) * 8;
    float s[8] = {0.f,0.f,0.f,0.f,0.f,0.f,0.f,0.f};
    #pragma unroll 8
    for (int m = 0; m < QC; ++m) {
        const float rx = rs[m] * Xs[m][p];
        #pragma unroll
        for (int j = 0; j < 8; ++j) s[j] = fmaf(rx, Bs[m][n0 + j], s[j]);
    }
    float* dst = SH + ((((size_t)b * NHEADS + h) * NC + c) * PDIM + p) * NSTATE + n0;
    *(float4*)(dst)     = make_float4(s[0], s[1], s[2], s[3]);
    *(float4*)(dst + 4) = make_float4(s[4], s[5], s[6], s[7]);
}

// ---------------------------------------------------------------------------
// Sequential scan over chunks (in place).
// ---------------------------------------------------------------------------
__global__ __launch_bounds__(256)
void state_scan_kernel(float* __restrict__ SH, const float* __restrict__ cums,
                       const float* __restrict__ init_states)
{
    __shared__ float decays[NC];
    const int b = blockIdx.x / NHEADS;
    const int h = blockIdx.x % NHEADS;
    const int tid = threadIdx.x;
    if (tid < NC)
        decays[tid] = __expf(cums[((size_t)b * LL + tid * QC + QC - 1) * NHEADS + h]);
    __syncthreads();
    const int p = tid >> 2;
    const int nb = (tid & 3) * 8;
    float hs[8];
    {
        const float* is = init_states + ((size_t)h * PDIM + p) * NSTATE + nb;
        #pragma unroll
        for (int i = 0; i < 8; ++i) hs[i] = is[i];
    }
    float* base = SH + (((size_t)b * NHEADS + h) * NC) * (PDIM * NSTATE) + p * NSTATE + nb;
    for (int c = 0; c < NC; ++c) {
        float* slot = base + (size_t)c * (PDIM * NSTATE);
        float4 s0 = *(float4*)(slot);
        float4 s1 = *(float4*)(slot + 4);
        *(float4*)(slot)     = make_float4(hs[0], hs[1], hs[2], hs[3]);
        *(float4*)(slot + 4) = make_float4(hs[4], hs[5], hs[6], hs[7]);
        const float dc = decays[c];
        hs[0] = fmaf(dc, hs[0], s0.x); hs[1] = fmaf(dc, hs[1], s0.y);
        hs[2] = fmaf(dc, hs[2], s0.z); hs[3] = fmaf(dc, hs[3], s0.w);
        hs[4] = fmaf(dc, hs[4], s1.x); hs[5] = fmaf(dc, hs[5], s1.y);
        hs[6] = fmaf(dc, hs[6], s1.z); hs[7] = fmaf(dc, hs[7], s1.w);
    }
}

// ---------------------------------------------------------------------------
// Intra-chunk + inter-chunk + D term.
// ---------------------------------------------------------------------------
__global__ __launch_bounds__(256)
void intra_kernel(const float* __restrict__ xc, const float* __restrict__ BCdt,
                  const float* __restrict__ dtv, const float* __restrict__ cums,
                  const float* __restrict__ SH, const float* __restrict__ Ds,
                  float* __restrict__ ysum)
{
    __shared__ float Xs[QC][64];
    __shared__ float Bs[QC][33];
    __shared__ float Cs[QC][33];
    __shared__ float Hs[PDIM][33];
    __shared__ float Gs[QC][65];
    __shared__ float cuS[QC], dtS[QC], Ei[QC];
    const int c = blockIdx.x, h = blockIdx.y, b = blockIdx.z;
    const int k = h / NHK;
    const int dch0 = (h - k * NHK) * PDIM;
    const int tid = threadIdx.x;
    #pragma unroll
    for (int r = 0; r < 16; ++r) {
        const int idx = tid + r * 256;
        const int i = idx >> 6, p = idx & 63;
        const int pos = (k == 0) ? (c * QC + i) : (i * QC + c);
        Xs[i][p] = xc[(((size_t)b << 12) + pos) * INNER + dch0 + p];
    }
    #pragma unroll
    for (int r = 0; r < 16; ++r) {
        const int idx = tid + r * 256;
        const int i = idx >> 6, q = idx & 63;
        const float v = BCdt[(((size_t)b * LL + c * QC + i) * 2 + k) * CPROJ + q];
        if (q < NSTATE) Bs[i][q] = v; else Cs[i][q - NSTATE] = v;
    }
    #pragma unroll
    for (int r = 0; r < 8; ++r) {
        const int idx = tid + r * 256;
        const int p = idx >> 5, n = idx & 31;
        Hs[p][n] = SH[((((size_t)b * NHEADS + h) * NC + c) * PDIM + p) * NSTATE + n];
    }
    if (tid < QC) {
        const size_t o = ((size_t)b * LL + c * QC + tid) * NHEADS + h;
        const float cu = cums[o];
        cuS[tid] = cu;
        dtS[tid] = dtv[o];
        Ei[tid]  = __expf(cu);
    }
    __syncthreads();
    {
        const int m = tid & 63;
        const int ig = tid >> 6;
        #pragma unroll
        for (int ii = 0; ii < 16; ++ii) {
            const int i = ig * 16 + ii;
            float acc = 0.f;
            #pragma unroll
            for (int n = 0; n < NSTATE; ++n) acc = fmaf(Cs[i][n], Bs[m][n], acc);
            float wexp = fminf(cuS[i] - cuS[m], 0.f);
            Gs[i][m] = (m <= i) ? __expf(wexp) * dtS[m] * acc : 0.f;
        }
    }
    __syncthreads();
    const float Dh = Ds[h];
    const int p = tid & 63;
    const int ig = tid >> 6;
    #pragma unroll
    for (int ii = 0; ii < 16; ++ii) {
        const int i = ig * 16 + ii;
        float acc = Dh * Xs[i][p];
        float accI = 0.f;
        #pragma unroll
        for (int n = 0; n < NSTATE; ++n) accI = fmaf(Cs[i][n], Hs[p][n], accI);
        acc = fmaf(Ei[i], accI, acc);
        #pragma unroll 16
        for (int m = 0; m < QC; ++m) acc = fmaf(Gs[i][m], Xs[m][p], acc);
        const int pos = (k == 0) ? (c * QC + i) : (i * QC + c);
        atomicAdd(&ysum[(((size_t)b << 12) + pos) * INNER + dch0 + p], acc);
    }
}

// ---------------------------------------------------------------------------
// gate: yg_bf = bf16( ysum * silu(z) )
// ---------------------------------------------------------------------------
__global__ __launch_bounds__(256)
void gate_kernel(const float* __restrict__ ysum, const float* __restrict__ z,
                 unsigned short* __restrict__ ygbf)
{
    const size_t e = (size_t)blockIdx.x * 256 + threadIdx.x;
    if (e >= (size_t)BB * LL * INNER) return;
    ygbf[e] = f2bf(ysum[e] * silu_f(z[e]));
}

__global__ __launch_bounds__(256)
void report_ws_kernel(float* __restrict__ out, int n, float val)
{
    const int e = blockIdx.x * 256 + threadIdx.x;
    if (e < n) out[e] = val;
}

// ---------------------------------------------------------------------------
extern "C" void kernel_launch(void* const* d_in, const int* in_sizes, int n_in,
                              void* d_out, int out_size, void* d_ws, size_t ws_size,
                              hipStream_t stream)
{
    const float* x          = (const float*)d_in[0];
    const float* W_in       = (const float*)d_in[1];
    const float* conv_w     = (const float*)d_in[2];
    const float* conv_b     = (const float*)d_in[3];
    const float* xpw        = (const float*)d_in[4];
    const float* A_logs     = (const float*)d_in[5];
    const float* Ds         = (const float*)d_in[6];
    const float* dt_bias    = (const float*)d_in[7];
    const float* init_states= (const float*)d_in[8];
    const float* W_out      = (const float*)d_in[9];
    const float* W1         = (const float*)d_in[10];
    const float* b1         = (const float*)d_in[11];
    const float* W2         = (const float*)d_in[12];
    const float* b2         = (const float*)d_in[13];
    float* out = (float*)d_out;

    if (ws_size < (size_t)WS_REQ) {
        const float mib = (float)((double)ws_size / 1048576.0);
        report_ws_kernel<<<(out_size + 255) / 256, 256, 0, stream>>>(out, out_size, mib);
        return;
    }

    char* ws = (char*)d_ws;
    float* xl    = (float*)(ws + WS_XL);
    float* xc    = (float*)(ws + WS_XC);
    float* BCdt  = (float*)(ws + WS_BCDT);
    float* dtv   = (float*)(ws + WS_DTV);
    float* cums  = (float*)(ws + WS_CUMS);
    float* ysum  = (float*)(ws + WS_YSUM);
    unsigned short* x_bf   = (unsigned short*)(ws + WS_XBF);
    unsigned short* Winb   = (unsigned short*)(ws + WS_WINB);
    unsigned short* wpadb  = (unsigned short*)(ws + WS_WPADB);
    unsigned short* Woutb  = (unsigned short*)(ws + WS_WOUTB);
    unsigned short* W1b    = (unsigned short*)(ws + WS_W1B);
    unsigned short* W2b    = (unsigned short*)(ws + WS_W2B);
    unsigned short* xc_bf  = (unsigned short*)(ws + WS_YSUM);   // overlay: dead at memset
    unsigned short* yg_bf  = (unsigned short*)(ws + WS_XC);     // overlay: xc dead after intra
    unsigned short* out_bf = (unsigned short*)(ws + WS_BCDT);   // overlay: BCdt dead after intra
    unsigned short* h1_bf  = (unsigned short*)(ws + WS_XL);     // overlay: z dead after gate
    float* SH = xl;     // overlay: xl dead after conv; SH dead after intra
    float* z  = xl;     // overlay: written after intra

    const int M = BB * LL;  // 32768

    // 0) bf16 conversions (weights + x)
    cvt_kernel<<<(M * CIN + 255) / 256, 256, 0, stream>>>(x, x_bf, M * CIN);
    cvt_kernel<<<(HID * CIN + 255) / 256, 256, 0, stream>>>(W_in, Winb, HID * CIN);
    cvt_kernel<<<(HID * CIN + 255) / 256, 256, 0, stream>>>(W1, W1b, HID * CIN);
    cvt_pad_kernel<<<(128 * INNER + 255) / 256, 256, 0, stream>>>(xpw, wpadb, CPROJ, 128 * INNER, INNER);
    cvt_pad_kernel<<<(128 * INNER + 255) / 256, 256, 0, stream>>>(xpw + CPROJ * INNER, wpadb + 128 * INNER, CPROJ, 128 * INNER, INNER);
    cvt_pad_kernel<<<(256 * INNER + 255) / 256, 256, 0, stream>>>(W_out, Woutb, CIN, 256 * INNER, INNER);
    cvt_pad_kernel<<<(256 * HID + 255) / 256, 256, 0, stream>>>(W2, W2b, CIN, 256 * HID, HID);

    // 1) xl = x @ W_in[0:384]^T   (bf16 MFMA)
    gemm_bf16<0,0><<<dim3(M/128, INNER/128), 256, 0, stream>>>(x_bf, Winb, nullptr, nullptr, xl, nullptr, CIN, INNER, INNER);

    // 2) depthwise conv + bias + SiLU -> xc f32 + xc_bf
    conv_dw_kernel<<<(M * INNER) / 256, 256, 0, stream>>>(xl, conv_w, conv_b, xc, xc_bf);

    // 3) BCdt projection as two bf16 GEMMs (N=128 padded, interleaved output)
    gemm_bf16<0,0><<<dim3(M/128, 1), 256, 0, stream>>>(xc_bf, wpadb, nullptr, nullptr, BCdt, nullptr, INNER, 2*CPROJ, CPROJ);
    gemm_bf16<0,1><<<dim3(M/128, 1), 256, 0, stream>>>(xc_bf, wpadb + 128 * INNER, nullptr, nullptr, BCdt + CPROJ, nullptr, INNER, 2*CPROJ, CPROJ);

    // 3b) dt softplus + per-chunk cumsum
    dtcums_kernel<<<(BB * NHEADS * NC) / 4, 256, 0, stream>>>(BCdt, dt_bias, A_logs, dtv, cums);

    // 4) chunked scan (fp32)
    chunk_state_kernel<<<dim3(NC, NHEADS, BB), 256, 0, stream>>>(xc, BCdt, dtv, cums, SH);
    state_scan_kernel<<<BB * NHEADS, 256, 0, stream>>>(SH, cums, init_states);
    hipMemsetAsync(ysum, 0, (size_t)M * INNER * sizeof(float), stream);   // xc_bf dead
    intra_kernel<<<dim3(NC, NHEADS, BB), 256, 0, stream>>>(xc, BCdt, dtv, cums, SH, Ds, ysum);

    // 5) z = x @ W_in[384:768]^T  (SH dead now; z overlays xl)
    gemm_bf16<0,0><<<dim3(M/128, INNER/128), 256, 0, stream>>>(x_bf, Winb + (size_t)INNER * CIN, nullptr, nullptr, z, nullptr, CIN, INNER, INNER);
    gate_kernel<<<(M * INNER) / 256, 256, 0, stream>>>(ysum, z, yg_bf);

    // 5b) out = x + yg @ W_out^T   (dual write: f32 out + bf16 out_bf)
    gemm_bf16<3,0><<<dim3(M/128, 2), 256, 0, stream>>>(yg_bf, Woutb, nullptr, x, out, out_bf, INNER, CIN, CIN);

    // 6) MLP: h1_bf = bf16(silu(out @ W1^T + b1));  out += h1 @ W2^T + b2
    gemm_bf16<1,0><<<dim3(M/128, HID/128), 256, 0, stream>>>(out_bf, W1b, b1, nullptr, nullptr, h1_bf, CIN, HID, HID);
    gemm_bf16<2,0><<<dim3(M/128, 2), 256, 0, stream>>>(h1_bf, W2b, b2, out, out, nullptr, HID, CIN, CIN);
}

// Round 7
// 454.079 us; speedup vs baseline: 7.1056x; 1.4700x over previous
//
#include <hip/hip_runtime.h>
#include <math.h>

#define BB 8
#define HH 64
#define WW 64
#define CIN 192
#define INNER 384
#define LL 4096          // HH*WW
#define NSTATE 32
#define PDIM 64
#define NHK 6            // INNER/PDIM
#define NHEADS 12        // 2*NHK
#define HID 768
#define CPROJ 70         // 2*NSTATE + NHK
#define QC 64            // chunk length
#define NC 64            // LL/QC chunks

// workspace layout (bytes)
#define WS_XL    0u                   // (B,L,384) f32 50331648 ; SH overlay; z overlay; h1_bf overlay
#define WS_XC    50331648u            // (B,L,384) f32 50331648 ; yg_bf overlay after intra
#define WS_BCDT  100663296u           // (B,L,2,70) f32 18350080 ; out_bf overlay after intra
#define WS_DTV   119013376u           // (B,L,12) f32 1572864
#define WS_CUMS  120586240u           // (B,L,12) f32 1572864
#define WS_YSUM  122159104u           // (B,L,384) f32 50331648 ; xc_bf overlay pre-memset
#define WS_XBF   172490752u           // (M,192) bf16 12582912
#define WS_WINB  185073664u           // W_in bf16 768x192      294912
#define WS_WPADB 185368576u           // xpw padded bf16 2x128x384 196608
#define WS_WOUTB 185565184u           // W_out padded bf16 256x384 196608
#define WS_W1B   185761792u           // W1 bf16 768x192        294912
#define WS_W2B   186056704u           // W2 padded bf16 256x768 393216
#define WS_REQ   186449920u

typedef __attribute__((ext_vector_type(8))) short short8;
typedef __attribute__((ext_vector_type(4))) float f32x4;

__device__ __forceinline__ float silu_f(float x) { return x / (1.f + __expf(-x)); }

__device__ __forceinline__ unsigned short f2bf(float f) {
    unsigned u = __float_as_uint(f);
    u += 0x7fffu + ((u >> 16) & 1u);
    return (unsigned short)(u >> 16);
}
__device__ __forceinline__ float bf2f(unsigned short u) {
    return __uint_as_float(((unsigned)u) << 16);
}

// ---------------------------------------------------------------------------
// bf16 MFMA GEMM: C[m,n] = sum_k A[m,k]*Wt[n,k].  A,Wt bf16; acc f32.
// 128x128 tile, BK=64, 4 waves x (64x64), mfma_f32_16x16x32_bf16.
// ---------------------------------------------------------------------------
template<int EPI, int TRANSA>
__global__ __launch_bounds__(256)
void gemm_bf16(const unsigned short* __restrict__ A, const unsigned short* __restrict__ Wt,
               const float* __restrict__ bias, const float* __restrict__ res,
               float* __restrict__ Cf, unsigned short* __restrict__ Cb,
               int Kd, int ldc, int nmax)
{
    __shared__ __align__(16) short Als[128 * 64];
    __shared__ __align__(16) short Bls[128 * 64];
    const int tid = threadIdx.x;
    const int m0 = blockIdx.x * 128;
    const int n0 = blockIdx.y * 128;
    const int lane = tid & 63;
    const int wv = tid >> 6;
    const int wm = (wv >> 1) << 6;
    const int wn = (wv & 1) << 6;

    const unsigned short* gA[4];
    const unsigned short* gB[4];
    int lw[4];
    #pragma unroll
    for (int c = 0; c < 4; ++c) {
        const int idx = c * 256 + tid;
        const int row = idx >> 3;
        const int kb  = idx & 7;
        const int sb  = kb ^ (row & 7);
        lw[c] = row * 64 + sb * 8;
        size_t arow;
        const int mm = m0 + row;
        if (TRANSA) {
            const int bq = mm >> 12, lq = mm & 4095;
            arow = ((size_t)bq << 12) + (size_t)(((lq & 63) << 6) + (lq >> 6));
        } else {
            arow = (size_t)mm;
        }
        gA[c] = A + arow * Kd + kb * 8;
        gB[c] = Wt + (size_t)(n0 + row) * Kd + kb * 8;
    }

    f32x4 acc[4][4];
    #pragma unroll
    for (int i = 0; i < 4; ++i)
        #pragma unroll
        for (int j = 0; j < 4; ++j) acc[i][j] = (f32x4){0.f, 0.f, 0.f, 0.f};

    const int NT = Kd >> 6;
    short8 pA[4], pB[4];
    #pragma unroll
    for (int c = 0; c < 4; ++c) {
        pA[c] = *(const short8*)(gA[c]);
        pB[c] = *(const short8*)(gB[c]);
    }
    for (int kt = 0; kt < NT; ++kt) {
        __syncthreads();
        #pragma unroll
        for (int c = 0; c < 4; ++c) {
            *(short8*)&Als[lw[c]] = pA[c];
            *(short8*)&Bls[lw[c]] = pB[c];
        }
        __syncthreads();
        if (kt + 1 < NT) {
            #pragma unroll
            for (int c = 0; c < 4; ++c) {
                pA[c] = *(const short8*)(gA[c] + (kt + 1) * 64);
                pB[c] = *(const short8*)(gB[c] + (kt + 1) * 64);
            }
        }
        #pragma unroll
        for (int ks = 0; ks < 2; ++ks) {
            short8 af[4], bfr[4];
            #pragma unroll
            for (int r = 0; r < 4; ++r) {
                const int rowa = wm + r * 16 + (lane & 15);
                const int rowb = wn + r * 16 + (lane & 15);
                const int kb = ks * 4 + (lane >> 4);
                af[r]  = *(const short8*)&Als[rowa * 64 + ((kb ^ (rowa & 7)) << 3)];
                bfr[r] = *(const short8*)&Bls[rowb * 64 + ((kb ^ (rowb & 7)) << 3)];
            }
            #pragma unroll
            for (int mr = 0; mr < 4; ++mr)
                #pragma unroll
                for (int nr = 0; nr < 4; ++nr)
                    acc[mr][nr] = __builtin_amdgcn_mfma_f32_16x16x32_bf16(af[mr], bfr[nr], acc[mr][nr], 0, 0, 0);
        }
    }
    #pragma unroll
    for (int mr = 0; mr < 4; ++mr) {
        #pragma unroll
        for (int nr = 0; nr < 4; ++nr) {
            const int n = n0 + wn + nr * 16 + (lane & 15);
            if (n >= nmax) continue;
            const int mb = m0 + wm + mr * 16 + ((lane >> 4) << 2);
            #pragma unroll
            for (int q = 0; q < 4; ++q) {
                const size_t off = (size_t)(mb + q) * ldc + n;
                float v = acc[mr][nr][q];
                if (EPI == 0) { Cf[off] = v; }
                else if (EPI == 1) { v = silu_f(v + bias[n]); Cb[off] = f2bf(v); }
                else if (EPI == 2) { v += bias[n] + res[off]; Cf[off] = v; }
                else if (EPI == 3) { v += res[off]; Cf[off] = v; Cb[off] = f2bf(v); }
            }
        }
    }
}

// ---------------------------------------------------------------------------
// f32 -> bf16 converters (flat / row-padded with zeros)
// ---------------------------------------------------------------------------
__global__ __launch_bounds__(256)
void cvt_kernel(const float* __restrict__ src, unsigned short* __restrict__ dst, int n)
{
    const int i = blockIdx.x * 256 + threadIdx.x;
    if (i < n) dst[i] = f2bf(src[i]);
}

__global__ __launch_bounds__(256)
void cvt_pad_kernel(const float* __restrict__ src, unsigned short* __restrict__ dst,
                    int srcRows, int total, int cols)
{
    const int i = blockIdx.x * 256 + threadIdx.x;
    if (i >= total) return;
    const int r = i / cols;
    dst[i] = (r < srcRows) ? f2bf(src[i]) : (unsigned short)0;
}

// ---------------------------------------------------------------------------
// Depthwise 3x3 conv + bias + SiLU.  xl (B,L,384) -> xc f32 + xc_bf bf16
// ---------------------------------------------------------------------------
__global__ __launch_bounds__(256)
void conv_dw_kernel(const float* __restrict__ xl, const float* __restrict__ cw,
                    const float* __restrict__ cb, float* __restrict__ xc,
                    unsigned short* __restrict__ xcbf)
{
    const size_t e = (size_t)blockIdx.x * 256 + threadIdx.x;
    if (e >= (size_t)BB * LL * INNER) return;
    const int d = (int)(e % INNER);
    const size_t m = e / INNER;
    const int b = (int)(m >> 12);
    const int r = (int)(m & 4095);
    const int i = r >> 6;
    const int j = r & 63;
    const float* wd = cw + d * 9;
    float s = 0.f;
    #pragma unroll
    for (int di = 0; di < 3; ++di) {
        const int ii = i + di - 1;
        if (ii < 0 || ii >= HH) continue;
        #pragma unroll
        for (int dj = 0; dj < 3; ++dj) {
            const int jj = j + dj - 1;
            if (jj < 0 || jj >= WW) continue;
            s = fmaf(xl[(((size_t)b << 12) + (size_t)(ii * 64 + jj)) * INNER + d], wd[di*3+dj], s);
        }
    }
    s += cb[d];
    const float v = silu_f(s);
    xc[e] = v;
    xcbf[e] = f2bf(v);
}

// ---------------------------------------------------------------------------
// dtv = softplus(dt_raw + dt_bias[h]); cums = per-chunk inclusive prefix sum
// ---------------------------------------------------------------------------
__global__ __launch_bounds__(256)
void dtcums_kernel(const float* __restrict__ BCdt, const float* __restrict__ dt_bias,
                   const float* __restrict__ A_logs,
                   float* __restrict__ dtv, float* __restrict__ cums)
{
    const int w = blockIdx.x * 4 + (threadIdx.x >> 6);
    const int lane = threadIdx.x & 63;
    const int b = w / (NHEADS * NC);
    const int rem = w - b * (NHEADS * NC);
    const int h = rem / NC;
    const int c = rem - h * NC;
    const int k = h / NHK;
    const int hq = h - k * NHK;
    const int l = c * QC + lane;
    const float dtraw = BCdt[(((size_t)b * LL + l) * 2 + k) * CPROJ + 2*NSTATE + hq];
    const float xx = dtraw + dt_bias[h];
    const float sp = (xx > 20.f) ? xx : log1pf(expf(xx));
    float s = -expf(A_logs[h]) * sp;
    #pragma unroll
    for (int d = 1; d < 64; d <<= 1) {
        const float o = __shfl_up(s, d);
        if (lane >= d) s += o;
    }
    dtv[((size_t)b * LL + l) * NHEADS + h] = sp;
    cums[((size_t)b * LL + l) * NHEADS + h] = s;
}

// ---------------------------------------------------------------------------
// Chunk states: S_c[p,n] = sum_m dt[m]*exp(cu[63]-cu[m]) * x[m][p] * B[m][n]
// ---------------------------------------------------------------------------
__global__ __launch_bounds__(256)
void chunk_state_kernel(const float* __restrict__ xc, const float* __restrict__ BCdt,
                        const float* __restrict__ dtv, const float* __restrict__ cums,
                        float* __restrict__ SH)
{
    __shared__ float Xs[QC][64];
    __shared__ float Bs[QC][33];
    __shared__ float cuS[QC];
    __shared__ float rs[QC];
    const int c = blockIdx.x, h = blockIdx.y, b = blockIdx.z;
    const int k = h / NHK;
    const int dch0 = (h - k * NHK) * PDIM;
    const int tid = threadIdx.x;
    #pragma unroll
    for (int r = 0; r < 16; ++r) {
        const int idx = tid + r * 256;
        const int i = idx >> 6, p = idx & 63;
        const int pos = (k == 0) ? (c * QC + i) : (i * QC + c);
        Xs[i][p] = xc[(((size_t)b << 12) + pos) * INNER + dch0 + p];
    }
    #pragma unroll
    for (int r = 0; r < 8; ++r) {
        const int idx = tid + r * 256;
        const int i = idx >> 5, n = idx & 31;
        Bs[i][n] = BCdt[(((size_t)b * LL + c * QC + i) * 2 + k) * CPROJ + n];
    }
    if (tid < QC)
        cuS[tid] = cums[((size_t)b * LL + c * QC + tid) * NHEADS + h];
    __syncthreads();
    if (tid < QC)
        rs[tid] = dtv[((size_t)b * LL + c * QC + tid) * NHEADS + h] * __expf(cuS[QC-1] - cuS[tid]);
    __syncthreads();
    const int p = tid & 63;
    const int n0 = (tid >> 6) * 8;
    float s[8] = {0.f,0.f,0.f,0.f,0.f,0.f,0.f,0.f};
    #pragma unroll 8
    for (int m = 0; m < QC; ++m) {
        const float rx = rs[m] * Xs[m][p];
        #pragma unroll
        for (int j = 0; j < 8; ++j) s[j] = fmaf(rx, Bs[m][n0 + j], s[j]);
    }
    float* dst = SH + ((((size_t)b * NHEADS + h) * NC + c) * PDIM + p) * NSTATE + n0;
    *(float4*)(dst)     = make_float4(s[0], s[1], s[2], s[3]);
    *(float4*)(dst + 4) = make_float4(s[4], s[5], s[6], s[7]);
}

// ---------------------------------------------------------------------------
// Sequential scan over chunks (in place).
// ---------------------------------------------------------------------------
__global__ __launch_bounds__(256)
void state_scan_kernel(float* __restrict__ SH, const float* __restrict__ cums,
                       const float* __restrict__ init_states)
{
    __shared__ float decays[NC];
    const int b = blockIdx.x / NHEADS;
    const int h = blockIdx.x % NHEADS;
    const int tid = threadIdx.x;
    if (tid < NC)
        decays[tid] = __expf(cums[((size_t)b * LL + tid * QC + QC - 1) * NHEADS + h]);
    __syncthreads();
    const int p = tid >> 2;
    const int nb = (tid & 3) * 8;
    float hs[8];
    {
        const float* is = init_states + ((size_t)h * PDIM + p) * NSTATE + nb;
        #pragma unroll
        for (int i = 0; i < 8; ++i) hs[i] = is[i];
    }
    float* base = SH + (((size_t)b * NHEADS + h) * NC) * (PDIM * NSTATE) + p * NSTATE + nb;
    for (int c = 0; c < NC; ++c) {
        float* slot = base + (size_t)c * (PDIM * NSTATE);
        float4 s0 = *(float4*)(slot);
        float4 s1 = *(float4*)(slot + 4);
        *(float4*)(slot)     = make_float4(hs[0], hs[1], hs[2], hs[3]);
        *(float4*)(slot + 4) = make_float4(hs[4], hs[5], hs[6], hs[7]);
        const float dc = decays[c];
        hs[0] = fmaf(dc, hs[0], s0.x); hs[1] = fmaf(dc, hs[1], s0.y);
        hs[2] = fmaf(dc, hs[2], s0.z); hs[3] = fmaf(dc, hs[3], s0.w);
        hs[4] = fmaf(dc, hs[4], s1.x); hs[5] = fmaf(dc, hs[5], s1.y);
        hs[6] = fmaf(dc, hs[6], s1.z); hs[7] = fmaf(dc, hs[7], s1.w);
    }
}

// ---------------------------------------------------------------------------
// Intra-chunk + inter-chunk + D term via bf16 MFMA.  grid (NC, NHEADS, BB).
// Wave w owns output rows i in [16w,16w+16): G=C·B^T (4 mfma) -> mask/scale ->
// Gb; inter=C·H^T (4 mfma) -> acc = Ei[i]*acc + Dh*X; acc += G·X (8 mfma).
// Frag layouts identical to gemm_bf16 (verified): A/B row=lane&15, kblk=lane>>4;
// D col=lane&15, row=(lane>>4)*4+q.
// ---------------------------------------------------------------------------
__global__ __launch_bounds__(256)
void intra_kernel(const float* __restrict__ xc, const float* __restrict__ BCdt,
                  const float* __restrict__ dtv, const float* __restrict__ cums,
                  const float* __restrict__ SH, const float* __restrict__ Ds,
                  float* __restrict__ ysum)
{
    __shared__ __align__(16) unsigned short Bs[QC][32];    // [m][n]
    __shared__ __align__(16) unsigned short Cs[QC][32];    // [i][n]
    __shared__ __align__(16) unsigned short Hs[PDIM][32];  // [p][n]
    __shared__ __align__(16) unsigned short Xb[PDIM][72];  // [p][m]  (X^T)
    __shared__ __align__(16) unsigned short Gb[QC][72];    // [i][m]
    __shared__ float cuS[QC], dtS[QC], Ei[QC];
    const int c = blockIdx.x, h = blockIdx.y, b = blockIdx.z;
    const int k = h / NHK;
    const int dch0 = (h - k * NHK) * PDIM;
    const int tid = threadIdx.x;
    const int lane = tid & 63;
    const int w = tid >> 6;

    #pragma unroll
    for (int r = 0; r < 16; ++r) {
        const int idx = tid + r * 256;
        const int m = idx >> 6, p = idx & 63;
        const int pos = (k == 0) ? (c * QC + m) : (m * QC + c);
        Xb[p][m] = f2bf(xc[(((size_t)b << 12) + pos) * INNER + dch0 + p]);
    }
    #pragma unroll
    for (int r = 0; r < 16; ++r) {
        const int idx = tid + r * 256;
        const int i = idx >> 6, q = idx & 63;
        const float v = BCdt[(((size_t)b * LL + c * QC + i) * 2 + k) * CPROJ + q];
        if (q < NSTATE) Bs[i][q] = f2bf(v); else Cs[i][q - NSTATE] = f2bf(v);
    }
    #pragma unroll
    for (int r = 0; r < 8; ++r) {
        const int idx = tid + r * 256;
        const int p = idx >> 5, n = idx & 31;
        Hs[p][n] = f2bf(SH[((((size_t)b * NHEADS + h) * NC + c) * PDIM + p) * NSTATE + n]);
    }
    if (tid < QC) {
        const size_t o = ((size_t)b * LL + c * QC + tid) * NHEADS + h;
        const float cu = cums[o];
        cuS[tid] = cu;
        dtS[tid] = dtv[o];
        Ei[tid]  = __expf(cu);
    }
    __syncthreads();

    const int rowf = lane & 15;
    const int ko   = lane >> 4;
    const short8 cfrag = *(const short8*)&Cs[w * 16 + rowf][ko * 8];

    // matmul1: G_raw tiles (it=w, mt=0..3)
    f32x4 graw[4];
    #pragma unroll
    for (int mt = 0; mt < 4; ++mt) {
        const short8 bfrag = *(const short8*)&Bs[mt * 16 + rowf][ko * 8];
        graw[mt] = __builtin_amdgcn_mfma_f32_16x16x32_bf16(cfrag, bfrag, (f32x4){0.f,0.f,0.f,0.f}, 0, 0, 0);
    }
    // mask + scale + store Gb (wave w writes only rows 16w..16w+15)
    #pragma unroll
    for (int mt = 0; mt < 4; ++mt) {
        const int m = mt * 16 + rowf;
        const float cum = cuS[m];
        const float dtm = dtS[m];
        #pragma unroll
        for (int q = 0; q < 4; ++q) {
            const int i = w * 16 + ko * 4 + q;
            float g = 0.f;
            if (m <= i) g = __expf(fminf(cuS[i] - cum, 0.f)) * dtm * graw[mt][q];
            Gb[i][m] = f2bf(g);
        }
    }
    // matmul2: inter tiles (it=w, pt=0..3)
    f32x4 acc[4];
    #pragma unroll
    for (int pt = 0; pt < 4; ++pt) {
        const short8 hfrag = *(const short8*)&Hs[pt * 16 + rowf][ko * 8];
        acc[pt] = __builtin_amdgcn_mfma_f32_16x16x32_bf16(cfrag, hfrag, (f32x4){0.f,0.f,0.f,0.f}, 0, 0, 0);
    }
    const float Dh = Ds[h];
    #pragma unroll
    for (int pt = 0; pt < 4; ++pt) {
        const int p = pt * 16 + rowf;
        #pragma unroll
        for (int q = 0; q < 4; ++q) {
            const int i = w * 16 + ko * 4 + q;
            acc[pt][q] = acc[pt][q] * Ei[i] + Dh * bf2f(Xb[p][i]);
        }
    }
    // matmul3: acc += G·X  (wave w reads only its own Gb rows -> no barrier)
    #pragma unroll
    for (int ks = 0; ks < 2; ++ks) {
        const short8 gfrag = *(const short8*)&Gb[w * 16 + rowf][ks * 32 + ko * 8];
        #pragma unroll
        for (int pt = 0; pt < 4; ++pt) {
            const short8 xfrag = *(const short8*)&Xb[pt * 16 + rowf][ks * 32 + ko * 8];
            acc[pt] = __builtin_amdgcn_mfma_f32_16x16x32_bf16(gfrag, xfrag, acc[pt], 0, 0, 0);
        }
    }
    // epilogue
    #pragma unroll
    for (int pt = 0; pt < 4; ++pt) {
        const int p = pt * 16 + rowf;
        #pragma unroll
        for (int q = 0; q < 4; ++q) {
            const int i = w * 16 + ko * 4 + q;
            const int pos = (k == 0) ? (c * QC + i) : (i * QC + c);
            atomicAdd(&ysum[(((size_t)b << 12) + pos) * INNER + dch0 + p], acc[pt][q]);
        }
    }
}

// ---------------------------------------------------------------------------
// gate: yg_bf = bf16( ysum * silu(z) )
// ---------------------------------------------------------------------------
__global__ __launch_bounds__(256)
void gate_kernel(const float* __restrict__ ysum, const float* __restrict__ z,
                 unsigned short* __restrict__ ygbf)
{
    const size_t e = (size_t)blockIdx.x * 256 + threadIdx.x;
    if (e >= (size_t)BB * LL * INNER) return;
    ygbf[e] = f2bf(ysum[e] * silu_f(z[e]));
}

__global__ __launch_bounds__(256)
void report_ws_kernel(float* __restrict__ out, int n, float val)
{
    const int e = blockIdx.x * 256 + threadIdx.x;
    if (e < n) out[e] = val;
}

// ---------------------------------------------------------------------------
extern "C" void kernel_launch(void* const* d_in, const int* in_sizes, int n_in,
                              void* d_out, int out_size, void* d_ws, size_t ws_size,
                              hipStream_t stream)
{
    const float* x          = (const float*)d_in[0];
    const float* W_in       = (const float*)d_in[1];
    const float* conv_w     = (const float*)d_in[2];
    const float* conv_b     = (const float*)d_in[3];
    const float* xpw        = (const float*)d_in[4];
    const float* A_logs     = (const float*)d_in[5];
    const float* Ds         = (const float*)d_in[6];
    const float* dt_bias    = (const float*)d_in[7];
    const float* init_states= (const float*)d_in[8];
    const float* W_out      = (const float*)d_in[9];
    const float* W1         = (const float*)d_in[10];
    const float* b1         = (const float*)d_in[11];
    const float* W2         = (const float*)d_in[12];
    const float* b2         = (const float*)d_in[13];
    float* out = (float*)d_out;

    if (ws_size < (size_t)WS_REQ) {
        const float mib = (float)((double)ws_size / 1048576.0);
        report_ws_kernel<<<(out_size + 255) / 256, 256, 0, stream>>>(out, out_size, mib);
        return;
    }

    char* ws = (char*)d_ws;
    float* xl    = (float*)(ws + WS_XL);
    float* xc    = (float*)(ws + WS_XC);
    float* BCdt  = (float*)(ws + WS_BCDT);
    float* dtv   = (float*)(ws + WS_DTV);
    float* cums  = (float*)(ws + WS_CUMS);
    float* ysum  = (float*)(ws + WS_YSUM);
    unsigned short* x_bf   = (unsigned short*)(ws + WS_XBF);
    unsigned short* Winb   = (unsigned short*)(ws + WS_WINB);
    unsigned short* wpadb  = (unsigned short*)(ws + WS_WPADB);
    unsigned short* Woutb  = (unsigned short*)(ws + WS_WOUTB);
    unsigned short* W1b    = (unsigned short*)(ws + WS_W1B);
    unsigned short* W2b    = (unsigned short*)(ws + WS_W2B);
    unsigned short* xc_bf  = (unsigned short*)(ws + WS_YSUM);   // overlay: dead at memset
    unsigned short* yg_bf  = (unsigned short*)(ws + WS_XC);     // overlay: xc dead after intra
    unsigned short* out_bf = (unsigned short*)(ws + WS_BCDT);   // overlay: BCdt dead after intra
    unsigned short* h1_bf  = (unsigned short*)(ws + WS_XL);     // overlay: z dead after gate
    float* SH = xl;     // overlay: xl dead after conv; SH dead after intra
    float* z  = xl;     // overlay: written after intra

    const int M = BB * LL;  // 32768

    // 0) bf16 conversions (weights + x)
    cvt_kernel<<<(M * CIN + 255) / 256, 256, 0, stream>>>(x, x_bf, M * CIN);
    cvt_kernel<<<(HID * CIN + 255) / 256, 256, 0, stream>>>(W_in, Winb, HID * CIN);
    cvt_kernel<<<(HID * CIN + 255) / 256, 256, 0, stream>>>(W1, W1b, HID * CIN);
    cvt_pad_kernel<<<(128 * INNER + 255) / 256, 256, 0, stream>>>(xpw, wpadb, CPROJ, 128 * INNER, INNER);
    cvt_pad_kernel<<<(128 * INNER + 255) / 256, 256, 0, stream>>>(xpw + CPROJ * INNER, wpadb + 128 * INNER, CPROJ, 128 * INNER, INNER);
    cvt_pad_kernel<<<(256 * INNER + 255) / 256, 256, 0, stream>>>(W_out, Woutb, CIN, 256 * INNER, INNER);
    cvt_pad_kernel<<<(256 * HID + 255) / 256, 256, 0, stream>>>(W2, W2b, CIN, 256 * HID, HID);

    // 1) xl = x @ W_in[0:384]^T   (bf16 MFMA)
    gemm_bf16<0,0><<<dim3(M/128, INNER/128), 256, 0, stream>>>(x_bf, Winb, nullptr, nullptr, xl, nullptr, CIN, INNER, INNER);

    // 2) depthwise conv + bias + SiLU -> xc f32 + xc_bf
    conv_dw_kernel<<<(M * INNER) / 256, 256, 0, stream>>>(xl, conv_w, conv_b, xc, xc_bf);

    // 3) BCdt projection as two bf16 GEMMs (N=128 padded, interleaved output)
    gemm_bf16<0,0><<<dim3(M/128, 1), 256, 0, stream>>>(xc_bf, wpadb, nullptr, nullptr, BCdt, nullptr, INNER, 2*CPROJ, CPROJ);
    gemm_bf16<0,1><<<dim3(M/128, 1), 256, 0, stream>>>(xc_bf, wpadb + 128 * INNER, nullptr, nullptr, BCdt + CPROJ, nullptr, INNER, 2*CPROJ, CPROJ);

    // 3b) dt softplus + per-chunk cumsum
    dtcums_kernel<<<(BB * NHEADS * NC) / 4, 256, 0, stream>>>(BCdt, dt_bias, A_logs, dtv, cums);

    // 4) chunked scan
    chunk_state_kernel<<<dim3(NC, NHEADS, BB), 256, 0, stream>>>(xc, BCdt, dtv, cums, SH);
    state_scan_kernel<<<BB * NHEADS, 256, 0, stream>>>(SH, cums, init_states);
    hipMemsetAsync(ysum, 0, (size_t)M * INNER * sizeof(float), stream);   // xc_bf dead
    intra_kernel<<<dim3(NC, NHEADS, BB), 256, 0, stream>>>(xc, BCdt, dtv, cums, SH, Ds, ysum);

    // 5) z = x @ W_in[384:768]^T  (SH dead now; z overlays xl)
    gemm_bf16<0,0><<<dim3(M/128, INNER/128), 256, 0, stream>>>(x_bf, Winb + (size_t)INNER * CIN, nullptr, nullptr, z, nullptr, CIN, INNER, INNER);
    gate_kernel<<<(M * INNER) / 256, 256, 0, stream>>>(ysum, z, yg_bf);

    // 5b) out = x + yg @ W_out^T   (dual write: f32 out + bf16 out_bf)
    gemm_bf16<3,0><<<dim3(M/128, 2), 256, 0, stream>>>(yg_bf, Woutb, nullptr, x, out, out_bf, INNER, CIN, CIN);

    // 6) MLP: h1_bf = bf16(silu(out @ W1^T + b1));  out += h1 @ W2^T + b2
    gemm_bf16<1,0><<<dim3(M/128, HID/128), 256, 0, stream>>>(out_bf, W1b, b1, nullptr, nullptr, h1_bf, CIN, HID, HID);
    gemm_bf16<2,0><<<dim3(M/128, 2), 256, 0, stream>>>(h1_bf, W2b, b2, out, out, nullptr, HID, CIN, CIN);
}

// Round 9
// 387.132 us; speedup vs baseline: 8.3344x; 1.1729x over previous
//
#include <hip/hip_runtime.h>
#include <math.h>

#define BB 8
#define HH 64
#define WW 64
#define CIN 192
#define INNER 384
#define LL 4096          // HH*WW
#define NSTATE 32
#define PDIM 64
#define NHK 6            // INNER/PDIM
#define NHEADS 12        // 2*NHK
#define HID 768
#define CPROJ 70         // 2*NSTATE + NHK
#define QC 64            // chunk length
#define NC 64            // LL/QC chunks

// workspace layout (bytes) — offsets unchanged from the proven round-6 map
#define WS_XL    0u                   // bf16 xl (25MB); SHb (25.2MB) / z_bf / h1_bf (50MB) overlays
#define WS_XC    50331648u            // bf16 xc (25MB); yg_bf overlay after intra
#define WS_BCDT  100663296u           // (B,L,2,70) f32 18350080 ; out_bf overlay after intra
#define WS_DTV   119013376u           // (B,L,12) f32 1572864
#define WS_CUMS  120586240u           // (B,L,12) f32 1572864
#define WS_YSUM  122159104u           // (B,L,384) f32 50331648
#define WS_XBF   172490752u           // (M,192) bf16 12582912
#define WS_WINB  185073664u           // W_in bf16 768x192      294912
#define WS_WPADB 185368576u           // xpw padded bf16 2x128x384 196608
#define WS_WOUTB 185565184u           // W_out padded bf16 256x384 196608
#define WS_W1B   185761792u           // W1 bf16 768x192        294912
#define WS_W2B   186056704u           // W2 padded bf16 256x768 393216
#define WS_REQ   186449920u

typedef __attribute__((ext_vector_type(8))) short short8;
typedef __attribute__((ext_vector_type(4))) float f32x4;

__device__ __forceinline__ float silu_f(float x) { return x / (1.f + __expf(-x)); }

__device__ __forceinline__ unsigned short f2bf(float f) {
    unsigned u = __float_as_uint(f);
    u += 0x7fffu + ((u >> 16) & 1u);
    return (unsigned short)(u >> 16);
}
__device__ __forceinline__ float bf2f(unsigned short u) {
    return __uint_as_float(((unsigned)u) << 16);
}

// ---------------------------------------------------------------------------
// bf16 MFMA GEMM: C[m,n] = sum_k A[m,k]*Wt[n,k].  A,Wt bf16; acc f32.
// 128x128 tile, BK=64, 4 waves x (64x64), mfma_f32_16x16x32_bf16.
// EPI: 0 Cf=acc; 1 Cb=bf16(silu(acc+bias)); 2 Cf=acc+bias+res; 3 Cf=acc+res & Cb;
//      4 Cb=bf16(acc).
// ---------------------------------------------------------------------------
template<int EPI, int TRANSA>
__global__ __launch_bounds__(256)
void gemm_bf16(const unsigned short* __restrict__ A, const unsigned short* __restrict__ Wt,
               const float* __restrict__ bias, const float* __restrict__ res,
               float* __restrict__ Cf, unsigned short* __restrict__ Cb,
               int Kd, int ldc, int nmax)
{
    __shared__ __align__(16) short Als[128 * 64];
    __shared__ __align__(16) short Bls[128 * 64];
    const int tid = threadIdx.x;
    const int m0 = blockIdx.x * 128;
    const int n0 = blockIdx.y * 128;
    const int lane = tid & 63;
    const int wv = tid >> 6;
    const int wm = (wv >> 1) << 6;
    const int wn = (wv & 1) << 6;

    const unsigned short* gA[4];
    const unsigned short* gB[4];
    int lw[4];
    #pragma unroll
    for (int c = 0; c < 4; ++c) {
        const int idx = c * 256 + tid;
        const int row = idx >> 3;
        const int kb  = idx & 7;
        const int sb  = kb ^ (row & 7);
        lw[c] = row * 64 + sb * 8;
        size_t arow;
        const int mm = m0 + row;
        if (TRANSA) {
            const int bq = mm >> 12, lq = mm & 4095;
            arow = ((size_t)bq << 12) + (size_t)(((lq & 63) << 6) + (lq >> 6));
        } else {
            arow = (size_t)mm;
        }
        gA[c] = A + arow * Kd + kb * 8;
        gB[c] = Wt + (size_t)(n0 + row) * Kd + kb * 8;
    }

    f32x4 acc[4][4];
    #pragma unroll
    for (int i = 0; i < 4; ++i)
        #pragma unroll
        for (int j = 0; j < 4; ++j) acc[i][j] = (f32x4){0.f, 0.f, 0.f, 0.f};

    const int NT = Kd >> 6;
    short8 pA[4], pB[4];
    #pragma unroll
    for (int c = 0; c < 4; ++c) {
        pA[c] = *(const short8*)(gA[c]);
        pB[c] = *(const short8*)(gB[c]);
    }
    for (int kt = 0; kt < NT; ++kt) {
        __syncthreads();
        #pragma unroll
        for (int c = 0; c < 4; ++c) {
            *(short8*)&Als[lw[c]] = pA[c];
            *(short8*)&Bls[lw[c]] = pB[c];
        }
        __syncthreads();
        if (kt + 1 < NT) {
            #pragma unroll
            for (int c = 0; c < 4; ++c) {
                pA[c] = *(const short8*)(gA[c] + (kt + 1) * 64);
                pB[c] = *(const short8*)(gB[c] + (kt + 1) * 64);
            }
        }
        #pragma unroll
        for (int ks = 0; ks < 2; ++ks) {
            short8 af[4], bfr[4];
            #pragma unroll
            for (int r = 0; r < 4; ++r) {
                const int rowa = wm + r * 16 + (lane & 15);
                const int rowb = wn + r * 16 + (lane & 15);
                const int kb = ks * 4 + (lane >> 4);
                af[r]  = *(const short8*)&Als[rowa * 64 + ((kb ^ (rowa & 7)) << 3)];
                bfr[r] = *(const short8*)&Bls[rowb * 64 + ((kb ^ (rowb & 7)) << 3)];
            }
            #pragma unroll
            for (int mr = 0; mr < 4; ++mr)
                #pragma unroll
                for (int nr = 0; nr < 4; ++nr)
                    acc[mr][nr] = __builtin_amdgcn_mfma_f32_16x16x32_bf16(af[mr], bfr[nr], acc[mr][nr], 0, 0, 0);
        }
    }
    #pragma unroll
    for (int mr = 0; mr < 4; ++mr) {
        #pragma unroll
        for (int nr = 0; nr < 4; ++nr) {
            const int n = n0 + wn + nr * 16 + (lane & 15);
            if (n >= nmax) continue;
            const int mb = m0 + wm + mr * 16 + ((lane >> 4) << 2);
            #pragma unroll
            for (int q = 0; q < 4; ++q) {
                const size_t off = (size_t)(mb + q) * ldc + n;
                float v = acc[mr][nr][q];
                if (EPI == 0) { Cf[off] = v; }
                else if (EPI == 1) { v = silu_f(v + bias[n]); Cb[off] = f2bf(v); }
                else if (EPI == 2) { v += bias[n] + res[off]; Cf[off] = v; }
                else if (EPI == 3) { v += res[off]; Cf[off] = v; Cb[off] = f2bf(v); }
                else if (EPI == 4) { Cb[off] = f2bf(v); }
            }
        }
    }
}

// ---------------------------------------------------------------------------
// f32 -> bf16 converters (flat / row-padded with zeros)
// ---------------------------------------------------------------------------
__global__ __launch_bounds__(256)
void cvt_kernel(const float* __restrict__ src, unsigned short* __restrict__ dst, int n)
{
    const int i = blockIdx.x * 256 + threadIdx.x;
    if (i < n) dst[i] = f2bf(src[i]);
}

__global__ __launch_bounds__(256)
void cvt_pad_kernel(const float* __restrict__ src, unsigned short* __restrict__ dst,
                    int srcRows, int total, int cols)
{
    const int i = blockIdx.x * 256 + threadIdx.x;
    if (i >= total) return;
    const int r = i / cols;
    dst[i] = (r < srcRows) ? f2bf(src[i]) : (unsigned short)0;
}

// ---------------------------------------------------------------------------
// Depthwise 3x3 conv + bias + SiLU, 8 channels/thread, bf16 in/out.
// xl_bf (B,L,384) -> xc_bf (B,L,384)
// ---------------------------------------------------------------------------
__global__ __launch_bounds__(256)
void conv_dw_kernel(const unsigned short* __restrict__ xl, const float* __restrict__ cw,
                    const float* __restrict__ cb, unsigned short* __restrict__ xcbf)
{
    const int t = blockIdx.x * 256 + threadIdx.x;     // < M * 48
    const int dv = t % (INNER / 8);
    const int m  = t / (INNER / 8);
    const int b = m >> 12;
    const int r = m & 4095;
    const int i = r >> 6;
    const int j = r & 63;
    const int d0 = dv * 8;

    // preload 8 channels x 9 taps of weights (contiguous 72 floats)
    float wreg[72];
    {
        const float4* w4 = (const float4*)(cw + d0 * 9);
        #pragma unroll
        for (int u = 0; u < 18; ++u) {
            const float4 v = w4[u];
            wreg[4*u+0] = v.x; wreg[4*u+1] = v.y; wreg[4*u+2] = v.z; wreg[4*u+3] = v.w;
        }
    }
    float acc[8];
    {
        const float4 b0 = *(const float4*)(cb + d0);
        const float4 b1 = *(const float4*)(cb + d0 + 4);
        acc[0]=b0.x; acc[1]=b0.y; acc[2]=b0.z; acc[3]=b0.w;
        acc[4]=b1.x; acc[5]=b1.y; acc[6]=b1.z; acc[7]=b1.w;
    }
    #pragma unroll
    for (int di = 0; di < 3; ++di) {
        const int ii = i + di - 1;
        if (ii < 0 || ii >= HH) continue;
        #pragma unroll
        for (int dj = 0; dj < 3; ++dj) {
            const int jj = j + dj - 1;
            if (jj < 0 || jj >= WW) continue;
            const uint4 v = *(const uint4*)(xl + (((size_t)b << 12) + (size_t)(ii * 64 + jj)) * INNER + d0);
            const int t9 = di * 3 + dj;
            const unsigned ua[4] = {v.x, v.y, v.z, v.w};
            #pragma unroll
            for (int w2 = 0; w2 < 4; ++w2) {
                const float xlo = __uint_as_float(ua[w2] << 16);
                const float xhi = __uint_as_float(ua[w2] & 0xffff0000u);
                acc[2*w2+0] = fmaf(xlo, wreg[(2*w2+0)*9 + t9], acc[2*w2+0]);
                acc[2*w2+1] = fmaf(xhi, wreg[(2*w2+1)*9 + t9], acc[2*w2+1]);
            }
        }
    }
    unsigned o[4];
    #pragma unroll
    for (int w2 = 0; w2 < 4; ++w2) {
        const unsigned lo = f2bf(silu_f(acc[2*w2+0]));
        const unsigned hi = f2bf(silu_f(acc[2*w2+1]));
        o[w2] = lo | (hi << 16);
    }
    *(uint4*)(xcbf + (size_t)m * INNER + d0) = make_uint4(o[0], o[1], o[2], o[3]);
}

// ---------------------------------------------------------------------------
// dtv = softplus(dt_raw + dt_bias[h]); cums = per-chunk inclusive prefix sum
// ---------------------------------------------------------------------------
__global__ __launch_bounds__(256)
void dtcums_kernel(const float* __restrict__ BCdt, const float* __restrict__ dt_bias,
                   const float* __restrict__ A_logs,
                   float* __restrict__ dtv, float* __restrict__ cums)
{
    const int w = blockIdx.x * 4 + (threadIdx.x >> 6);
    const int lane = threadIdx.x & 63;
    const int b = w / (NHEADS * NC);
    const int rem = w - b * (NHEADS * NC);
    const int h = rem / NC;
    const int c = rem - h * NC;
    const int k = h / NHK;
    const int hq = h - k * NHK;
    const int l = c * QC + lane;
    const float dtraw = BCdt[(((size_t)b * LL + l) * 2 + k) * CPROJ + 2*NSTATE + hq];
    const float xx = dtraw + dt_bias[h];
    const float sp = (xx > 20.f) ? xx : log1pf(expf(xx));
    float s = -expf(A_logs[h]) * sp;
    #pragma unroll
    for (int d = 1; d < 64; d <<= 1) {
        const float o = __shfl_up(s, d);
        if (lane >= d) s += o;
    }
    dtv[((size_t)b * LL + l) * NHEADS + h] = sp;
    cums[((size_t)b * LL + l) * NHEADS + h] = s;
}

// ---------------------------------------------------------------------------
// Chunk states: S_c[p,n] = sum_m dt[m]*exp(cu[63]-cu[m]) * x[m][p] * B[m][n]
// xc bf16 in, SH bf16 out.
// ---------------------------------------------------------------------------
__global__ __launch_bounds__(256)
void chunk_state_kernel(const unsigned short* __restrict__ xcbf, const float* __restrict__ BCdt,
                        const float* __restrict__ dtv, const float* __restrict__ cums,
                        unsigned short* __restrict__ SHb)
{
    __shared__ float Xs[QC][64];
    __shared__ float Bs[QC][33];
    __shared__ float cuS[QC];
    __shared__ float rs[QC];
    const int c = blockIdx.x, h = blockIdx.y, b = blockIdx.z;
    const int k = h / NHK;
    const int dch0 = (h - k * NHK) * PDIM;
    const int tid = threadIdx.x;
    #pragma unroll
    for (int r = 0; r < 16; ++r) {
        const int idx = tid + r * 256;
        const int i = idx >> 6, p = idx & 63;
        const int pos = (k == 0) ? (c * QC + i) : (i * QC + c);
        Xs[i][p] = bf2f(xcbf[(((size_t)b << 12) + pos) * INNER + dch0 + p]);
    }
    #pragma unroll
    for (int r = 0; r < 8; ++r) {
        const int idx = tid + r * 256;
        const int i = idx >> 5, n = idx & 31;
        Bs[i][n] = BCdt[(((size_t)b * LL + c * QC + i) * 2 + k) * CPROJ + n];
    }
    if (tid < QC)
        cuS[tid] = cums[((size_t)b * LL + c * QC + tid) * NHEADS + h];
    __syncthreads();
    if (tid < QC)
        rs[tid] = dtv[((size_t)b * LL + c * QC + tid) * NHEADS + h] * __expf(cuS[QC-1] - cuS[tid]);
    __syncthreads();
    const int p = tid & 63;
    const int n0 = (tid >> 6) * 8;
    float s[8] = {0.f,0.f,0.f,0.f,0.f,0.f,0.f,0.f};
    #pragma unroll 8
    for (int m = 0; m < QC; ++m) {
        const float rx = rs[m] * Xs[m][p];
        #pragma unroll
        for (int j = 0; j < 8; ++j) s[j] = fmaf(rx, Bs[m][n0 + j], s[j]);
    }
    unsigned o[4];
    #pragma unroll
    for (int w2 = 0; w2 < 4; ++w2)
        o[w2] = (unsigned)f2bf(s[2*w2]) | ((unsigned)f2bf(s[2*w2+1]) << 16);
    *(uint4*)(SHb + ((((size_t)b * NHEADS + h) * NC + c) * PDIM + p) * NSTATE + n0) =
        make_uint4(o[0], o[1], o[2], o[3]);
}

// ---------------------------------------------------------------------------
// Sequential scan over chunks (in place, bf16 slots, f32 running state).
// ---------------------------------------------------------------------------
__global__ __launch_bounds__(256)
void state_scan_kernel(unsigned short* __restrict__ SHb, const float* __restrict__ cums,
                       const float* __restrict__ init_states)
{
    __shared__ float decays[NC];
    const int b = blockIdx.x / NHEADS;
    const int h = blockIdx.x % NHEADS;
    const int tid = threadIdx.x;
    if (tid < NC)
        decays[tid] = __expf(cums[((size_t)b * LL + tid * QC + QC - 1) * NHEADS + h]);
    __syncthreads();
    const int p = tid >> 2;
    const int nb = (tid & 3) * 8;
    float hs[8];
    {
        const float* is = init_states + ((size_t)h * PDIM + p) * NSTATE + nb;
        #pragma unroll
        for (int i = 0; i < 8; ++i) hs[i] = is[i];
    }
    unsigned short* base = SHb + (((size_t)b * NHEADS + h) * NC) * (PDIM * NSTATE) + p * NSTATE + nb;
    for (int c = 0; c < NC; ++c) {
        unsigned short* slot = base + (size_t)c * (PDIM * NSTATE);
        const uint4 sv = *(const uint4*)slot;
        const unsigned ua[4] = {sv.x, sv.y, sv.z, sv.w};
        unsigned o[4];
        #pragma unroll
        for (int w2 = 0; w2 < 4; ++w2)
            o[w2] = (unsigned)f2bf(hs[2*w2]) | ((unsigned)f2bf(hs[2*w2+1]) << 16);
        *(uint4*)slot = make_uint4(o[0], o[1], o[2], o[3]);
        const float dc = decays[c];
        #pragma unroll
        for (int w2 = 0; w2 < 4; ++w2) {
            hs[2*w2+0] = fmaf(dc, hs[2*w2+0], __uint_as_float(ua[w2] << 16));
            hs[2*w2+1] = fmaf(dc, hs[2*w2+1], __uint_as_float(ua[w2] & 0xffff0000u));
        }
    }
}

// ---------------------------------------------------------------------------
// Intra-chunk + inter-chunk + D term via bf16 MFMA.  grid (NC, NHEADS, BB).
// ---------------------------------------------------------------------------
__global__ __launch_bounds__(256)
void intra_kernel(const unsigned short* __restrict__ xcbf, const float* __restrict__ BCdt,
                  const float* __restrict__ dtv, const float* __restrict__ cums,
                  const unsigned short* __restrict__ SHb, const float* __restrict__ Ds,
                  float* __restrict__ ysum)
{
    __shared__ __align__(16) unsigned short Bs[QC][32];    // [m][n]
    __shared__ __align__(16) unsigned short Cs[QC][32];    // [i][n]
    __shared__ __align__(16) unsigned short Hs[PDIM][32];  // [p][n]
    __shared__ __align__(16) unsigned short Xb[PDIM][72];  // [p][m]  (X^T)
    __shared__ __align__(16) unsigned short Gb[QC][72];    // [i][m]
    __shared__ float cuS[QC], dtS[QC], Ei[QC];
    const int c = blockIdx.x, h = blockIdx.y, b = blockIdx.z;
    const int k = h / NHK;
    const int dch0 = (h - k * NHK) * PDIM;
    const int tid = threadIdx.x;
    const int lane = tid & 63;
    const int w = tid >> 6;

    #pragma unroll
    for (int r = 0; r < 16; ++r) {
        const int idx = tid + r * 256;
        const int m = idx >> 6, p = idx & 63;
        const int pos = (k == 0) ? (c * QC + m) : (m * QC + c);
        Xb[p][m] = xcbf[(((size_t)b << 12) + pos) * INNER + dch0 + p];
    }
    #pragma unroll
    for (int r = 0; r < 16; ++r) {
        const int idx = tid + r * 256;
        const int i = idx >> 6, q = idx & 63;
        const float v = BCdt[(((size_t)b * LL + c * QC + i) * 2 + k) * CPROJ + q];
        if (q < NSTATE) Bs[i][q] = f2bf(v); else Cs[i][q - NSTATE] = f2bf(v);
    }
    #pragma unroll
    for (int r = 0; r < 8; ++r) {
        const int idx = tid + r * 256;
        const int p = idx >> 5, n = idx & 31;
        Hs[p][n] = SHb[((((size_t)b * NHEADS + h) * NC + c) * PDIM + p) * NSTATE + n];
    }
    if (tid < QC) {
        const size_t o = ((size_t)b * LL + c * QC + tid) * NHEADS + h;
        const float cu = cums[o];
        cuS[tid] = cu;
        dtS[tid] = dtv[o];
        Ei[tid]  = __expf(cu);
    }
    __syncthreads();

    const int rowf = lane & 15;
    const int ko   = lane >> 4;
    const short8 cfrag = *(const short8*)&Cs[w * 16 + rowf][ko * 8];

    // matmul1: G_raw tiles (it=w, mt=0..3)
    f32x4 graw[4];
    #pragma unroll
    for (int mt = 0; mt < 4; ++mt) {
        const short8 bfrag = *(const short8*)&Bs[mt * 16 + rowf][ko * 8];
        graw[mt] = __builtin_amdgcn_mfma_f32_16x16x32_bf16(cfrag, bfrag, (f32x4){0.f,0.f,0.f,0.f}, 0, 0, 0);
    }
    #pragma unroll
    for (int mt = 0; mt < 4; ++mt) {
        const int m = mt * 16 + rowf;
        const float cum = cuS[m];
        const float dtm = dtS[m];
        #pragma unroll
        for (int q = 0; q < 4; ++q) {
            const int i = w * 16 + ko * 4 + q;
            float g = 0.f;
            if (m <= i) g = __expf(fminf(cuS[i] - cum, 0.f)) * dtm * graw[mt][q];
            Gb[i][m] = f2bf(g);
        }
    }
    // matmul2: inter tiles (it=w, pt=0..3)
    f32x4 acc[4];
    #pragma unroll
    for (int pt = 0; pt < 4; ++pt) {
        const short8 hfrag = *(const short8*)&Hs[pt * 16 + rowf][ko * 8];
        acc[pt] = __builtin_amdgcn_mfma_f32_16x16x32_bf16(cfrag, hfrag, (f32x4){0.f,0.f,0.f,0.f}, 0, 0, 0);
    }
    const float Dh = Ds[h];
    #pragma unroll
    for (int pt = 0; pt < 4; ++pt) {
        const int p = pt * 16 + rowf;
        #pragma unroll
        for (int q = 0; q < 4; ++q) {
            const int i = w * 16 + ko * 4 + q;
            acc[pt][q] = acc[pt][q] * Ei[i] + Dh * bf2f(Xb[p][i]);
        }
    }
    // matmul3: acc += G·X  (wave w reads only its own Gb rows)
    #pragma unroll
    for (int ks = 0; ks < 2; ++ks) {
        const short8 gfrag = *(const short8*)&Gb[w * 16 + rowf][ks * 32 + ko * 8];
        #pragma unroll
        for (int pt = 0; pt < 4; ++pt) {
            const short8 xfrag = *(const short8*)&Xb[pt * 16 + rowf][ks * 32 + ko * 8];
            acc[pt] = __builtin_amdgcn_mfma_f32_16x16x32_bf16(gfrag, xfrag, acc[pt], 0, 0, 0);
        }
    }
    #pragma unroll
    for (int pt = 0; pt < 4; ++pt) {
        const int p = pt * 16 + rowf;
        #pragma unroll
        for (int q = 0; q < 4; ++q) {
            const int i = w * 16 + ko * 4 + q;
            const int pos = (k == 0) ? (c * QC + i) : (i * QC + c);
            atomicAdd(&ysum[(((size_t)b << 12) + pos) * INNER + dch0 + p], acc[pt][q]);
        }
    }
}

// ---------------------------------------------------------------------------
// gate: yg_bf = bf16( ysum * silu(z_bf) )
// ---------------------------------------------------------------------------
__global__ __launch_bounds__(256)
void gate_kernel(const float* __restrict__ ysum, const unsigned short* __restrict__ zb,
                 unsigned short* __restrict__ ygbf)
{
    const size_t e = (size_t)blockIdx.x * 256 + threadIdx.x;
    if (e >= (size_t)BB * LL * INNER) return;
    ygbf[e] = f2bf(ysum[e] * silu_f(bf2f(zb[e])));
}

__global__ __launch_bounds__(256)
void report_ws_kernel(float* __restrict__ out, int n, float val)
{
    const int e = blockIdx.x * 256 + threadIdx.x;
    if (e < n) out[e] = val;
}

// ---------------------------------------------------------------------------
extern "C" void kernel_launch(void* const* d_in, const int* in_sizes, int n_in,
                              void* d_out, int out_size, void* d_ws, size_t ws_size,
                              hipStream_t stream)
{
    const float* x          = (const float*)d_in[0];
    const float* W_in       = (const float*)d_in[1];
    const float* conv_w     = (const float*)d_in[2];
    const float* conv_b     = (const float*)d_in[3];
    const float* xpw        = (const float*)d_in[4];
    const float* A_logs     = (const float*)d_in[5];
    const float* Ds         = (const float*)d_in[6];
    const float* dt_bias    = (const float*)d_in[7];
    const float* init_states= (const float*)d_in[8];
    const float* W_out      = (const float*)d_in[9];
    const float* W1         = (const float*)d_in[10];
    const float* b1         = (const float*)d_in[11];
    const float* W2         = (const float*)d_in[12];
    const float* b2         = (const float*)d_in[13];
    float* out = (float*)d_out;

    if (ws_size < (size_t)WS_REQ) {
        const float mib = (float)((double)ws_size / 1048576.0);
        report_ws_kernel<<<(out_size + 255) / 256, 256, 0, stream>>>(out, out_size, mib);
        return;
    }

    char* ws = (char*)d_ws;
    unsigned short* xl_bf = (unsigned short*)(ws + WS_XL);
    unsigned short* xc_bf = (unsigned short*)(ws + WS_XC);
    float* BCdt  = (float*)(ws + WS_BCDT);
    float* dtv   = (float*)(ws + WS_DTV);
    float* cums  = (float*)(ws + WS_CUMS);
    float* ysum  = (float*)(ws + WS_YSUM);
    unsigned short* x_bf   = (unsigned short*)(ws + WS_XBF);
    unsigned short* Winb   = (unsigned short*)(ws + WS_WINB);
    unsigned short* wpadb  = (unsigned short*)(ws + WS_WPADB);
    unsigned short* Woutb  = (unsigned short*)(ws + WS_WOUTB);
    unsigned short* W1b    = (unsigned short*)(ws + WS_W1B);
    unsigned short* W2b    = (unsigned short*)(ws + WS_W2B);
    unsigned short* SHb    = (unsigned short*)(ws + WS_XL);   // overlay: xl dead after conv
    unsigned short* z_bf   = (unsigned short*)(ws + WS_XL);   // overlay: SH dead after intra
    unsigned short* h1_bf  = (unsigned short*)(ws + WS_XL);   // overlay: z dead after gate
    unsigned short* yg_bf  = (unsigned short*)(ws + WS_XC);   // overlay: xc dead after intra
    unsigned short* out_bf = (unsigned short*)(ws + WS_BCDT); // overlay: BCdt dead after intra

    const int M = BB * LL;  // 32768

    // 0) bf16 conversions (weights + x)
    cvt_kernel<<<(M * CIN + 255) / 256, 256, 0, stream>>>(x, x_bf, M * CIN);
    cvt_kernel<<<(HID * CIN + 255) / 256, 256, 0, stream>>>(W_in, Winb, HID * CIN);
    cvt_kernel<<<(HID * CIN + 255) / 256, 256, 0, stream>>>(W1, W1b, HID * CIN);
    cvt_pad_kernel<<<(128 * INNER + 255) / 256, 256, 0, stream>>>(xpw, wpadb, CPROJ, 128 * INNER, INNER);
    cvt_pad_kernel<<<(128 * INNER + 255) / 256, 256, 0, stream>>>(xpw + CPROJ * INNER, wpadb + 128 * INNER, CPROJ, 128 * INNER, INNER);
    cvt_pad_kernel<<<(256 * INNER + 255) / 256, 256, 0, stream>>>(W_out, Woutb, CIN, 256 * INNER, INNER);
    cvt_pad_kernel<<<(256 * HID + 255) / 256, 256, 0, stream>>>(W2, W2b, CIN, 256 * HID, HID);

    // 1) xl_bf = bf16( x @ W_in[0:384]^T )
    gemm_bf16<4,0><<<dim3(M/128, INNER/128), 256, 0, stream>>>(x_bf, Winb, nullptr, nullptr, nullptr, xl_bf, CIN, INNER, INNER);

    // 2) depthwise conv + bias + SiLU -> xc_bf   (xl dead after this)
    conv_dw_kernel<<<(M * INNER / 8) / 256, 256, 0, stream>>>(xl_bf, conv_w, conv_b, xc_bf);

    // 3) BCdt projection as two bf16 GEMMs
    gemm_bf16<0,0><<<dim3(M/128, 1), 256, 0, stream>>>(xc_bf, wpadb, nullptr, nullptr, BCdt, nullptr, INNER, 2*CPROJ, CPROJ);
    gemm_bf16<0,1><<<dim3(M/128, 1), 256, 0, stream>>>(xc_bf, wpadb + 128 * INNER, nullptr, nullptr, BCdt + CPROJ, nullptr, INNER, 2*CPROJ, CPROJ);

    // 3b) dt softplus + per-chunk cumsum
    dtcums_kernel<<<(BB * NHEADS * NC) / 4, 256, 0, stream>>>(BCdt, dt_bias, A_logs, dtv, cums);

    // 4) chunked scan
    chunk_state_kernel<<<dim3(NC, NHEADS, BB), 256, 0, stream>>>(xc_bf, BCdt, dtv, cums, SHb);
    state_scan_kernel<<<BB * NHEADS, 256, 0, stream>>>(SHb, cums, init_states);
    hipMemsetAsync(ysum, 0, (size_t)M * INNER * sizeof(float), stream);
    intra_kernel<<<dim3(NC, NHEADS, BB), 256, 0, stream>>>(xc_bf, BCdt, dtv, cums, SHb, Ds, ysum);

    // 5) z_bf = bf16( x @ W_in[384:768]^T )  (SH dead now)
    gemm_bf16<4,0><<<dim3(M/128, INNER/128), 256, 0, stream>>>(x_bf, Winb + (size_t)INNER * CIN, nullptr, nullptr, nullptr, z_bf, CIN, INNER, INNER);
    gate_kernel<<<(M * INNER) / 256, 256, 0, stream>>>(ysum, z_bf, yg_bf);

    // 5b) out = x + yg @ W_out^T   (dual write: f32 out + bf16 out_bf)
    gemm_bf16<3,0><<<dim3(M/128, 2), 256, 0, stream>>>(yg_bf, Woutb, nullptr, x, out, out_bf, INNER, CIN, CIN);

    // 6) MLP: h1_bf = bf16(silu(out @ W1^T + b1));  out += h1 @ W2^T + b2
    gemm_bf16<1,0><<<dim3(M/128, HID/128), 256, 0, stream>>>(out_bf, W1b, b1, nullptr, nullptr, h1_bf, CIN, HID, HID);
    gemm_bf16<2,0><<<dim3(M/128, 2), 256, 0, stream>>>(h1_bf, W2b, b2, out, out, nullptr, HID, CIN, CIN);
}

// Round 10
// 331.926 us; speedup vs baseline: 9.7205x; 1.1663x over previous
//
#include <hip/hip_runtime.h>
#include <math.h>

#define BB 8
#define HH 64
#define WW 64
#define CIN 192
#define INNER 384
#define LL 4096          // HH*WW
#define NSTATE 32
#define PDIM 64
#define NHK 6            // INNER/PDIM
#define NHEADS 12        // 2*NHK
#define HID 768
#define CPROJ 70         // 2*NSTATE + NHK
#define QC 64            // chunk length
#define NC 64            // LL/QC chunks

// workspace layout (bytes)
#define WS_XLZ   0u                   // bf16 xlz (B,L,768) 50331648 ; h1_bf overlay after gate
#define WS_XC    50331648u            // bf16 xc (B,L,384) 25165824 ; yg_bf overlay after intra
#define WS_Y1    75497472u            // bf16 y1 (B,L,384) 25165824
#define WS_BCDT  100663296u           // (B,L,2,70) f32 18350080 ; out_bf overlay after intra
#define WS_DTV   119013376u           // (B,L,12) f32 1572864
#define WS_CUMS  120586240u           // (B,L,12) f32 1572864
#define WS_SHB   122159104u           // bf16 SH (B,NH,NC,P,N) 25165824
#define WS_Y0    147324928u           // bf16 y0 (B,L,384) 25165824
#define WS_XBF   172490752u           // (M,192) bf16 12582912 (dead after in_proj)
#define WS_WINB  185073664u           // W_in bf16 768x192      294912
#define WS_WPADB 185368576u           // xpw padded bf16 2x128x384 196608
#define WS_WOUTB 185565184u           // W_out padded bf16 256x384 196608
#define WS_W1B   185761792u           // W1 bf16 768x192        294912
#define WS_W2B   186056704u           // W2 padded bf16 256x768 393216
#define WS_REQ   186449920u

typedef __attribute__((ext_vector_type(8))) short short8;
typedef __attribute__((ext_vector_type(4))) float f32x4;

__device__ __forceinline__ float silu_f(float x) { return x / (1.f + __expf(-x)); }

__device__ __forceinline__ unsigned short f2bf(float f) {
    unsigned u = __float_as_uint(f);
    u += 0x7fffu + ((u >> 16) & 1u);
    return (unsigned short)(u >> 16);
}
__device__ __forceinline__ float bf2f(unsigned short u) {
    return __uint_as_float(((unsigned)u) << 16);
}

// ---------------------------------------------------------------------------
// bf16 MFMA GEMM: C[m,n] = sum_k A[m,k]*Wt[n,k].  A,Wt bf16; acc f32.
// 128x128 tile, BK=64, 4 waves x (64x64), mfma_f32_16x16x32_bf16.
// EPI: 0 Cf=acc; 1 Cb=bf16(silu(acc+bias)); 2 Cf=acc+bias+res; 3 Cf=acc+res & Cb;
//      4 Cb=bf16(acc).
// ---------------------------------------------------------------------------
template<int EPI, int TRANSA>
__global__ __launch_bounds__(256)
void gemm_bf16(const unsigned short* __restrict__ A, const unsigned short* __restrict__ Wt,
               const float* __restrict__ bias, const float* __restrict__ res,
               float* __restrict__ Cf, unsigned short* __restrict__ Cb,
               int Kd, int ldc, int nmax)
{
    __shared__ __align__(16) short Als[128 * 64];
    __shared__ __align__(16) short Bls[128 * 64];
    const int tid = threadIdx.x;
    const int m0 = blockIdx.x * 128;
    const int n0 = blockIdx.y * 128;
    const int lane = tid & 63;
    const int wv = tid >> 6;
    const int wm = (wv >> 1) << 6;
    const int wn = (wv & 1) << 6;

    const unsigned short* gA[4];
    const unsigned short* gB[4];
    int lw[4];
    #pragma unroll
    for (int c = 0; c < 4; ++c) {
        const int idx = c * 256 + tid;
        const int row = idx >> 3;
        const int kb  = idx & 7;
        const int sb  = kb ^ (row & 7);
        lw[c] = row * 64 + sb * 8;
        size_t arow;
        const int mm = m0 + row;
        if (TRANSA) {
            const int bq = mm >> 12, lq = mm & 4095;
            arow = ((size_t)bq << 12) + (size_t)(((lq & 63) << 6) + (lq >> 6));
        } else {
            arow = (size_t)mm;
        }
        gA[c] = A + arow * Kd + kb * 8;
        gB[c] = Wt + (size_t)(n0 + row) * Kd + kb * 8;
    }

    f32x4 acc[4][4];
    #pragma unroll
    for (int i = 0; i < 4; ++i)
        #pragma unroll
        for (int j = 0; j < 4; ++j) acc[i][j] = (f32x4){0.f, 0.f, 0.f, 0.f};

    const int NT = Kd >> 6;
    short8 pA[4], pB[4];
    #pragma unroll
    for (int c = 0; c < 4; ++c) {
        pA[c] = *(const short8*)(gA[c]);
        pB[c] = *(const short8*)(gB[c]);
    }
    for (int kt = 0; kt < NT; ++kt) {
        __syncthreads();
        #pragma unroll
        for (int c = 0; c < 4; ++c) {
            *(short8*)&Als[lw[c]] = pA[c];
            *(short8*)&Bls[lw[c]] = pB[c];
        }
        __syncthreads();
        if (kt + 1 < NT) {
            #pragma unroll
            for (int c = 0; c < 4; ++c) {
                pA[c] = *(const short8*)(gA[c] + (kt + 1) * 64);
                pB[c] = *(const short8*)(gB[c] + (kt + 1) * 64);
            }
        }
        #pragma unroll
        for (int ks = 0; ks < 2; ++ks) {
            short8 af[4], bfr[4];
            #pragma unroll
            for (int r = 0; r < 4; ++r) {
                const int rowa = wm + r * 16 + (lane & 15);
                const int rowb = wn + r * 16 + (lane & 15);
                const int kb = ks * 4 + (lane >> 4);
                af[r]  = *(const short8*)&Als[rowa * 64 + ((kb ^ (rowa & 7)) << 3)];
                bfr[r] = *(const short8*)&Bls[rowb * 64 + ((kb ^ (rowb & 7)) << 3)];
            }
            #pragma unroll
            for (int mr = 0; mr < 4; ++mr)
                #pragma unroll
                for (int nr = 0; nr < 4; ++nr)
                    acc[mr][nr] = __builtin_amdgcn_mfma_f32_16x16x32_bf16(af[mr], bfr[nr], acc[mr][nr], 0, 0, 0);
        }
    }
    #pragma unroll
    for (int mr = 0; mr < 4; ++mr) {
        #pragma unroll
        for (int nr = 0; nr < 4; ++nr) {
            const int n = n0 + wn + nr * 16 + (lane & 15);
            if (n >= nmax) continue;
            const int mb = m0 + wm + mr * 16 + ((lane >> 4) << 2);
            #pragma unroll
            for (int q = 0; q < 4; ++q) {
                const size_t off = (size_t)(mb + q) * ldc + n;
                float v = acc[mr][nr][q];
                if (EPI == 0) { Cf[off] = v; }
                else if (EPI == 1) { v = silu_f(v + bias[n]); Cb[off] = f2bf(v); }
                else if (EPI == 2) { v += bias[n] + res[off]; Cf[off] = v; }
                else if (EPI == 3) { v += res[off]; Cf[off] = v; Cb[off] = f2bf(v); }
                else if (EPI == 4) { Cb[off] = f2bf(v); }
            }
        }
    }
}

// ---------------------------------------------------------------------------
// f32 -> bf16 converters (flat / row-padded with zeros)
// ---------------------------------------------------------------------------
__global__ __launch_bounds__(256)
void cvt_kernel(const float* __restrict__ src, unsigned short* __restrict__ dst, int n)
{
    const int i = blockIdx.x * 256 + threadIdx.x;
    if (i < n) dst[i] = f2bf(src[i]);
}

__global__ __launch_bounds__(256)
void cvt_pad_kernel(const float* __restrict__ src, unsigned short* __restrict__ dst,
                    int srcRows, int total, int cols)
{
    const int i = blockIdx.x * 256 + threadIdx.x;
    if (i >= total) return;
    const int r = i / cols;
    dst[i] = (r < srcRows) ? f2bf(src[i]) : (unsigned short)0;
}

// ---------------------------------------------------------------------------
// Depthwise 3x3 conv + bias + SiLU, 8 channels/thread, bf16 in/out.
// xlz (B,L,768), channels 0..383 -> xc_bf (B,L,384)
// ---------------------------------------------------------------------------
__global__ __launch_bounds__(256)
void conv_dw_kernel(const unsigned short* __restrict__ xlz, const float* __restrict__ cw,
                    const float* __restrict__ cb, unsigned short* __restrict__ xcbf)
{
    const int t = blockIdx.x * 256 + threadIdx.x;     // < M * 48
    const int dv = t % (INNER / 8);
    const int m  = t / (INNER / 8);
    const int b = m >> 12;
    const int r = m & 4095;
    const int i = r >> 6;
    const int j = r & 63;
    const int d0 = dv * 8;

    float wreg[72];
    {
        const float4* w4 = (const float4*)(cw + d0 * 9);
        #pragma unroll
        for (int u = 0; u < 18; ++u) {
            const float4 v = w4[u];
            wreg[4*u+0] = v.x; wreg[4*u+1] = v.y; wreg[4*u+2] = v.z; wreg[4*u+3] = v.w;
        }
    }
    float acc[8];
    {
        const float4 b0 = *(const float4*)(cb + d0);
        const float4 b1 = *(const float4*)(cb + d0 + 4);
        acc[0]=b0.x; acc[1]=b0.y; acc[2]=b0.z; acc[3]=b0.w;
        acc[4]=b1.x; acc[5]=b1.y; acc[6]=b1.z; acc[7]=b1.w;
    }
    #pragma unroll
    for (int di = 0; di < 3; ++di) {
        const int ii = i + di - 1;
        if (ii < 0 || ii >= HH) continue;
        #pragma unroll
        for (int dj = 0; dj < 3; ++dj) {
            const int jj = j + dj - 1;
            if (jj < 0 || jj >= WW) continue;
            const uint4 v = *(const uint4*)(xlz + (((size_t)b << 12) + (size_t)(ii * 64 + jj)) * 768 + d0);
            const int t9 = di * 3 + dj;
            const unsigned ua[4] = {v.x, v.y, v.z, v.w};
            #pragma unroll
            for (int w2 = 0; w2 < 4; ++w2) {
                const float xlo = __uint_as_float(ua[w2] << 16);
                const float xhi = __uint_as_float(ua[w2] & 0xffff0000u);
                acc[2*w2+0] = fmaf(xlo, wreg[(2*w2+0)*9 + t9], acc[2*w2+0]);
                acc[2*w2+1] = fmaf(xhi, wreg[(2*w2+1)*9 + t9], acc[2*w2+1]);
            }
        }
    }
    unsigned o[4];
    #pragma unroll
    for (int w2 = 0; w2 < 4; ++w2) {
        const unsigned lo = f2bf(silu_f(acc[2*w2+0]));
        const unsigned hi = f2bf(silu_f(acc[2*w2+1]));
        o[w2] = lo | (hi << 16);
    }
    *(uint4*)(xcbf + (size_t)m * INNER + d0) = make_uint4(o[0], o[1], o[2], o[3]);
}

// ---------------------------------------------------------------------------
// dtv = softplus(dt_raw + dt_bias[h]); cums = per-chunk inclusive prefix sum
// ---------------------------------------------------------------------------
__global__ __launch_bounds__(256)
void dtcums_kernel(const float* __restrict__ BCdt, const float* __restrict__ dt_bias,
                   const float* __restrict__ A_logs,
                   float* __restrict__ dtv, float* __restrict__ cums)
{
    const int w = blockIdx.x * 4 + (threadIdx.x >> 6);
    const int lane = threadIdx.x & 63;
    const int b = w / (NHEADS * NC);
    const int rem = w - b * (NHEADS * NC);
    const int h = rem / NC;
    const int c = rem - h * NC;
    const int k = h / NHK;
    const int hq = h - k * NHK;
    const int l = c * QC + lane;
    const float dtraw = BCdt[(((size_t)b * LL + l) * 2 + k) * CPROJ + 2*NSTATE + hq];
    const float xx = dtraw + dt_bias[h];
    const float sp = (xx > 20.f) ? xx : log1pf(expf(xx));
    float s = -expf(A_logs[h]) * sp;
    #pragma unroll
    for (int d = 1; d < 64; d <<= 1) {
        const float o = __shfl_up(s, d);
        if (lane >= d) s += o;
    }
    dtv[((size_t)b * LL + l) * NHEADS + h] = sp;
    cums[((size_t)b * LL + l) * NHEADS + h] = s;
}

// ---------------------------------------------------------------------------
// Chunk states: S_c[p,n] = sum_m dt[m]*exp(cu[63]-cu[m]) * x[m][p] * B[m][n]
// xc bf16 in, SH bf16 out.
// ---------------------------------------------------------------------------
__global__ __launch_bounds__(256)
void chunk_state_kernel(const unsigned short* __restrict__ xcbf, const float* __restrict__ BCdt,
                        const float* __restrict__ dtv, const float* __restrict__ cums,
                        unsigned short* __restrict__ SHb)
{
    __shared__ float Xs[QC][64];
    __shared__ float Bs[QC][33];
    __shared__ float cuS[QC];
    __shared__ float rs[QC];
    const int c = blockIdx.x, h = blockIdx.y, b = blockIdx.z;
    const int k = h / NHK;
    const int dch0 = (h - k * NHK) * PDIM;
    const int tid = threadIdx.x;
    #pragma unroll
    for (int r = 0; r < 16; ++r) {
        const int idx = tid + r * 256;
        const int i = idx >> 6, p = idx & 63;
        const int pos = (k == 0) ? (c * QC + i) : (i * QC + c);
        Xs[i][p] = bf2f(xcbf[(((size_t)b << 12) + pos) * INNER + dch0 + p]);
    }
    #pragma unroll
    for (int r = 0; r < 8; ++r) {
        const int idx = tid + r * 256;
        const int i = idx >> 5, n = idx & 31;
        Bs[i][n] = BCdt[(((size_t)b * LL + c * QC + i) * 2 + k) * CPROJ + n];
    }
    if (tid < QC)
        cuS[tid] = cums[((size_t)b * LL + c * QC + tid) * NHEADS + h];
    __syncthreads();
    if (tid < QC)
        rs[tid] = dtv[((size_t)b * LL + c * QC + tid) * NHEADS + h] * __expf(cuS[QC-1] - cuS[tid]);
    __syncthreads();
    const int p = tid & 63;
    const int n0 = (tid >> 6) * 8;
    float s[8] = {0.f,0.f,0.f,0.f,0.f,0.f,0.f,0.f};
    #pragma unroll 8
    for (int m = 0; m < QC; ++m) {
        const float rx = rs[m] * Xs[m][p];
        #pragma unroll
        for (int j = 0; j < 8; ++j) s[j] = fmaf(rx, Bs[m][n0 + j], s[j]);
    }
    unsigned o[4];
    #pragma unroll
    for (int w2 = 0; w2 < 4; ++w2)
        o[w2] = (unsigned)f2bf(s[2*w2]) | ((unsigned)f2bf(s[2*w2+1]) << 16);
    *(uint4*)(SHb + ((((size_t)b * NHEADS + h) * NC + c) * PDIM + p) * NSTATE + n0) =
        make_uint4(o[0], o[1], o[2], o[3]);
}

// ---------------------------------------------------------------------------
// Sequential scan over chunks (in place, bf16 slots, f32 running state).
// ---------------------------------------------------------------------------
__global__ __launch_bounds__(256)
void state_scan_kernel(unsigned short* __restrict__ SHb, const float* __restrict__ cums,
                       const float* __restrict__ init_states)
{
    __shared__ float decays[NC];
    const int b = blockIdx.x / NHEADS;
    const int h = blockIdx.x % NHEADS;
    const int tid = threadIdx.x;
    if (tid < NC)
        decays[tid] = __expf(cums[((size_t)b * LL + tid * QC + QC - 1) * NHEADS + h]);
    __syncthreads();
    const int p = tid >> 2;
    const int nb = (tid & 3) * 8;
    float hs[8];
    {
        const float* is = init_states + ((size_t)h * PDIM + p) * NSTATE + nb;
        #pragma unroll
        for (int i = 0; i < 8; ++i) hs[i] = is[i];
    }
    unsigned short* base = SHb + (((size_t)b * NHEADS + h) * NC) * (PDIM * NSTATE) + p * NSTATE + nb;
    for (int c = 0; c < NC; ++c) {
        unsigned short* slot = base + (size_t)c * (PDIM * NSTATE);
        const uint4 sv = *(const uint4*)slot;
        const unsigned ua[4] = {sv.x, sv.y, sv.z, sv.w};
        unsigned o[4];
        #pragma unroll
        for (int w2 = 0; w2 < 4; ++w2)
            o[w2] = (unsigned)f2bf(hs[2*w2]) | ((unsigned)f2bf(hs[2*w2+1]) << 16);
        *(uint4*)slot = make_uint4(o[0], o[1], o[2], o[3]);
        const float dc = decays[c];
        #pragma unroll
        for (int w2 = 0; w2 < 4; ++w2) {
            hs[2*w2+0] = fmaf(dc, hs[2*w2+0], __uint_as_float(ua[w2] << 16));
            hs[2*w2+1] = fmaf(dc, hs[2*w2+1], __uint_as_float(ua[w2] & 0xffff0000u));
        }
    }
}

// ---------------------------------------------------------------------------
// Intra-chunk + inter-chunk + D term via bf16 MFMA.  grid (NC, NHEADS, BB).
// Direct bf16 stores to y0 (k=0) / y1 (k=1) — each element written exactly
// once per direction, no atomics.  Bs/Cs/Hs padded to 40 (80B = 5x16B rows,
// gcd(5,8)=1 -> conflict-free b128 frag reads).
// ---------------------------------------------------------------------------
__global__ __launch_bounds__(256)
void intra_kernel(const unsigned short* __restrict__ xcbf, const float* __restrict__ BCdt,
                  const float* __restrict__ dtv, const float* __restrict__ cums,
                  const unsigned short* __restrict__ SHb, const float* __restrict__ Ds,
                  unsigned short* __restrict__ y0, unsigned short* __restrict__ y1)
{
    __shared__ __align__(16) unsigned short Bs[QC][40];    // [m][n]
    __shared__ __align__(16) unsigned short Cs[QC][40];    // [i][n]
    __shared__ __align__(16) unsigned short Hs[PDIM][40];  // [p][n]
    __shared__ __align__(16) unsigned short Xb[PDIM][72];  // [p][m]  (X^T)
    __shared__ __align__(16) unsigned short Gb[QC][72];    // [i][m]
    __shared__ float cuS[QC], dtS[QC], Ei[QC];
    const int c = blockIdx.x, h = blockIdx.y, b = blockIdx.z;
    const int k = h / NHK;
    const int dch0 = (h - k * NHK) * PDIM;
    const int tid = threadIdx.x;
    const int lane = tid & 63;
    const int w = tid >> 6;

    #pragma unroll
    for (int r = 0; r < 16; ++r) {
        const int idx = tid + r * 256;
        const int m = idx >> 6, p = idx & 63;
        const int pos = (k == 0) ? (c * QC + m) : (m * QC + c);
        Xb[p][m] = xcbf[(((size_t)b << 12) + pos) * INNER + dch0 + p];
    }
    #pragma unroll
    for (int r = 0; r < 16; ++r) {
        const int idx = tid + r * 256;
        const int i = idx >> 6, q = idx & 63;
        const float v = BCdt[(((size_t)b * LL + c * QC + i) * 2 + k) * CPROJ + q];
        if (q < NSTATE) Bs[i][q] = f2bf(v); else Cs[i][q - NSTATE] = f2bf(v);
    }
    #pragma unroll
    for (int r = 0; r < 8; ++r) {
        const int idx = tid + r * 256;
        const int p = idx >> 5, n = idx & 31;
        Hs[p][n] = SHb[((((size_t)b * NHEADS + h) * NC + c) * PDIM + p) * NSTATE + n];
    }
    if (tid < QC) {
        const size_t o = ((size_t)b * LL + c * QC + tid) * NHEADS + h;
        const float cu = cums[o];
        cuS[tid] = cu;
        dtS[tid] = dtv[o];
        Ei[tid]  = __expf(cu);
    }
    __syncthreads();

    const int rowf = lane & 15;
    const int ko   = lane >> 4;
    const short8 cfrag = *(const short8*)&Cs[w * 16 + rowf][ko * 8];

    // matmul1: G_raw tiles (it=w, mt=0..3)
    f32x4 graw[4];
    #pragma unroll
    for (int mt = 0; mt < 4; ++mt) {
        const short8 bfrag = *(const short8*)&Bs[mt * 16 + rowf][ko * 8];
        graw[mt] = __builtin_amdgcn_mfma_f32_16x16x32_bf16(cfrag, bfrag, (f32x4){0.f,0.f,0.f,0.f}, 0, 0, 0);
    }
    #pragma unroll
    for (int mt = 0; mt < 4; ++mt) {
        const int m = mt * 16 + rowf;
        const float cum = cuS[m];
        const float dtm = dtS[m];
        #pragma unroll
        for (int q = 0; q < 4; ++q) {
            const int i = w * 16 + ko * 4 + q;
            float g = 0.f;
            if (m <= i) g = __expf(fminf(cuS[i] - cum, 0.f)) * dtm * graw[mt][q];
            Gb[i][m] = f2bf(g);
        }
    }
    // matmul2: inter tiles (it=w, pt=0..3)
    f32x4 acc[4];
    #pragma unroll
    for (int pt = 0; pt < 4; ++pt) {
        const short8 hfrag = *(const short8*)&Hs[pt * 16 + rowf][ko * 8];
        acc[pt] = __builtin_amdgcn_mfma_f32_16x16x32_bf16(cfrag, hfrag, (f32x4){0.f,0.f,0.f,0.f}, 0, 0, 0);
    }
    const float Dh = Ds[h];
    #pragma unroll
    for (int pt = 0; pt < 4; ++pt) {
        const int p = pt * 16 + rowf;
        #pragma unroll
        for (int q = 0; q < 4; ++q) {
            const int i = w * 16 + ko * 4 + q;
            acc[pt][q] = acc[pt][q] * Ei[i] + Dh * bf2f(Xb[p][i]);
        }
    }
    // matmul3: acc += G·X  (wave w reads only its own Gb rows)
    #pragma unroll
    for (int ks = 0; ks < 2; ++ks) {
        const short8 gfrag = *(const short8*)&Gb[w * 16 + rowf][ks * 32 + ko * 8];
        #pragma unroll
        for (int pt = 0; pt < 4; ++pt) {
            const short8 xfrag = *(const short8*)&Xb[pt * 16 + rowf][ks * 32 + ko * 8];
            acc[pt] = __builtin_amdgcn_mfma_f32_16x16x32_bf16(gfrag, xfrag, acc[pt], 0, 0, 0);
        }
    }
    // epilogue: direct bf16 store (exactly one writer per element per direction)
    unsigned short* yk = (k == 0) ? y0 : y1;
    #pragma unroll
    for (int pt = 0; pt < 4; ++pt) {
        const int p = pt * 16 + rowf;
        #pragma unroll
        for (int q = 0; q < 4; ++q) {
            const int i = w * 16 + ko * 4 + q;
            const int pos = (k == 0) ? (c * QC + i) : (i * QC + c);
            yk[(((size_t)b << 12) + pos) * INNER + dch0 + p] = f2bf(acc[pt][q]);
        }
    }
}

// ---------------------------------------------------------------------------
// gate: yg_bf = bf16( (y0+y1) * silu(z) ), 8 elems/thread.
// ---------------------------------------------------------------------------
__global__ __launch_bounds__(256)
void gate_kernel(const unsigned short* __restrict__ y0, const unsigned short* __restrict__ y1,
                 const unsigned short* __restrict__ xlz, unsigned short* __restrict__ ygbf)
{
    const int t = blockIdx.x * 256 + threadIdx.x;   // < M*48
    const int dv = t % (INNER / 8);
    const int m  = t / (INNER / 8);
    const int d0 = dv * 8;
    const uint4 a = *(const uint4*)(y0 + (size_t)m * INNER + d0);
    const uint4 bv = *(const uint4*)(y1 + (size_t)m * INNER + d0);
    const uint4 zv = *(const uint4*)(xlz + (size_t)m * 768 + INNER + d0);
    const unsigned ua[4] = {a.x, a.y, a.z, a.w};
    const unsigned ub[4] = {bv.x, bv.y, bv.z, bv.w};
    const unsigned uz[4] = {zv.x, zv.y, zv.z, zv.w};
    unsigned o[4];
    #pragma unroll
    for (int w2 = 0; w2 < 4; ++w2) {
        const float ylo = __uint_as_float(ua[w2] << 16) + __uint_as_float(ub[w2] << 16);
        const float yhi = __uint_as_float(ua[w2] & 0xffff0000u) + __uint_as_float(ub[w2] & 0xffff0000u);
        const float zlo = __uint_as_float(uz[w2] << 16);
        const float zhi = __uint_as_float(uz[w2] & 0xffff0000u);
        o[w2] = (unsigned)f2bf(ylo * silu_f(zlo)) | ((unsigned)f2bf(yhi * silu_f(zhi)) << 16);
    }
    *(uint4*)(ygbf + (size_t)m * INNER + d0) = make_uint4(o[0], o[1], o[2], o[3]);
}

__global__ __launch_bounds__(256)
void report_ws_kernel(float* __restrict__ out, int n, float val)
{
    const int e = blockIdx.x * 256 + threadIdx.x;
    if (e < n) out[e] = val;
}

// ---------------------------------------------------------------------------
extern "C" void kernel_launch(void* const* d_in, const int* in_sizes, int n_in,
                              void* d_out, int out_size, void* d_ws, size_t ws_size,
                              hipStream_t stream)
{
    const float* x          = (const float*)d_in[0];
    const float* W_in       = (const float*)d_in[1];
    const float* conv_w     = (const float*)d_in[2];
    const float* conv_b     = (const float*)d_in[3];
    const float* xpw        = (const float*)d_in[4];
    const float* A_logs     = (const float*)d_in[5];
    const float* Ds         = (const float*)d_in[6];
    const float* dt_bias    = (const float*)d_in[7];
    const float* init_states= (const float*)d_in[8];
    const float* W_out      = (const float*)d_in[9];
    const float* W1         = (const float*)d_in[10];
    const float* b1         = (const float*)d_in[11];
    const float* W2         = (const float*)d_in[12];
    const float* b2         = (const float*)d_in[13];
    float* out = (float*)d_out;

    if (ws_size < (size_t)WS_REQ) {
        const float mib = (float)((double)ws_size / 1048576.0);
        report_ws_kernel<<<(out_size + 255) / 256, 256, 0, stream>>>(out, out_size, mib);
        return;
    }

    char* ws = (char*)d_ws;
    unsigned short* xlz   = (unsigned short*)(ws + WS_XLZ);
    unsigned short* xc_bf = (unsigned short*)(ws + WS_XC);
    unsigned short* y1    = (unsigned short*)(ws + WS_Y1);
    float* BCdt  = (float*)(ws + WS_BCDT);
    float* dtv   = (float*)(ws + WS_DTV);
    float* cums  = (float*)(ws + WS_CUMS);
    unsigned short* SHb   = (unsigned short*)(ws + WS_SHB);
    unsigned short* y0    = (unsigned short*)(ws + WS_Y0);
    unsigned short* x_bf  = (unsigned short*)(ws + WS_XBF);
    unsigned short* Winb  = (unsigned short*)(ws + WS_WINB);
    unsigned short* wpadb = (unsigned short*)(ws + WS_WPADB);
    unsigned short* Woutb = (unsigned short*)(ws + WS_WOUTB);
    unsigned short* W1b   = (unsigned short*)(ws + WS_W1B);
    unsigned short* W2b   = (unsigned short*)(ws + WS_W2B);
    unsigned short* yg_bf  = (unsigned short*)(ws + WS_XC);   // overlay: xc dead after intra
    unsigned short* out_bf = (unsigned short*)(ws + WS_BCDT); // overlay: BCdt dead after intra
    unsigned short* h1_bf  = (unsigned short*)(ws + WS_XLZ);  // overlay: xlz dead after gate

    const int M = BB * LL;  // 32768

    // 0) bf16 conversions (weights + x)
    cvt_kernel<<<(M * CIN + 255) / 256, 256, 0, stream>>>(x, x_bf, M * CIN);
    cvt_kernel<<<(HID * CIN + 255) / 256, 256, 0, stream>>>(W_in, Winb, HID * CIN);
    cvt_kernel<<<(HID * CIN + 255) / 256, 256, 0, stream>>>(W1, W1b, HID * CIN);
    cvt_pad_kernel<<<(128 * INNER + 255) / 256, 256, 0, stream>>>(xpw, wpadb, CPROJ, 128 * INNER, INNER);
    cvt_pad_kernel<<<(128 * INNER + 255) / 256, 256, 0, stream>>>(xpw + CPROJ * INNER, wpadb + 128 * INNER, CPROJ, 128 * INNER, INNER);
    cvt_pad_kernel<<<(256 * INNER + 255) / 256, 256, 0, stream>>>(W_out, Woutb, CIN, 256 * INNER, INNER);
    cvt_pad_kernel<<<(256 * HID + 255) / 256, 256, 0, stream>>>(W2, W2b, CIN, 256 * HID, HID);

    // 1) xlz = bf16( x @ W_in^T )   (single N=768 GEMM: xl | z)
    gemm_bf16<4,0><<<dim3(M/128, HID/128), 256, 0, stream>>>(x_bf, Winb, nullptr, nullptr, nullptr, xlz, CIN, HID, HID);

    // 2) depthwise conv + bias + SiLU -> xc_bf
    conv_dw_kernel<<<(M * INNER / 8) / 256, 256, 0, stream>>>(xlz, conv_w, conv_b, xc_bf);

    // 3) BCdt projection as two bf16 GEMMs
    gemm_bf16<0,0><<<dim3(M/128, 1), 256, 0, stream>>>(xc_bf, wpadb, nullptr, nullptr, BCdt, nullptr, INNER, 2*CPROJ, CPROJ);
    gemm_bf16<0,1><<<dim3(M/128, 1), 256, 0, stream>>>(xc_bf, wpadb + 128 * INNER, nullptr, nullptr, BCdt + CPROJ, nullptr, INNER, 2*CPROJ, CPROJ);

    // 3b) dt softplus + per-chunk cumsum
    dtcums_kernel<<<(BB * NHEADS * NC) / 4, 256, 0, stream>>>(BCdt, dt_bias, A_logs, dtv, cums);

    // 4) chunked scan (no memset, no atomics)
    chunk_state_kernel<<<dim3(NC, NHEADS, BB), 256, 0, stream>>>(xc_bf, BCdt, dtv, cums, SHb);
    state_scan_kernel<<<BB * NHEADS, 256, 0, stream>>>(SHb, cums, init_states);
    intra_kernel<<<dim3(NC, NHEADS, BB), 256, 0, stream>>>(xc_bf, BCdt, dtv, cums, SHb, Ds, y0, y1);

    // 5) gate: yg = (y0+y1) * silu(z)
    gate_kernel<<<(M * INNER / 8) / 256, 256, 0, stream>>>(y0, y1, xlz, yg_bf);

    // 5b) out = x + yg @ W_out^T   (dual write: f32 out + bf16 out_bf)
    gemm_bf16<3,0><<<dim3(M/128, 2), 256, 0, stream>>>(yg_bf, Woutb, nullptr, x, out, out_bf, INNER, CIN, CIN);

    // 6) MLP: h1_bf = bf16(silu(out @ W1^T + b1));  out += h1 @ W2^T + b2
    gemm_bf16<1,0><<<dim3(M/128, HID/128), 256, 0, stream>>>(out_bf, W1b, b1, nullptr, nullptr, h1_bf, CIN, HID, HID);
    gemm_bf16<2,0><<<dim3(M/128, 2), 256, 0, stream>>>(h1_bf, W2b, b2, out, out, nullptr, HID, CIN, CIN);
}

// Round 11
// 299.424 us; speedup vs baseline: 10.7757x; 1.1086x over previous
//
#include <hip/hip_runtime.h>
#include <math.h>

#define BB 8
#define HH 64
#define WW 64
#define CIN 192
#define INNER 384
#define LL 4096          // HH*WW
#define NSTATE 32
#define PDIM 64
#define NHK 6            // INNER/PDIM
#define NHEADS 12        // 2*NHK
#define HID 768
#define CPROJ 70         // 2*NSTATE + NHK
#define QC 64            // chunk length
#define NC 64            // LL/QC chunks

// workspace layout (bytes)
#define WS_XLZ   0u                   // bf16 xlz (B,L,768) 50331648 ; h1_bf overlay after gate
#define WS_XC    50331648u            // bf16 xc (B,L,384) 25165824 ; yg_bf overlay after intra
#define WS_Y1    75497472u            // bf16 y1 (B,L,384) 25165824
#define WS_BCDT  100663296u           // (B,L,2,70) f32 18350080 ; out_bf overlay after intra
#define WS_DTV   119013376u           // (B,L,12) f32 1572864
#define WS_CUMS  120586240u           // (B,L,12) f32 1572864
#define WS_SHB   122159104u           // bf16 SH (B,NH,NC,P,N) 25165824
#define WS_Y0    147324928u           // bf16 y0 (B,L,384) 25165824
#define WS_XBF   172490752u           // (M,192) bf16 12582912 (dead after in_proj)
#define WS_WINB  185073664u           // W_in bf16 768x192      294912
#define WS_WPADB 185368576u           // xpw padded bf16 2x128x384 196608
#define WS_WOUTB 185565184u           // W_out padded bf16 256x384 196608
#define WS_W1B   185761792u           // W1 bf16 768x192        294912
#define WS_W2B   186056704u           // W2 padded bf16 256x768 393216
#define WS_REQ   186449920u

typedef __attribute__((ext_vector_type(8))) short short8;
typedef __attribute__((ext_vector_type(4))) float f32x4;

__device__ __forceinline__ float silu_f(float x) { return x / (1.f + __expf(-x)); }

__device__ __forceinline__ unsigned short f2bf(float f) {
    unsigned u = __float_as_uint(f);
    u += 0x7fffu + ((u >> 16) & 1u);
    return (unsigned short)(u >> 16);
}
__device__ __forceinline__ float bf2f(unsigned short u) {
    return __uint_as_float(((unsigned)u) << 16);
}

// ---------------------------------------------------------------------------
// bf16 MFMA GEMM: C[m,n] = sum_k A[m,k]*Wt[n,k].  A,Wt bf16; acc f32.
// 128x128 tile, BK=64, 4 waves x (64x64), mfma_f32_16x16x32_bf16.
// EPI: 0 Cf=acc; 1 Cb=bf16(silu(acc+bias)); 2 Cf=acc+bias+res; 3 Cf=acc+res & Cb;
//      4 Cb=bf16(acc).
// ---------------------------------------------------------------------------
template<int EPI, int TRANSA>
__global__ __launch_bounds__(256)
void gemm_bf16(const unsigned short* __restrict__ A, const unsigned short* __restrict__ Wt,
               const float* __restrict__ bias, const float* __restrict__ res,
               float* __restrict__ Cf, unsigned short* __restrict__ Cb,
               int Kd, int ldc, int nmax)
{
    __shared__ __align__(16) short Als[128 * 64];
    __shared__ __align__(16) short Bls[128 * 64];
    const int tid = threadIdx.x;
    const int m0 = blockIdx.x * 128;
    const int n0 = blockIdx.y * 128;
    const int lane = tid & 63;
    const int wv = tid >> 6;
    const int wm = (wv >> 1) << 6;
    const int wn = (wv & 1) << 6;

    const unsigned short* gA[4];
    const unsigned short* gB[4];
    int lw[4];
    #pragma unroll
    for (int c = 0; c < 4; ++c) {
        const int idx = c * 256 + tid;
        const int row = idx >> 3;
        const int kb  = idx & 7;
        const int sb  = kb ^ (row & 7);
        lw[c] = row * 64 + sb * 8;
        size_t arow;
        const int mm = m0 + row;
        if (TRANSA) {
            const int bq = mm >> 12, lq = mm & 4095;
            arow = ((size_t)bq << 12) + (size_t)(((lq & 63) << 6) + (lq >> 6));
        } else {
            arow = (size_t)mm;
        }
        gA[c] = A + arow * Kd + kb * 8;
        gB[c] = Wt + (size_t)(n0 + row) * Kd + kb * 8;
    }

    f32x4 acc[4][4];
    #pragma unroll
    for (int i = 0; i < 4; ++i)
        #pragma unroll
        for (int j = 0; j < 4; ++j) acc[i][j] = (f32x4){0.f, 0.f, 0.f, 0.f};

    const int NT = Kd >> 6;
    short8 pA[4], pB[4];
    #pragma unroll
    for (int c = 0; c < 4; ++c) {
        pA[c] = *(const short8*)(gA[c]);
        pB[c] = *(const short8*)(gB[c]);
    }
    for (int kt = 0; kt < NT; ++kt) {
        __syncthreads();
        #pragma unroll
        for (int c = 0; c < 4; ++c) {
            *(short8*)&Als[lw[c]] = pA[c];
            *(short8*)&Bls[lw[c]] = pB[c];
        }
        __syncthreads();
        if (kt + 1 < NT) {
            #pragma unroll
            for (int c = 0; c < 4; ++c) {
                pA[c] = *(const short8*)(gA[c] + (kt + 1) * 64);
                pB[c] = *(const short8*)(gB[c] + (kt + 1) * 64);
            }
        }
        #pragma unroll
        for (int ks = 0; ks < 2; ++ks) {
            short8 af[4], bfr[4];
            #pragma unroll
            for (int r = 0; r < 4; ++r) {
                const int rowa = wm + r * 16 + (lane & 15);
                const int rowb = wn + r * 16 + (lane & 15);
                const int kb = ks * 4 + (lane >> 4);
                af[r]  = *(const short8*)&Als[rowa * 64 + ((kb ^ (rowa & 7)) << 3)];
                bfr[r] = *(const short8*)&Bls[rowb * 64 + ((kb ^ (rowb & 7)) << 3)];
            }
            #pragma unroll
            for (int mr = 0; mr < 4; ++mr)
                #pragma unroll
                for (int nr = 0; nr < 4; ++nr)
                    acc[mr][nr] = __builtin_amdgcn_mfma_f32_16x16x32_bf16(af[mr], bfr[nr], acc[mr][nr], 0, 0, 0);
        }
    }
    #pragma unroll
    for (int mr = 0; mr < 4; ++mr) {
        #pragma unroll
        for (int nr = 0; nr < 4; ++nr) {
            const int n = n0 + wn + nr * 16 + (lane & 15);
            if (n >= nmax) continue;
            const int mb = m0 + wm + mr * 16 + ((lane >> 4) << 2);
            #pragma unroll
            for (int q = 0; q < 4; ++q) {
                const size_t off = (size_t)(mb + q) * ldc + n;
                float v = acc[mr][nr][q];
                if (EPI == 0) { Cf[off] = v; }
                else if (EPI == 1) { v = silu_f(v + bias[n]); Cb[off] = f2bf(v); }
                else if (EPI == 2) { v += bias[n] + res[off]; Cf[off] = v; }
                else if (EPI == 3) { v += res[off]; Cf[off] = v; Cb[off] = f2bf(v); }
                else if (EPI == 4) { Cb[off] = f2bf(v); }
            }
        }
    }
}

// ---------------------------------------------------------------------------
// f32 -> bf16 converters (flat / row-padded with zeros)
// ---------------------------------------------------------------------------
__global__ __launch_bounds__(256)
void cvt_kernel(const float* __restrict__ src, unsigned short* __restrict__ dst, int n)
{
    const int i = blockIdx.x * 256 + threadIdx.x;
    if (i < n) dst[i] = f2bf(src[i]);
}

__global__ __launch_bounds__(256)
void cvt_pad_kernel(const float* __restrict__ src, unsigned short* __restrict__ dst,
                    int srcRows, int total, int cols)
{
    const int i = blockIdx.x * 256 + threadIdx.x;
    if (i >= total) return;
    const int r = i / cols;
    dst[i] = (r < srcRows) ? f2bf(src[i]) : (unsigned short)0;
}

// ---------------------------------------------------------------------------
// Depthwise 3x3 conv + bias + SiLU, 8 channels/thread, bf16 in/out.
// xlz (B,L,768), channels 0..383 -> xc_bf (B,L,384)
// ---------------------------------------------------------------------------
__global__ __launch_bounds__(256)
void conv_dw_kernel(const unsigned short* __restrict__ xlz, const float* __restrict__ cw,
                    const float* __restrict__ cb, unsigned short* __restrict__ xcbf)
{
    const int t = blockIdx.x * 256 + threadIdx.x;     // < M * 48
    const int dv = t % (INNER / 8);
    const int m  = t / (INNER / 8);
    const int b = m >> 12;
    const int r = m & 4095;
    const int i = r >> 6;
    const int j = r & 63;
    const int d0 = dv * 8;

    float wreg[72];
    {
        const float4* w4 = (const float4*)(cw + d0 * 9);
        #pragma unroll
        for (int u = 0; u < 18; ++u) {
            const float4 v = w4[u];
            wreg[4*u+0] = v.x; wreg[4*u+1] = v.y; wreg[4*u+2] = v.z; wreg[4*u+3] = v.w;
        }
    }
    float acc[8];
    {
        const float4 b0 = *(const float4*)(cb + d0);
        const float4 b1 = *(const float4*)(cb + d0 + 4);
        acc[0]=b0.x; acc[1]=b0.y; acc[2]=b0.z; acc[3]=b0.w;
        acc[4]=b1.x; acc[5]=b1.y; acc[6]=b1.z; acc[7]=b1.w;
    }
    #pragma unroll
    for (int di = 0; di < 3; ++di) {
        const int ii = i + di - 1;
        if (ii < 0 || ii >= HH) continue;
        #pragma unroll
        for (int dj = 0; dj < 3; ++dj) {
            const int jj = j + dj - 1;
            if (jj < 0 || jj >= WW) continue;
            const uint4 v = *(const uint4*)(xlz + (((size_t)b << 12) + (size_t)(ii * 64 + jj)) * 768 + d0);
            const int t9 = di * 3 + dj;
            const unsigned ua[4] = {v.x, v.y, v.z, v.w};
            #pragma unroll
            for (int w2 = 0; w2 < 4; ++w2) {
                const float xlo = __uint_as_float(ua[w2] << 16);
                const float xhi = __uint_as_float(ua[w2] & 0xffff0000u);
                acc[2*w2+0] = fmaf(xlo, wreg[(2*w2+0)*9 + t9], acc[2*w2+0]);
                acc[2*w2+1] = fmaf(xhi, wreg[(2*w2+1)*9 + t9], acc[2*w2+1]);
            }
        }
    }
    unsigned o[4];
    #pragma unroll
    for (int w2 = 0; w2 < 4; ++w2) {
        const unsigned lo = f2bf(silu_f(acc[2*w2+0]));
        const unsigned hi = f2bf(silu_f(acc[2*w2+1]));
        o[w2] = lo | (hi << 16);
    }
    *(uint4*)(xcbf + (size_t)m * INNER + d0) = make_uint4(o[0], o[1], o[2], o[3]);
}

// ---------------------------------------------------------------------------
// dtv = softplus(dt_raw + dt_bias[h]); cums = per-chunk inclusive prefix sum
// ---------------------------------------------------------------------------
__global__ __launch_bounds__(256)
void dtcums_kernel(const float* __restrict__ BCdt, const float* __restrict__ dt_bias,
                   const float* __restrict__ A_logs,
                   float* __restrict__ dtv, float* __restrict__ cums)
{
    const int w = blockIdx.x * 4 + (threadIdx.x >> 6);
    const int lane = threadIdx.x & 63;
    const int b = w / (NHEADS * NC);
    const int rem = w - b * (NHEADS * NC);
    const int h = rem / NC;
    const int c = rem - h * NC;
    const int k = h / NHK;
    const int hq = h - k * NHK;
    const int l = c * QC + lane;
    const float dtraw = BCdt[(((size_t)b * LL + l) * 2 + k) * CPROJ + 2*NSTATE + hq];
    const float xx = dtraw + dt_bias[h];
    const float sp = (xx > 20.f) ? xx : log1pf(expf(xx));
    float s = -expf(A_logs[h]) * sp;
    #pragma unroll
    for (int d = 1; d < 64; d <<= 1) {
        const float o = __shfl_up(s, d);
        if (lane >= d) s += o;
    }
    dtv[((size_t)b * LL + l) * NHEADS + h] = sp;
    cums[((size_t)b * LL + l) * NHEADS + h] = s;
}

// ---------------------------------------------------------------------------
// Chunk states via bf16 MFMA: S_c[p,n] = sum_m (rs[m]*x[m][p]) * B[m][n]
// rs folded into the B operand.  4 MFMAs per wave (p-tile), D-layout store.
// ---------------------------------------------------------------------------
__global__ __launch_bounds__(256)
void chunk_state_kernel(const unsigned short* __restrict__ xcbf, const float* __restrict__ BCdt,
                        const float* __restrict__ dtv, const float* __restrict__ cums,
                        unsigned short* __restrict__ SHb)
{
    __shared__ __align__(16) unsigned short Xb[PDIM][72];    // [p][m]  (X^T)
    __shared__ __align__(16) unsigned short Bsc[NSTATE][72]; // [n][m]  (rs[m]*B^T)
    __shared__ float cuS[QC], rs[QC];
    const int c = blockIdx.x, h = blockIdx.y, b = blockIdx.z;
    const int k = h / NHK;
    const int dch0 = (h - k * NHK) * PDIM;
    const int tid = threadIdx.x;
    const int lane = tid & 63;
    const int w = tid >> 6;

    #pragma unroll
    for (int r = 0; r < 16; ++r) {
        const int idx = tid + r * 256;
        const int m = idx >> 6, p = idx & 63;
        const int pos = (k == 0) ? (c * QC + m) : (m * QC + c);
        Xb[p][m] = xcbf[(((size_t)b << 12) + pos) * INNER + dch0 + p];
    }
    if (tid < QC)
        cuS[tid] = cums[((size_t)b * LL + c * QC + tid) * NHEADS + h];
    __syncthreads();
    if (tid < QC)
        rs[tid] = dtv[((size_t)b * LL + c * QC + tid) * NHEADS + h] * __expf(cuS[QC-1] - cuS[tid]);
    __syncthreads();
    #pragma unroll
    for (int r = 0; r < 8; ++r) {
        const int idx = tid + r * 256;
        const int m = idx >> 5, n = idx & 31;
        Bsc[n][m] = f2bf(rs[m] * BCdt[(((size_t)b * LL + c * QC + m) * 2 + k) * CPROJ + n]);
    }
    __syncthreads();

    const int rowf = lane & 15;
    const int ko   = lane >> 4;
    f32x4 acc[2] = {{0.f,0.f,0.f,0.f},{0.f,0.f,0.f,0.f}};
    #pragma unroll
    for (int ks = 0; ks < 2; ++ks) {
        const short8 af = *(const short8*)&Xb[w * 16 + rowf][ks * 32 + ko * 8];
        #pragma unroll
        for (int nt = 0; nt < 2; ++nt) {
            const short8 bfr = *(const short8*)&Bsc[nt * 16 + rowf][ks * 32 + ko * 8];
            acc[nt] = __builtin_amdgcn_mfma_f32_16x16x32_bf16(af, bfr, acc[nt], 0, 0, 0);
        }
    }
    unsigned short* base = SHb + ((((size_t)b * NHEADS + h) * NC + c) * PDIM) * NSTATE;
    #pragma unroll
    for (int nt = 0; nt < 2; ++nt) {
        #pragma unroll
        for (int q = 0; q < 4; ++q) {
            const int p = w * 16 + ko * 4 + q;
            base[p * NSTATE + nt * 16 + rowf] = f2bf(acc[nt][q]);
        }
    }
}

// ---------------------------------------------------------------------------
// Sequential scan over chunks (in place, bf16 slots, f32 running state).
// ---------------------------------------------------------------------------
__global__ __launch_bounds__(256)
void state_scan_kernel(unsigned short* __restrict__ SHb, const float* __restrict__ cums,
                       const float* __restrict__ init_states)
{
    __shared__ float decays[NC];
    const int b = blockIdx.x / NHEADS;
    const int h = blockIdx.x % NHEADS;
    const int tid = threadIdx.x;
    if (tid < NC)
        decays[tid] = __expf(cums[((size_t)b * LL + tid * QC + QC - 1) * NHEADS + h]);
    __syncthreads();
    const int p = tid >> 2;
    const int nb = (tid & 3) * 8;
    float hs[8];
    {
        const float* is = init_states + ((size_t)h * PDIM + p) * NSTATE + nb;
        #pragma unroll
        for (int i = 0; i < 8; ++i) hs[i] = is[i];
    }
    unsigned short* base = SHb + (((size_t)b * NHEADS + h) * NC) * (PDIM * NSTATE) + p * NSTATE + nb;
    for (int c = 0; c < NC; ++c) {
        unsigned short* slot = base + (size_t)c * (PDIM * NSTATE);
        const uint4 sv = *(const uint4*)slot;
        const unsigned ua[4] = {sv.x, sv.y, sv.z, sv.w};
        unsigned o[4];
        #pragma unroll
        for (int w2 = 0; w2 < 4; ++w2)
            o[w2] = (unsigned)f2bf(hs[2*w2]) | ((unsigned)f2bf(hs[2*w2+1]) << 16);
        *(uint4*)slot = make_uint4(o[0], o[1], o[2], o[3]);
        const float dc = decays[c];
        #pragma unroll
        for (int w2 = 0; w2 < 4; ++w2) {
            hs[2*w2+0] = fmaf(dc, hs[2*w2+0], __uint_as_float(ua[w2] << 16));
            hs[2*w2+1] = fmaf(dc, hs[2*w2+1], __uint_as_float(ua[w2] & 0xffff0000u));
        }
    }
}

// ---------------------------------------------------------------------------
// Intra-chunk + inter-chunk + D term via bf16 MFMA.  grid (NC, NHEADS, BB).
// Direct bf16 stores to y0/y1 — no atomics.  Bs/Cs/Hs stride 40 (conflict-free).
// ---------------------------------------------------------------------------
__global__ __launch_bounds__(256)
void intra_kernel(const unsigned short* __restrict__ xcbf, const float* __restrict__ BCdt,
                  const float* __restrict__ dtv, const float* __restrict__ cums,
                  const unsigned short* __restrict__ SHb, const float* __restrict__ Ds,
                  unsigned short* __restrict__ y0, unsigned short* __restrict__ y1)
{
    __shared__ __align__(16) unsigned short Bs[QC][40];    // [m][n]
    __shared__ __align__(16) unsigned short Cs[QC][40];    // [i][n]
    __shared__ __align__(16) unsigned short Hs[PDIM][40];  // [p][n]
    __shared__ __align__(16) unsigned short Xb[PDIM][72];  // [p][m]  (X^T)
    __shared__ __align__(16) unsigned short Gb[QC][72];    // [i][m]
    __shared__ float cuS[QC], dtS[QC], Ei[QC];
    const int c = blockIdx.x, h = blockIdx.y, b = blockIdx.z;
    const int k = h / NHK;
    const int dch0 = (h - k * NHK) * PDIM;
    const int tid = threadIdx.x;
    const int lane = tid & 63;
    const int w = tid >> 6;

    #pragma unroll
    for (int r = 0; r < 16; ++r) {
        const int idx = tid + r * 256;
        const int m = idx >> 6, p = idx & 63;
        const int pos = (k == 0) ? (c * QC + m) : (m * QC + c);
        Xb[p][m] = xcbf[(((size_t)b << 12) + pos) * INNER + dch0 + p];
    }
    #pragma unroll
    for (int r = 0; r < 16; ++r) {
        const int idx = tid + r * 256;
        const int i = idx >> 6, q = idx & 63;
        const float v = BCdt[(((size_t)b * LL + c * QC + i) * 2 + k) * CPROJ + q];
        if (q < NSTATE) Bs[i][q] = f2bf(v); else Cs[i][q - NSTATE] = f2bf(v);
    }
    #pragma unroll
    for (int r = 0; r < 8; ++r) {
        const int idx = tid + r * 256;
        const int p = idx >> 5, n = idx & 31;
        Hs[p][n] = SHb[((((size_t)b * NHEADS + h) * NC + c) * PDIM + p) * NSTATE + n];
    }
    if (tid < QC) {
        const size_t o = ((size_t)b * LL + c * QC + tid) * NHEADS + h;
        const float cu = cums[o];
        cuS[tid] = cu;
        dtS[tid] = dtv[o];
        Ei[tid]  = __expf(cu);
    }
    __syncthreads();

    const int rowf = lane & 15;
    const int ko   = lane >> 4;
    const short8 cfrag = *(const short8*)&Cs[w * 16 + rowf][ko * 8];

    // matmul1: G_raw tiles (it=w, mt=0..3)
    f32x4 graw[4];
    #pragma unroll
    for (int mt = 0; mt < 4; ++mt) {
        const short8 bfrag = *(const short8*)&Bs[mt * 16 + rowf][ko * 8];
        graw[mt] = __builtin_amdgcn_mfma_f32_16x16x32_bf16(cfrag, bfrag, (f32x4){0.f,0.f,0.f,0.f}, 0, 0, 0);
    }
    #pragma unroll
    for (int mt = 0; mt < 4; ++mt) {
        const int m = mt * 16 + rowf;
        const float cum = cuS[m];
        const float dtm = dtS[m];
        #pragma unroll
        for (int q = 0; q < 4; ++q) {
            const int i = w * 16 + ko * 4 + q;
            float g = 0.f;
            if (m <= i) g = __expf(fminf(cuS[i] - cum, 0.f)) * dtm * graw[mt][q];
            Gb[i][m] = f2bf(g);
        }
    }
    // matmul2: inter tiles (it=w, pt=0..3)
    f32x4 acc[4];
    #pragma unroll
    for (int pt = 0; pt < 4; ++pt) {
        const short8 hfrag = *(const short8*)&Hs[pt * 16 + rowf][ko * 8];
        acc[pt] = __builtin_amdgcn_mfma_f32_16x16x32_bf16(cfrag, hfrag, (f32x4){0.f,0.f,0.f,0.f}, 0, 0, 0);
    }
    const float Dh = Ds[h];
    #pragma unroll
    for (int pt = 0; pt < 4; ++pt) {
        const int p = pt * 16 + rowf;
        #pragma unroll
        for (int q = 0; q < 4; ++q) {
            const int i = w * 16 + ko * 4 + q;
            acc[pt][q] = acc[pt][q] * Ei[i] + Dh * bf2f(Xb[p][i]);
        }
    }
    // matmul3: acc += G·X  (wave w reads only its own Gb rows)
    #pragma unroll
    for (int ks = 0; ks < 2; ++ks) {
        const short8 gfrag = *(const short8*)&Gb[w * 16 + rowf][ks * 32 + ko * 8];
        #pragma unroll
        for (int pt = 0; pt < 4; ++pt) {
            const short8 xfrag = *(const short8*)&Xb[pt * 16 + rowf][ks * 32 + ko * 8];
            acc[pt] = __builtin_amdgcn_mfma_f32_16x16x32_bf16(gfrag, xfrag, acc[pt], 0, 0, 0);
        }
    }
    // epilogue: direct bf16 store (exactly one writer per element per direction)
    unsigned short* yk = (k == 0) ? y0 : y1;
    #pragma unroll
    for (int pt = 0; pt < 4; ++pt) {
        const int p = pt * 16 + rowf;
        #pragma unroll
        for (int q = 0; q < 4; ++q) {
            const int i = w * 16 + ko * 4 + q;
            const int pos = (k == 0) ? (c * QC + i) : (i * QC + c);
            yk[(((size_t)b << 12) + pos) * INNER + dch0 + p] = f2bf(acc[pt][q]);
        }
    }
}

// ---------------------------------------------------------------------------
// gate: yg_bf = bf16( (y0+y1) * silu(z) ), 8 elems/thread.
// ---------------------------------------------------------------------------
__global__ __launch_bounds__(256)
void gate_kernel(const unsigned short* __restrict__ y0, const unsigned short* __restrict__ y1,
                 const unsigned short* __restrict__ xlz, unsigned short* __restrict__ ygbf)
{
    const int t = blockIdx.x * 256 + threadIdx.x;   // < M*48
    const int dv = t % (INNER / 8);
    const int m  = t / (INNER / 8);
    const int d0 = dv * 8;
    const uint4 a = *(const uint4*)(y0 + (size_t)m * INNER + d0);
    const uint4 bv = *(const uint4*)(y1 + (size_t)m * INNER + d0);
    const uint4 zv = *(const uint4*)(xlz + (size_t)m * 768 + INNER + d0);
    const unsigned ua[4] = {a.x, a.y, a.z, a.w};
    const unsigned ub[4] = {bv.x, bv.y, bv.z, bv.w};
    const unsigned uz[4] = {zv.x, zv.y, zv.z, zv.w};
    unsigned o[4];
    #pragma unroll
    for (int w2 = 0; w2 < 4; ++w2) {
        const float ylo = __uint_as_float(ua[w2] << 16) + __uint_as_float(ub[w2] << 16);
        const float yhi = __uint_as_float(ua[w2] & 0xffff0000u) + __uint_as_float(ub[w2] & 0xffff0000u);
        const float zlo = __uint_as_float(uz[w2] << 16);
        const float zhi = __uint_as_float(uz[w2] & 0xffff0000u);
        o[w2] = (unsigned)f2bf(ylo * silu_f(zlo)) | ((unsigned)f2bf(yhi * silu_f(zhi)) << 16);
    }
    *(uint4*)(ygbf + (size_t)m * INNER + d0) = make_uint4(o[0], o[1], o[2], o[3]);
}

__global__ __launch_bounds__(256)
void report_ws_kernel(float* __restrict__ out, int n, float val)
{
    const int e = blockIdx.x * 256 + threadIdx.x;
    if (e < n) out[e] = val;
}

// ---------------------------------------------------------------------------
extern "C" void kernel_launch(void* const* d_in, const int* in_sizes, int n_in,
                              void* d_out, int out_size, void* d_ws, size_t ws_size,
                              hipStream_t stream)
{
    const float* x          = (const float*)d_in[0];
    const float* W_in       = (const float*)d_in[1];
    const float* conv_w     = (const float*)d_in[2];
    const float* conv_b     = (const float*)d_in[3];
    const float* xpw        = (const float*)d_in[4];
    const float* A_logs     = (const float*)d_in[5];
    const float* Ds         = (const float*)d_in[6];
    const float* dt_bias    = (const float*)d_in[7];
    const float* init_states= (const float*)d_in[8];
    const float* W_out      = (const float*)d_in[9];
    const float* W1         = (const float*)d_in[10];
    const float* b1         = (const float*)d_in[11];
    const float* W2         = (const float*)d_in[12];
    const float* b2         = (const float*)d_in[13];
    float* out = (float*)d_out;

    if (ws_size < (size_t)WS_REQ) {
        const float mib = (float)((double)ws_size / 1048576.0);
        report_ws_kernel<<<(out_size + 255) / 256, 256, 0, stream>>>(out, out_size, mib);
        return;
    }

    char* ws = (char*)d_ws;
    unsigned short* xlz   = (unsigned short*)(ws + WS_XLZ);
    unsigned short* xc_bf = (unsigned short*)(ws + WS_XC);
    unsigned short* y1    = (unsigned short*)(ws + WS_Y1);
    float* BCdt  = (float*)(ws + WS_BCDT);
    float* dtv   = (float*)(ws + WS_DTV);
    float* cums  = (float*)(ws + WS_CUMS);
    unsigned short* SHb   = (unsigned short*)(ws + WS_SHB);
    unsigned short* y0    = (unsigned short*)(ws + WS_Y0);
    unsigned short* x_bf  = (unsigned short*)(ws + WS_XBF);
    unsigned short* Winb  = (unsigned short*)(ws + WS_WINB);
    unsigned short* wpadb = (unsigned short*)(ws + WS_WPADB);
    unsigned short* Woutb = (unsigned short*)(ws + WS_WOUTB);
    unsigned short* W1b   = (unsigned short*)(ws + WS_W1B);
    unsigned short* W2b   = (unsigned short*)(ws + WS_W2B);
    unsigned short* yg_bf  = (unsigned short*)(ws + WS_XC);   // overlay: xc dead after intra
    unsigned short* out_bf = (unsigned short*)(ws + WS_BCDT); // overlay: BCdt dead after intra
    unsigned short* h1_bf  = (unsigned short*)(ws + WS_XLZ);  // overlay: xlz dead after gate

    const int M = BB * LL;  // 32768

    // 0) bf16 conversions (weights + x)
    cvt_kernel<<<(M * CIN + 255) / 256, 256, 0, stream>>>(x, x_bf, M * CIN);
    cvt_kernel<<<(HID * CIN + 255) / 256, 256, 0, stream>>>(W_in, Winb, HID * CIN);
    cvt_kernel<<<(HID * CIN + 255) / 256, 256, 0, stream>>>(W1, W1b, HID * CIN);
    cvt_pad_kernel<<<(128 * INNER + 255) / 256, 256, 0, stream>>>(xpw, wpadb, CPROJ, 128 * INNER, INNER);
    cvt_pad_kernel<<<(128 * INNER + 255) / 256, 256, 0, stream>>>(xpw + CPROJ * INNER, wpadb + 128 * INNER, CPROJ, 128 * INNER, INNER);
    cvt_pad_kernel<<<(256 * INNER + 255) / 256, 256, 0, stream>>>(W_out, Woutb, CIN, 256 * INNER, INNER);
    cvt_pad_kernel<<<(256 * HID + 255) / 256, 256, 0, stream>>>(W2, W2b, CIN, 256 * HID, HID);

    // 1) xlz = bf16( x @ W_in^T )   (single N=768 GEMM: xl | z)
    gemm_bf16<4,0><<<dim3(M/128, HID/128), 256, 0, stream>>>(x_bf, Winb, nullptr, nullptr, nullptr, xlz, CIN, HID, HID);

    // 2) depthwise conv + bias + SiLU -> xc_bf
    conv_dw_kernel<<<(M * INNER / 8) / 256, 256, 0, stream>>>(xlz, conv_w, conv_b, xc_bf);

    // 3) BCdt projection as two bf16 GEMMs
    gemm_bf16<0,0><<<dim3(M/128, 1), 256, 0, stream>>>(xc_bf, wpadb, nullptr, nullptr, BCdt, nullptr, INNER, 2*CPROJ, CPROJ);
    gemm_bf16<0,1><<<dim3(M/128, 1), 256, 0, stream>>>(xc_bf, wpadb + 128 * INNER, nullptr, nullptr, BCdt + CPROJ, nullptr, INNER, 2*CPROJ, CPROJ);

    // 3b) dt softplus + per-chunk cumsum
    dtcums_kernel<<<(BB * NHEADS * NC) / 4, 256, 0, stream>>>(BCdt, dt_bias, A_logs, dtv, cums);

    // 4) chunked scan (no memset, no atomics)
    chunk_state_kernel<<<dim3(NC, NHEADS, BB), 256, 0, stream>>>(xc_bf, BCdt, dtv, cums, SHb);
    state_scan_kernel<<<BB * NHEADS, 256, 0, stream>>>(SHb, cums, init_states);
    intra_kernel<<<dim3(NC, NHEADS, BB), 256, 0, stream>>>(xc_bf, BCdt, dtv, cums, SHb, Ds, y0, y1);

    // 5) gate: yg = (y0+y1) * silu(z)
    gate_kernel<<<(M * INNER / 8) / 256, 256, 0, stream>>>(y0, y1, xlz, yg_bf);

    // 5b) out = x + yg @ W_out^T   (dual write: f32 out + bf16 out_bf)
    gemm_bf16<3,0><<<dim3(M/128, 2), 256, 0, stream>>>(yg_bf, Woutb, nullptr, x, out, out_bf, INNER, CIN, CIN);

    // 6) MLP: h1_bf = bf16(silu(out @ W1^T + b1));  out += h1 @ W2^T + b2
    gemm_bf16<1,0><<<dim3(M/128, HID/128), 256, 0, stream>>>(out_bf, W1b, b1, nullptr, nullptr, h1_bf, CIN, HID, HID);
    gemm_bf16<2,0><<<dim3(M/128, 2), 256, 0, stream>>>(h1_bf, W2b, b2, out, out, nullptr, HID, CIN, CIN);
}

// Round 12
// 275.872 us; speedup vs baseline: 11.6957x; 1.0854x over previous
//
#include <hip/hip_runtime.h>
#include <math.h>

#define BB 8
#define HH 64
#define WW 64
#define CIN 192
#define INNER 384
#define LL 4096          // HH*WW
#define NSTATE 32
#define PDIM 64
#define NHK 6            // INNER/PDIM
#define NHEADS 12        // 2*NHK
#define HID 768
#define CPROJ 70         // 2*NSTATE + NHK
#define QC 64            // chunk length
#define NC 64            // LL/QC chunks

// workspace layout (bytes)
#define WS_XLZ   0u                   // bf16 xlz (B,L,768) 50331648 ; h1_bf overlay after gate
#define WS_XC    50331648u            // bf16 xc (B,L,384) 25165824 ; yg_bf overlay after intra
#define WS_Y1    75497472u            // bf16 y1 (B,L,384) 25165824
#define WS_BCBF  100663296u           // bf16 BCbf (B,L,2,64) 8388608 ; out_bf overlay after intra
#define WS_DTRAW 109051904u           // f32 dtraw (B,L,2,6) 1572864 (dead after dtcums)
#define WS_DTV   119013376u           // (B,L,12) f32 1572864
#define WS_CUMS  120586240u           // (B,L,12) f32 1572864
#define WS_SHB   122159104u           // bf16 SH (B,NH,NC,P,N) 25165824
#define WS_Y0    147324928u           // bf16 y0 (B,L,384) 25165824
#define WS_XBF   172490752u           // (M,192) bf16 12582912 (dead after in_proj)
#define WS_WINB  185073664u           // W_in bf16 768x192      294912
#define WS_WPADB 185368576u           // xpw padded bf16 2x128x384 196608
#define WS_WOUTB 185565184u           // W_out padded bf16 256x384 196608
#define WS_W1B   185761792u           // W1 bf16 768x192        294912
#define WS_W2B   186056704u           // W2 padded bf16 256x768 393216
#define WS_REQ   186449920u

typedef __attribute__((ext_vector_type(8))) short short8;
typedef __attribute__((ext_vector_type(4))) float f32x4;

__device__ __forceinline__ float silu_f(float x) { return x / (1.f + __expf(-x)); }

__device__ __forceinline__ unsigned short f2bf(float f) {
    unsigned u = __float_as_uint(f);
    u += 0x7fffu + ((u >> 16) & 1u);
    return (unsigned short)(u >> 16);
}
__device__ __forceinline__ float bf2f(unsigned short u) {
    return __uint_as_float(((unsigned)u) << 16);
}

// ---------------------------------------------------------------------------
// bf16 MFMA GEMM: C[m,n] = sum_k A[m,k]*Wt[n,k].  A,Wt bf16; acc f32.
// 128x128 tile, BK=64, 4 waves x (64x64), mfma_f32_16x16x32_bf16.
// EPI: 0 Cf=acc; 1 Cb=bf16(silu(acc+bias)); 2 Cf=acc+bias+res; 3 Cf=acc+res & Cb;
//      4 Cb=bf16(acc); 5 split: n<64 -> Cb bf16 (stride 128), 64<=n<nmax -> Cf f32 (stride 12).
// ---------------------------------------------------------------------------
template<int EPI, int TRANSA>
__global__ __launch_bounds__(256)
void gemm_bf16(const unsigned short* __restrict__ A, const unsigned short* __restrict__ Wt,
               const float* __restrict__ bias, const float* __restrict__ res,
               float* __restrict__ Cf, unsigned short* __restrict__ Cb,
               int Kd, int ldc, int nmax)
{
    __shared__ __align__(16) short Als[128 * 64];
    __shared__ __align__(16) short Bls[128 * 64];
    const int tid = threadIdx.x;
    const int m0 = blockIdx.x * 128;
    const int n0 = blockIdx.y * 128;
    const int lane = tid & 63;
    const int wv = tid >> 6;
    const int wm = (wv >> 1) << 6;
    const int wn = (wv & 1) << 6;

    const unsigned short* gA[4];
    const unsigned short* gB[4];
    int lw[4];
    #pragma unroll
    for (int c = 0; c < 4; ++c) {
        const int idx = c * 256 + tid;
        const int row = idx >> 3;
        const int kb  = idx & 7;
        const int sb  = kb ^ (row & 7);
        lw[c] = row * 64 + sb * 8;
        size_t arow;
        const int mm = m0 + row;
        if (TRANSA) {
            const int bq = mm >> 12, lq = mm & 4095;
            arow = ((size_t)bq << 12) + (size_t)(((lq & 63) << 6) + (lq >> 6));
        } else {
            arow = (size_t)mm;
        }
        gA[c] = A + arow * Kd + kb * 8;
        gB[c] = Wt + (size_t)(n0 + row) * Kd + kb * 8;
    }

    f32x4 acc[4][4];
    #pragma unroll
    for (int i = 0; i < 4; ++i)
        #pragma unroll
        for (int j = 0; j < 4; ++j) acc[i][j] = (f32x4){0.f, 0.f, 0.f, 0.f};

    const int NT = Kd >> 6;
    short8 pA[4], pB[4];
    #pragma unroll
    for (int c = 0; c < 4; ++c) {
        pA[c] = *(const short8*)(gA[c]);
        pB[c] = *(const short8*)(gB[c]);
    }
    for (int kt = 0; kt < NT; ++kt) {
        __syncthreads();
        #pragma unroll
        for (int c = 0; c < 4; ++c) {
            *(short8*)&Als[lw[c]] = pA[c];
            *(short8*)&Bls[lw[c]] = pB[c];
        }
        __syncthreads();
        if (kt + 1 < NT) {
            #pragma unroll
            for (int c = 0; c < 4; ++c) {
                pA[c] = *(const short8*)(gA[c] + (kt + 1) * 64);
                pB[c] = *(const short8*)(gB[c] + (kt + 1) * 64);
            }
        }
        #pragma unroll
        for (int ks = 0; ks < 2; ++ks) {
            short8 af[4], bfr[4];
            #pragma unroll
            for (int r = 0; r < 4; ++r) {
                const int rowa = wm + r * 16 + (lane & 15);
                const int rowb = wn + r * 16 + (lane & 15);
                const int kb = ks * 4 + (lane >> 4);
                af[r]  = *(const short8*)&Als[rowa * 64 + ((kb ^ (rowa & 7)) << 3)];
                bfr[r] = *(const short8*)&Bls[rowb * 64 + ((kb ^ (rowb & 7)) << 3)];
            }
            #pragma unroll
            for (int mr = 0; mr < 4; ++mr)
                #pragma unroll
                for (int nr = 0; nr < 4; ++nr)
                    acc[mr][nr] = __builtin_amdgcn_mfma_f32_16x16x32_bf16(af[mr], bfr[nr], acc[mr][nr], 0, 0, 0);
        }
    }
    #pragma unroll
    for (int mr = 0; mr < 4; ++mr) {
        #pragma unroll
        for (int nr = 0; nr < 4; ++nr) {
            const int n = n0 + wn + nr * 16 + (lane & 15);
            if (n >= nmax) continue;
            const int mb = m0 + wm + mr * 16 + ((lane >> 4) << 2);
            #pragma unroll
            for (int q = 0; q < 4; ++q) {
                const size_t off = (size_t)(mb + q) * ldc + n;
                float v = acc[mr][nr][q];
                if (EPI == 0) { Cf[off] = v; }
                else if (EPI == 1) { v = silu_f(v + bias[n]); Cb[off] = f2bf(v); }
                else if (EPI == 2) { v += bias[n] + res[off]; Cf[off] = v; }
                else if (EPI == 3) { v += res[off]; Cf[off] = v; Cb[off] = f2bf(v); }
                else if (EPI == 4) { Cb[off] = f2bf(v); }
                else if (EPI == 5) {
                    if (n < 64) Cb[(size_t)(mb + q) * 128 + n] = f2bf(v);
                    else        Cf[(size_t)(mb + q) * 12 + (n - 64)] = v;
                }
            }
        }
    }
}

// ---------------------------------------------------------------------------
// f32 -> bf16 converters (flat / row-padded with zeros)
// ---------------------------------------------------------------------------
__global__ __launch_bounds__(256)
void cvt_kernel(const float* __restrict__ src, unsigned short* __restrict__ dst, int n)
{
    const int i = blockIdx.x * 256 + threadIdx.x;
    if (i < n) dst[i] = f2bf(src[i]);
}

__global__ __launch_bounds__(256)
void cvt_pad_kernel(const float* __restrict__ src, unsigned short* __restrict__ dst,
                    int srcRows, int total, int cols)
{
    const int i = blockIdx.x * 256 + threadIdx.x;
    if (i >= total) return;
    const int r = i / cols;
    dst[i] = (r < srcRows) ? f2bf(src[i]) : (unsigned short)0;
}

// ---------------------------------------------------------------------------
// Depthwise 3x3 conv + bias + SiLU, 8 channels/thread, bf16 in/out.
// ---------------------------------------------------------------------------
__global__ __launch_bounds__(256)
void conv_dw_kernel(const unsigned short* __restrict__ xlz, const float* __restrict__ cw,
                    const float* __restrict__ cb, unsigned short* __restrict__ xcbf)
{
    const int t = blockIdx.x * 256 + threadIdx.x;     // < M * 48
    const int dv = t % (INNER / 8);
    const int m  = t / (INNER / 8);
    const int b = m >> 12;
    const int r = m & 4095;
    const int i = r >> 6;
    const int j = r & 63;
    const int d0 = dv * 8;

    float wreg[72];
    {
        const float4* w4 = (const float4*)(cw + d0 * 9);
        #pragma unroll
        for (int u = 0; u < 18; ++u) {
            const float4 v = w4[u];
            wreg[4*u+0] = v.x; wreg[4*u+1] = v.y; wreg[4*u+2] = v.z; wreg[4*u+3] = v.w;
        }
    }
    float acc[8];
    {
        const float4 b0 = *(const float4*)(cb + d0);
        const float4 b1 = *(const float4*)(cb + d0 + 4);
        acc[0]=b0.x; acc[1]=b0.y; acc[2]=b0.z; acc[3]=b0.w;
        acc[4]=b1.x; acc[5]=b1.y; acc[6]=b1.z; acc[7]=b1.w;
    }
    #pragma unroll
    for (int di = 0; di < 3; ++di) {
        const int ii = i + di - 1;
        if (ii < 0 || ii >= HH) continue;
        #pragma unroll
        for (int dj = 0; dj < 3; ++dj) {
            const int jj = j + dj - 1;
            if (jj < 0 || jj >= WW) continue;
            const uint4 v = *(const uint4*)(xlz + (((size_t)b << 12) + (size_t)(ii * 64 + jj)) * 768 + d0);
            const int t9 = di * 3 + dj;
            const unsigned ua[4] = {v.x, v.y, v.z, v.w};
            #pragma unroll
            for (int w2 = 0; w2 < 4; ++w2) {
                const float xlo = __uint_as_float(ua[w2] << 16);
                const float xhi = __uint_as_float(ua[w2] & 0xffff0000u);
                acc[2*w2+0] = fmaf(xlo, wreg[(2*w2+0)*9 + t9], acc[2*w2+0]);
                acc[2*w2+1] = fmaf(xhi, wreg[(2*w2+1)*9 + t9], acc[2*w2+1]);
            }
        }
    }
    unsigned o[4];
    #pragma unroll
    for (int w2 = 0; w2 < 4; ++w2) {
        const unsigned lo = f2bf(silu_f(acc[2*w2+0]));
        const unsigned hi = f2bf(silu_f(acc[2*w2+1]));
        o[w2] = lo | (hi << 16);
    }
    *(uint4*)(xcbf + (size_t)m * INNER + d0) = make_uint4(o[0], o[1], o[2], o[3]);
}

// ---------------------------------------------------------------------------
// dtv = softplus(dtraw + dt_bias[h]); cums = per-chunk inclusive prefix sum
// dtraw layout (B,L,2,6).
// ---------------------------------------------------------------------------
__global__ __launch_bounds__(256)
void dtcums_kernel(const float* __restrict__ dtraw, const float* __restrict__ dt_bias,
                   const float* __restrict__ A_logs,
                   float* __restrict__ dtv, float* __restrict__ cums)
{
    const int w = blockIdx.x * 4 + (threadIdx.x >> 6);
    const int lane = threadIdx.x & 63;
    const int b = w / (NHEADS * NC);
    const int rem = w - b * (NHEADS * NC);
    const int h = rem / NC;
    const int c = rem - h * NC;
    const int k = h / NHK;
    const int hq = h - k * NHK;
    const int l = c * QC + lane;
    const float dtr = dtraw[(((size_t)b * LL + l) * 2 + k) * 6 + hq];
    const float xx = dtr + dt_bias[h];
    const float sp = (xx > 20.f) ? xx : log1pf(expf(xx));
    float s = -expf(A_logs[h]) * sp;
    #pragma unroll
    for (int d = 1; d < 64; d <<= 1) {
        const float o = __shfl_up(s, d);
        if (lane >= d) s += o;
    }
    dtv[((size_t)b * LL + l) * NHEADS + h] = sp;
    cums[((size_t)b * LL + l) * NHEADS + h] = s;
}

// ---------------------------------------------------------------------------
// Chunk states via bf16 MFMA: S_c[p,n] = sum_m (rs[m]*x[m][p]) * B[m][n]
// ---------------------------------------------------------------------------
__global__ __launch_bounds__(256)
void chunk_state_kernel(const unsigned short* __restrict__ xcbf, const unsigned short* __restrict__ BCbf,
                        const float* __restrict__ dtv, const float* __restrict__ cums,
                        unsigned short* __restrict__ SHb)
{
    __shared__ __align__(16) unsigned short Xb[PDIM][72];    // [p][m]  (X^T)
    __shared__ __align__(16) unsigned short Bsc[NSTATE][72]; // [n][m]  (rs[m]*B^T)
    __shared__ float cuS[QC], rs[QC];
    const int c = blockIdx.x, h = blockIdx.y, b = blockIdx.z;
    const int k = h / NHK;
    const int dch0 = (h - k * NHK) * PDIM;
    const int tid = threadIdx.x;
    const int lane = tid & 63;
    const int w = tid >> 6;

    #pragma unroll
    for (int r = 0; r < 16; ++r) {
        const int idx = tid + r * 256;
        const int m = idx >> 6, p = idx & 63;
        const int pos = (k == 0) ? (c * QC + m) : (m * QC + c);
        Xb[p][m] = xcbf[(((size_t)b << 12) + pos) * INNER + dch0 + p];
    }
    if (tid < QC)
        cuS[tid] = cums[((size_t)b * LL + c * QC + tid) * NHEADS + h];
    __syncthreads();
    if (tid < QC)
        rs[tid] = dtv[((size_t)b * LL + c * QC + tid) * NHEADS + h] * __expf(cuS[QC-1] - cuS[tid]);
    __syncthreads();
    #pragma unroll
    for (int r = 0; r < 8; ++r) {
        const int idx = tid + r * 256;
        const int m = idx >> 5, n = idx & 31;
        Bsc[n][m] = f2bf(rs[m] * bf2f(BCbf[(((size_t)b * LL + c * QC + m) * 2 + k) * 64 + n]));
    }
    __syncthreads();

    const int rowf = lane & 15;
    const int ko   = lane >> 4;
    f32x4 acc[2] = {{0.f,0.f,0.f,0.f},{0.f,0.f,0.f,0.f}};
    #pragma unroll
    for (int ks = 0; ks < 2; ++ks) {
        const short8 af = *(const short8*)&Xb[w * 16 + rowf][ks * 32 + ko * 8];
        #pragma unroll
        for (int nt = 0; nt < 2; ++nt) {
            const short8 bfr = *(const short8*)&Bsc[nt * 16 + rowf][ks * 32 + ko * 8];
            acc[nt] = __builtin_amdgcn_mfma_f32_16x16x32_bf16(af, bfr, acc[nt], 0, 0, 0);
        }
    }
    unsigned short* base = SHb + ((((size_t)b * NHEADS + h) * NC + c) * PDIM) * NSTATE;
    #pragma unroll
    for (int nt = 0; nt < 2; ++nt) {
        #pragma unroll
        for (int q = 0; q < 4; ++q) {
            const int p = w * 16 + ko * 4 + q;
            base[p * NSTATE + nt * 16 + rowf] = f2bf(acc[nt][q]);
        }
    }
}

// ---------------------------------------------------------------------------
// Sequential scan over chunks (in place, bf16 slots, f32 running state).
// 384 blocks x 64 threads: block = (b,h,quarter); 16 p-values per block.
// ---------------------------------------------------------------------------
__global__ __launch_bounds__(64)
void state_scan_kernel(unsigned short* __restrict__ SHb, const float* __restrict__ cums,
                       const float* __restrict__ init_states)
{
    __shared__ float decays[NC];
    const int g = blockIdx.x;
    const int bh = g >> 2;
    const int quarter = g & 3;
    const int b = bh / NHEADS;
    const int h = bh % NHEADS;
    const int tid = threadIdx.x;
    decays[tid] = __expf(cums[((size_t)b * LL + tid * QC + QC - 1) * NHEADS + h]);
    __syncthreads();
    const int p = quarter * 16 + (tid >> 2);
    const int nb = (tid & 3) * 8;
    float hs[8];
    {
        const float* is = init_states + ((size_t)h * PDIM + p) * NSTATE + nb;
        #pragma unroll
        for (int i = 0; i < 8; ++i) hs[i] = is[i];
    }
    unsigned short* base = SHb + (((size_t)b * NHEADS + h) * NC) * (PDIM * NSTATE) + p * NSTATE + nb;
    for (int c = 0; c < NC; ++c) {
        unsigned short* slot = base + (size_t)c * (PDIM * NSTATE);
        const uint4 sv = *(const uint4*)slot;
        const unsigned ua[4] = {sv.x, sv.y, sv.z, sv.w};
        unsigned o[4];
        #pragma unroll
        for (int w2 = 0; w2 < 4; ++w2)
            o[w2] = (unsigned)f2bf(hs[2*w2]) | ((unsigned)f2bf(hs[2*w2+1]) << 16);
        *(uint4*)slot = make_uint4(o[0], o[1], o[2], o[3]);
        const float dc = decays[c];
        #pragma unroll
        for (int w2 = 0; w2 < 4; ++w2) {
            hs[2*w2+0] = fmaf(dc, hs[2*w2+0], __uint_as_float(ua[w2] << 16));
            hs[2*w2+1] = fmaf(dc, hs[2*w2+1], __uint_as_float(ua[w2] & 0xffff0000u));
        }
    }
}

// ---------------------------------------------------------------------------
// Intra-chunk + inter-chunk + D term via bf16 MFMA.  grid (NC, NHEADS, BB).
// B/C/H staged with uint4 vector copies from bf16 sources.
// ---------------------------------------------------------------------------
__global__ __launch_bounds__(256)
void intra_kernel(const unsigned short* __restrict__ xcbf, const unsigned short* __restrict__ BCbf,
                  const float* __restrict__ dtv, const float* __restrict__ cums,
                  const unsigned short* __restrict__ SHb, const float* __restrict__ Ds,
                  unsigned short* __restrict__ y0, unsigned short* __restrict__ y1)
{
    __shared__ __align__(16) unsigned short Bs[QC][40];    // [m][n]
    __shared__ __align__(16) unsigned short Cs[QC][40];    // [i][n]
    __shared__ __align__(16) unsigned short Hs[PDIM][40];  // [p][n]
    __shared__ __align__(16) unsigned short Xb[PDIM][72];  // [p][m]  (X^T)
    __shared__ __align__(16) unsigned short Gb[QC][72];    // [i][m]
    __shared__ float cuS[QC], dtS[QC], Ei[QC];
    const int c = blockIdx.x, h = blockIdx.y, b = blockIdx.z;
    const int k = h / NHK;
    const int dch0 = (h - k * NHK) * PDIM;
    const int tid = threadIdx.x;
    const int lane = tid & 63;
    const int w = tid >> 6;

    #pragma unroll
    for (int r = 0; r < 16; ++r) {
        const int idx = tid + r * 256;
        const int m = idx >> 6, p = idx & 63;
        const int pos = (k == 0) ? (c * QC + m) : (m * QC + c);
        Xb[p][m] = xcbf[(((size_t)b << 12) + pos) * INNER + dch0 + p];
    }
    // B/C: vector copy from BCbf (b,l,2,64)
    #pragma unroll
    for (int r = 0; r < 2; ++r) {
        const int idx = tid + r * 256;
        const int i = idx >> 3, ch = idx & 7;
        const uint4 v = *(const uint4*)(BCbf + (((size_t)b * LL + c * QC + i) * 2 + k) * 64 + ch * 8);
        if (ch < 4) *(uint4*)&Bs[i][ch * 8] = v;
        else        *(uint4*)&Cs[i][(ch - 4) * 8] = v;
    }
    // H: vector copy
    {
        const int p = tid >> 2, ch = tid & 3;
        *(uint4*)&Hs[p][ch * 8] =
            *(const uint4*)(SHb + ((((size_t)b * NHEADS + h) * NC + c) * PDIM + p) * NSTATE + ch * 8);
    }
    if (tid < QC) {
        const size_t o = ((size_t)b * LL + c * QC + tid) * NHEADS + h;
        const float cu = cums[o];
        cuS[tid] = cu;
        dtS[tid] = dtv[o];
        Ei[tid]  = __expf(cu);
    }
    __syncthreads();

    const int rowf = lane & 15;
    const int ko   = lane >> 4;
    const short8 cfrag = *(const short8*)&Cs[w * 16 + rowf][ko * 8];

    // matmul1: G_raw tiles (it=w, mt=0..3)
    f32x4 graw[4];
    #pragma unroll
    for (int mt = 0; mt < 4; ++mt) {
        const short8 bfrag = *(const short8*)&Bs[mt * 16 + rowf][ko * 8];
        graw[mt] = __builtin_amdgcn_mfma_f32_16x16x32_bf16(cfrag, bfrag, (f32x4){0.f,0.f,0.f,0.f}, 0, 0, 0);
    }
    #pragma unroll
    for (int mt = 0; mt < 4; ++mt) {
        const int m = mt * 16 + rowf;
        const float cum = cuS[m];
        const float dtm = dtS[m];
        #pragma unroll
        for (int q = 0; q < 4; ++q) {
            const int i = w * 16 + ko * 4 + q;
            float g = 0.f;
            if (m <= i) g = __expf(fminf(cuS[i] - cum, 0.f)) * dtm * graw[mt][q];
            Gb[i][m] = f2bf(g);
        }
    }
    // matmul2: inter tiles (it=w, pt=0..3)
    f32x4 acc[4];
    #pragma unroll
    for (int pt = 0; pt < 4; ++pt) {
        const short8 hfrag = *(const short8*)&Hs[pt * 16 + rowf][ko * 8];
        acc[pt] = __builtin_amdgcn_mfma_f32_16x16x32_bf16(cfrag, hfrag, (f32x4){0.f,0.f,0.f,0.f}, 0, 0, 0);
    }
    const float Dh = Ds[h];
    #pragma unroll
    for (int pt = 0; pt < 4; ++pt) {
        const int p = pt * 16 + rowf;
        #pragma unroll
        for (int q = 0; q < 4; ++q) {
            const int i = w * 16 + ko * 4 + q;
            acc[pt][q] = acc[pt][q] * Ei[i] + Dh * bf2f(Xb[p][i]);
        }
    }
    // matmul3: acc += G·X  (wave w reads only its own Gb rows)
    #pragma unroll
    for (int ks = 0; ks < 2; ++ks) {
        const short8 gfrag = *(const short8*)&Gb[w * 16 + rowf][ks * 32 + ko * 8];
        #pragma unroll
        for (int pt = 0; pt < 4; ++pt) {
            const short8 xfrag = *(const short8*)&Xb[pt * 16 + rowf][ks * 32 + ko * 8];
            acc[pt] = __builtin_amdgcn_mfma_f32_16x16x32_bf16(gfrag, xfrag, acc[pt], 0, 0, 0);
        }
    }
    // epilogue: direct bf16 store (exactly one writer per element per direction)
    unsigned short* yk = (k == 0) ? y0 : y1;
    #pragma unroll
    for (int pt = 0; pt < 4; ++pt) {
        const int p = pt * 16 + rowf;
        #pragma unroll
        for (int q = 0; q < 4; ++q) {
            const int i = w * 16 + ko * 4 + q;
            const int pos = (k == 0) ? (c * QC + i) : (i * QC + c);
            yk[(((size_t)b << 12) + pos) * INNER + dch0 + p] = f2bf(acc[pt][q]);
        }
    }
}

// ---------------------------------------------------------------------------
// gate: yg_bf = bf16( (y0+y1) * silu(z) ), 8 elems/thread.
// ---------------------------------------------------------------------------
__global__ __launch_bounds__(256)
void gate_kernel(const unsigned short* __restrict__ y0, const unsigned short* __restrict__ y1,
                 const unsigned short* __restrict__ xlz, unsigned short* __restrict__ ygbf)
{
    const int t = blockIdx.x * 256 + threadIdx.x;   // < M*48
    const int dv = t % (INNER / 8);
    const int m  = t / (INNER / 8);
    const int d0 = dv * 8;
    const uint4 a = *(const uint4*)(y0 + (size_t)m * INNER + d0);
    const uint4 bv = *(const uint4*)(y1 + (size_t)m * INNER + d0);
    const uint4 zv = *(const uint4*)(xlz + (size_t)m * 768 + INNER + d0);
    const unsigned ua[4] = {a.x, a.y, a.z, a.w};
    const unsigned ub[4] = {bv.x, bv.y, bv.z, bv.w};
    const unsigned uz[4] = {zv.x, zv.y, zv.z, zv.w};
    unsigned o[4];
    #pragma unroll
    for (int w2 = 0; w2 < 4; ++w2) {
        const float ylo = __uint_as_float(ua[w2] << 16) + __uint_as_float(ub[w2] << 16);
        const float yhi = __uint_as_float(ua[w2] & 0xffff0000u) + __uint_as_float(ub[w2] & 0xffff0000u);
        const float zlo = __uint_as_float(uz[w2] << 16);
        const float zhi = __uint_as_float(uz[w2] & 0xffff0000u);
        o[w2] = (unsigned)f2bf(ylo * silu_f(zlo)) | ((unsigned)f2bf(yhi * silu_f(zhi)) << 16);
    }
    *(uint4*)(ygbf + (size_t)m * INNER + d0) = make_uint4(o[0], o[1], o[2], o[3]);
}

__global__ __launch_bounds__(256)
void report_ws_kernel(float* __restrict__ out, int n, float val)
{
    const int e = blockIdx.x * 256 + threadIdx.x;
    if (e < n) out[e] = val;
}

// ---------------------------------------------------------------------------
extern "C" void kernel_launch(void* const* d_in, const int* in_sizes, int n_in,
                              void* d_out, int out_size, void* d_ws, size_t ws_size,
                              hipStream_t stream)
{
    const float* x          = (const float*)d_in[0];
    const float* W_in       = (const float*)d_in[1];
    const float* conv_w     = (const float*)d_in[2];
    const float* conv_b     = (const float*)d_in[3];
    const float* xpw        = (const float*)d_in[4];
    const float* A_logs     = (const float*)d_in[5];
    const float* Ds         = (const float*)d_in[6];
    const float* dt_bias    = (const float*)d_in[7];
    const float* init_states= (const float*)d_in[8];
    const float* W_out      = (const float*)d_in[9];
    const float* W1         = (const float*)d_in[10];
    const float* b1         = (const float*)d_in[11];
    const float* W2         = (const float*)d_in[12];
    const float* b2         = (const float*)d_in[13];
    float* out = (float*)d_out;

    if (ws_size < (size_t)WS_REQ) {
        const float mib = (float)((double)ws_size / 1048576.0);
        report_ws_kernel<<<(out_size + 255) / 256, 256, 0, stream>>>(out, out_size, mib);
        return;
    }

    char* ws = (char*)d_ws;
    unsigned short* xlz   = (unsigned short*)(ws + WS_XLZ);
    unsigned short* xc_bf = (unsigned short*)(ws + WS_XC);
    unsigned short* y1    = (unsigned short*)(ws + WS_Y1);
    unsigned short* BCbf  = (unsigned short*)(ws + WS_BCBF);
    float* dtraw = (float*)(ws + WS_DTRAW);
    float* dtv   = (float*)(ws + WS_DTV);
    float* cums  = (float*)(ws + WS_CUMS);
    unsigned short* SHb   = (unsigned short*)(ws + WS_SHB);
    unsigned short* y0    = (unsigned short*)(ws + WS_Y0);
    unsigned short* x_bf  = (unsigned short*)(ws + WS_XBF);
    unsigned short* Winb  = (unsigned short*)(ws + WS_WINB);
    unsigned short* wpadb = (unsigned short*)(ws + WS_WPADB);
    unsigned short* Woutb = (unsigned short*)(ws + WS_WOUTB);
    unsigned short* W1b   = (unsigned short*)(ws + WS_W1B);
    unsigned short* W2b   = (unsigned short*)(ws + WS_W2B);
    unsigned short* yg_bf  = (unsigned short*)(ws + WS_XC);   // overlay: xc dead after intra
    unsigned short* out_bf = (unsigned short*)(ws + WS_BCBF); // overlay: BCbf dead after intra
    unsigned short* h1_bf  = (unsigned short*)(ws + WS_XLZ);  // overlay: xlz dead after gate

    const int M = BB * LL;  // 32768

    // 0) bf16 conversions (weights + x)
    cvt_kernel<<<(M * CIN + 255) / 256, 256, 0, stream>>>(x, x_bf, M * CIN);
    cvt_kernel<<<(HID * CIN + 255) / 256, 256, 0, stream>>>(W_in, Winb, HID * CIN);
    cvt_kernel<<<(HID * CIN + 255) / 256, 256, 0, stream>>>(W1, W1b, HID * CIN);
    cvt_pad_kernel<<<(128 * INNER + 255) / 256, 256, 0, stream>>>(xpw, wpadb, CPROJ, 128 * INNER, INNER);
    cvt_pad_kernel<<<(128 * INNER + 255) / 256, 256, 0, stream>>>(xpw + CPROJ * INNER, wpadb + 128 * INNER, CPROJ, 128 * INNER, INNER);
    cvt_pad_kernel<<<(256 * INNER + 255) / 256, 256, 0, stream>>>(W_out, Woutb, CIN, 256 * INNER, INNER);
    cvt_pad_kernel<<<(256 * HID + 255) / 256, 256, 0, stream>>>(W2, W2b, CIN, 256 * HID, HID);

    // 1) xlz = bf16( x @ W_in^T )   (single N=768 GEMM: xl | z)
    gemm_bf16<4,0><<<dim3(M/128, HID/128), 256, 0, stream>>>(x_bf, Winb, nullptr, nullptr, nullptr, xlz, CIN, HID, HID);

    // 2) depthwise conv + bias + SiLU -> xc_bf
    conv_dw_kernel<<<(M * INNER / 8) / 256, 256, 0, stream>>>(xlz, conv_w, conv_b, xc_bf);

    // 3) BCdt projection: split outputs (B/C -> bf16 BCbf, dt -> f32 dtraw)
    gemm_bf16<5,0><<<dim3(M/128, 1), 256, 0, stream>>>(xc_bf, wpadb, nullptr, nullptr, dtraw, BCbf, INNER, 0, CPROJ);
    gemm_bf16<5,1><<<dim3(M/128, 1), 256, 0, stream>>>(xc_bf, wpadb + 128 * INNER, nullptr, nullptr, dtraw + 6, BCbf + 64, INNER, 0, CPROJ);

    // 3b) dt softplus + per-chunk cumsum
    dtcums_kernel<<<(BB * NHEADS * NC) / 4, 256, 0, stream>>>(dtraw, dt_bias, A_logs, dtv, cums);

    // 4) chunked scan (no memset, no atomics)
    chunk_state_kernel<<<dim3(NC, NHEADS, BB), 256, 0, stream>>>(xc_bf, BCbf, dtv, cums, SHb);
    state_scan_kernel<<<BB * NHEADS * 4, 64, 0, stream>>>(SHb, cums, init_states);
    intra_kernel<<<dim3(NC, NHEADS, BB), 256, 0, stream>>>(xc_bf, BCbf, dtv, cums, SHb, Ds, y0, y1);

    // 5) gate: yg = (y0+y1) * silu(z)
    gate_kernel<<<(M * INNER / 8) / 256, 256, 0, stream>>>(y0, y1, xlz, yg_bf);

    // 5b) out = x + yg @ W_out^T   (dual write: f32 out + bf16 out_bf)
    gemm_bf16<3,0><<<dim3(M/128, 2), 256, 0, stream>>>(yg_bf, Woutb, nullptr, x, out, out_bf, INNER, CIN, CIN);

    // 6) MLP: h1_bf = bf16(silu(out @ W1^T + b1));  out += h1 @ W2^T + b2
    gemm_bf16<1,0><<<dim3(M/128, HID/128), 256, 0, stream>>>(out_bf, W1b, b1, nullptr, nullptr, h1_bf, CIN, HID, HID);
    gemm_bf16<2,0><<<dim3(M/128, 2), 256, 0, stream>>>(h1_bf, W2b, b2, out, out, nullptr, HID, CIN, CIN);
}

// Round 13
// 241.699 us; speedup vs baseline: 13.3493x; 1.1414x over previous
//
#include <hip/hip_runtime.h>
#include <math.h>

#define BB 8
#define HH 64
#define WW 64
#define CIN 192
#define INNER 384
#define LL 4096          // HH*WW
#define NSTATE 32
#define PDIM 64
#define NHK 6            // INNER/PDIM
#define NHEADS 12        // 2*NHK
#define HID 768
#define CPROJ 70         // 2*NSTATE + NHK
#define QC 64            // chunk length
#define NC 64            // LL/QC chunks

// workspace layout (bytes)
#define WS_XLZ   0u                   // bf16 xlz (B,L,768) 50331648 ; h1_bf overlay after gate
#define WS_XC    50331648u            // bf16 xc (B,L,384) 25165824 ; yg_bf overlay after intra
#define WS_Y1    75497472u            // bf16 y1 (B,L,384) 25165824
#define WS_BCBF  100663296u           // bf16 BCbf (B,L,2,64) 8388608 ; out_bf overlay after intra
#define WS_DTRAW 109051904u           // f32 dtraw (B,L,2,6) 1572864 (dead after dtcums)
#define WS_DTV   119013376u           // (B,L,12) f32 1572864
#define WS_CUMS  120586240u           // (B,L,12) f32 1572864
#define WS_SHB   122159104u           // bf16 SH (B,NH,NC,P,N) 25165824
#define WS_Y0    147324928u           // bf16 y0 (B,L,384) 25165824
#define WS_XBF   172490752u           // (M,192) bf16 12582912 (dead after in_proj)
#define WS_WINB  185073664u           // W_in bf16 768x192      294912
#define WS_WPADB 185368576u           // xpw padded bf16 2x128x384 196608
#define WS_WOUTB 185565184u           // W_out padded bf16 256x384 196608
#define WS_W1B   185761792u           // W1 bf16 768x192        294912
#define WS_W2B   186056704u           // W2 padded bf16 256x768 393216
#define WS_REQ   186449920u

typedef __attribute__((ext_vector_type(8))) short short8;
typedef __attribute__((ext_vector_type(4))) float f32x4;

__device__ __forceinline__ float silu_f(float x) { return x / (1.f + __expf(-x)); }

__device__ __forceinline__ unsigned short f2bf(float f) {
    unsigned u = __float_as_uint(f);
    u += 0x7fffu + ((u >> 16) & 1u);
    return (unsigned short)(u >> 16);
}
__device__ __forceinline__ float bf2f(unsigned short u) {
    return __uint_as_float(((unsigned)u) << 16);
}

// ---------------------------------------------------------------------------
// bf16 MFMA GEMM: C[m,n] = sum_k A[m,k]*Wt[n,k].  A,Wt bf16; acc f32.
// 128x128 tile, BK=64, 4 waves x (64x64), mfma_f32_16x16x32_bf16.
// EPI: 0 Cf=acc; 1 Cb=bf16(silu(acc+bias)); 2 Cf=acc+bias+res; 3 Cf=acc+res & Cb;
//      4 Cb=bf16(acc); 5 split: n<64 -> Cb bf16 (stride 128), 64<=n<nmax -> Cf f32 (stride 12).
// ---------------------------------------------------------------------------
template<int EPI, int TRANSA>
__global__ __launch_bounds__(256)
void gemm_bf16(const unsigned short* __restrict__ A, const unsigned short* __restrict__ Wt,
               const float* __restrict__ bias, const float* __restrict__ res,
               float* __restrict__ Cf, unsigned short* __restrict__ Cb,
               int Kd, int ldc, int nmax)
{
    __shared__ __align__(16) short Als[128 * 64];
    __shared__ __align__(16) short Bls[128 * 64];
    const int tid = threadIdx.x;
    const int m0 = blockIdx.x * 128;
    const int n0 = blockIdx.y * 128;
    const int lane = tid & 63;
    const int wv = tid >> 6;
    const int wm = (wv >> 1) << 6;
    const int wn = (wv & 1) << 6;

    const unsigned short* gA[4];
    const unsigned short* gB[4];
    int lw[4];
    #pragma unroll
    for (int c = 0; c < 4; ++c) {
        const int idx = c * 256 + tid;
        const int row = idx >> 3;
        const int kb  = idx & 7;
        const int sb  = kb ^ (row & 7);
        lw[c] = row * 64 + sb * 8;
        size_t arow;
        const int mm = m0 + row;
        if (TRANSA) {
            const int bq = mm >> 12, lq = mm & 4095;
            arow = ((size_t)bq << 12) + (size_t)(((lq & 63) << 6) + (lq >> 6));
        } else {
            arow = (size_t)mm;
        }
        gA[c] = A + arow * Kd + kb * 8;
        gB[c] = Wt + (size_t)(n0 + row) * Kd + kb * 8;
    }

    f32x4 acc[4][4];
    #pragma unroll
    for (int i = 0; i < 4; ++i)
        #pragma unroll
        for (int j = 0; j < 4; ++j) acc[i][j] = (f32x4){0.f, 0.f, 0.f, 0.f};

    const int NT = Kd >> 6;
    short8 pA[4], pB[4];
    #pragma unroll
    for (int c = 0; c < 4; ++c) {
        pA[c] = *(const short8*)(gA[c]);
        pB[c] = *(const short8*)(gB[c]);
    }
    for (int kt = 0; kt < NT; ++kt) {
        __syncthreads();
        #pragma unroll
        for (int c = 0; c < 4; ++c) {
            *(short8*)&Als[lw[c]] = pA[c];
            *(short8*)&Bls[lw[c]] = pB[c];
        }
        __syncthreads();
        if (kt + 1 < NT) {
            #pragma unroll
            for (int c = 0; c < 4; ++c) {
                pA[c] = *(const short8*)(gA[c] + (kt + 1) * 64);
                pB[c] = *(const short8*)(gB[c] + (kt + 1) * 64);
            }
        }
        #pragma unroll
        for (int ks = 0; ks < 2; ++ks) {
            short8 af[4], bfr[4];
            #pragma unroll
            for (int r = 0; r < 4; ++r) {
                const int rowa = wm + r * 16 + (lane & 15);
                const int rowb = wn + r * 16 + (lane & 15);
                const int kb = ks * 4 + (lane >> 4);
                af[r]  = *(const short8*)&Als[rowa * 64 + ((kb ^ (rowa & 7)) << 3)];
                bfr[r] = *(const short8*)&Bls[rowb * 64 + ((kb ^ (rowb & 7)) << 3)];
            }
            #pragma unroll
            for (int mr = 0; mr < 4; ++mr)
                #pragma unroll
                for (int nr = 0; nr < 4; ++nr)
                    acc[mr][nr] = __builtin_amdgcn_mfma_f32_16x16x32_bf16(af[mr], bfr[nr], acc[mr][nr], 0, 0, 0);
        }
    }
    #pragma unroll
    for (int mr = 0; mr < 4; ++mr) {
        #pragma unroll
        for (int nr = 0; nr < 4; ++nr) {
            const int n = n0 + wn + nr * 16 + (lane & 15);
            if (n >= nmax) continue;
            const int mb = m0 + wm + mr * 16 + ((lane >> 4) << 2);
            #pragma unroll
            for (int q = 0; q < 4; ++q) {
                const size_t off = (size_t)(mb + q) * ldc + n;
                float v = acc[mr][nr][q];
                if (EPI == 0) { Cf[off] = v; }
                else if (EPI == 1) { v = silu_f(v + bias[n]); Cb[off] = f2bf(v); }
                else if (EPI == 2) { v += bias[n] + res[off]; Cf[off] = v; }
                else if (EPI == 3) { v += res[off]; Cf[off] = v; Cb[off] = f2bf(v); }
                else if (EPI == 4) { Cb[off] = f2bf(v); }
                else if (EPI == 5) {
                    if (n < 64) Cb[(size_t)(mb + q) * 128 + n] = f2bf(v);
                    else        Cf[(size_t)(mb + q) * 12 + (n - 64)] = v;
                }
            }
        }
    }
}

// ---------------------------------------------------------------------------
// x -> bf16 (flat)
// ---------------------------------------------------------------------------
__global__ __launch_bounds__(256)
void cvt_kernel(const float* __restrict__ src, unsigned short* __restrict__ dst, int n)
{
    const int i = blockIdx.x * 256 + threadIdx.x;
    if (i < n) dst[i] = f2bf(src[i]);
}

// ---------------------------------------------------------------------------
// All weight conversions in one launch.  Segments (element offsets):
// [0,147456)      W_in  -> Winb
// [.., +147456)   W1    -> W1b
// [.., +98304)    xpw   -> wpadb  (2 x 128 rows, src 70 rows each)
// [.., +98304)    W_out -> Woutb  (256 rows, src 192)
// [.., +196608)   W2    -> W2b    (256 rows, src 192)
// ---------------------------------------------------------------------------
__global__ __launch_bounds__(256)
void cvt_weights_kernel(const float* __restrict__ W_in, const float* __restrict__ W1,
                        const float* __restrict__ xpw, const float* __restrict__ W_out,
                        const float* __restrict__ W2,
                        unsigned short* __restrict__ Winb, unsigned short* __restrict__ W1b,
                        unsigned short* __restrict__ wpadb, unsigned short* __restrict__ Woutb,
                        unsigned short* __restrict__ W2b)
{
    int i = blockIdx.x * 256 + threadIdx.x;
    if (i < 147456) { Winb[i] = f2bf(W_in[i]); return; }
    i -= 147456;
    if (i < 147456) { W1b[i] = f2bf(W1[i]); return; }
    i -= 147456;
    if (i < 98304) {
        const int d = i % 384;
        const int rr = (i / 384) & 127;
        const int k = i / 49152;
        wpadb[i] = (rr < CPROJ) ? f2bf(xpw[((size_t)k * CPROJ + rr) * 384 + d]) : (unsigned short)0;
        return;
    }
    i -= 98304;
    if (i < 98304) {
        const int rr = i / 384;
        Woutb[i] = (rr < CIN) ? f2bf(W_out[i]) : (unsigned short)0;
        return;
    }
    i -= 98304;
    if (i < 196608) {
        const int rr = i / 768;
        W2b[i] = (rr < CIN) ? f2bf(W2[i]) : (unsigned short)0;
    }
}

// ---------------------------------------------------------------------------
// Depthwise 3x3 conv + bias + SiLU, rolling-row: each thread = (b, 8-row strip,
// j, 8 channels).  3-row register window; rows load once, feed 3 output rows.
// ---------------------------------------------------------------------------
__global__ __launch_bounds__(256)
void conv_dw_kernel(const unsigned short* __restrict__ xlz, const float* __restrict__ cw,
                    const float* __restrict__ cb, unsigned short* __restrict__ xcbf)
{
    const int t = blockIdx.x * 256 + threadIdx.x;   // < 196608
    const int dv = t % 48;
    int r = t / 48;
    const int j  = r & 63;  r >>= 6;
    const int ib = r & 7;   r >>= 3;
    const int b  = r;
    const int d0 = dv * 8;
    const int i0 = ib * 8;

    float wreg[72];
    {
        const float4* w4 = (const float4*)(cw + d0 * 9);
        #pragma unroll
        for (int u = 0; u < 18; ++u) {
            const float4 v = w4[u];
            wreg[4*u+0]=v.x; wreg[4*u+1]=v.y; wreg[4*u+2]=v.z; wreg[4*u+3]=v.w;
        }
    }
    float bias[8];
    {
        const float4 b0 = *(const float4*)(cb + d0);
        const float4 b1 = *(const float4*)(cb + d0 + 4);
        bias[0]=b0.x; bias[1]=b0.y; bias[2]=b0.z; bias[3]=b0.w;
        bias[4]=b1.x; bias[5]=b1.y; bias[6]=b1.z; bias[7]=b1.w;
    }

    const unsigned short* base = xlz + ((size_t)b << 12) * 768 + d0;
    const int jok[3] = { (j - 1 >= 0), 1, (j + 1 < WW) };

    unsigned rm[3][4], r0[3][4], rp[3][4];
    #pragma unroll
    for (int cj = 0; cj < 3; ++cj) {
        uint4 vm = make_uint4(0,0,0,0), v0 = make_uint4(0,0,0,0);
        if (jok[cj]) {
            if (i0 - 1 >= 0) vm = *(const uint4*)(base + (size_t)((i0-1) * 64 + j - 1 + cj) * 768);
            v0 = *(const uint4*)(base + (size_t)(i0 * 64 + j - 1 + cj) * 768);
        }
        rm[cj][0]=vm.x; rm[cj][1]=vm.y; rm[cj][2]=vm.z; rm[cj][3]=vm.w;
        r0[cj][0]=v0.x; r0[cj][1]=v0.y; r0[cj][2]=v0.z; r0[cj][3]=v0.w;
    }

    #pragma unroll
    for (int ii = 0; ii < 8; ++ii) {
        const int i = i0 + ii;
        #pragma unroll
        for (int cj = 0; cj < 3; ++cj) {
            uint4 vp = make_uint4(0,0,0,0);
            if (jok[cj] && (i + 1 < HH))
                vp = *(const uint4*)(base + (size_t)((i+1) * 64 + j - 1 + cj) * 768);
            rp[cj][0]=vp.x; rp[cj][1]=vp.y; rp[cj][2]=vp.z; rp[cj][3]=vp.w;
        }
        float acc[8];
        #pragma unroll
        for (int ch = 0; ch < 8; ++ch) acc[ch] = bias[ch];
        #pragma unroll
        for (int cj = 0; cj < 3; ++cj) {
            #pragma unroll
            for (int w2 = 0; w2 < 4; ++w2) {
                // row i-1 : taps 0..2
                acc[2*w2+0] = fmaf(__uint_as_float(rm[cj][w2] << 16),        wreg[(2*w2+0)*9 + cj],     acc[2*w2+0]);
                acc[2*w2+1] = fmaf(__uint_as_float(rm[cj][w2] & 0xffff0000u), wreg[(2*w2+1)*9 + cj],     acc[2*w2+1]);
                // row i   : taps 3..5
                acc[2*w2+0] = fmaf(__uint_as_float(r0[cj][w2] << 16),        wreg[(2*w2+0)*9 + 3 + cj], acc[2*w2+0]);
                acc[2*w2+1] = fmaf(__uint_as_float(r0[cj][w2] & 0xffff0000u), wreg[(2*w2+1)*9 + 3 + cj], acc[2*w2+1]);
                // row i+1 : taps 6..8
                acc[2*w2+0] = fmaf(__uint_as_float(rp[cj][w2] << 16),        wreg[(2*w2+0)*9 + 6 + cj], acc[2*w2+0]);
                acc[2*w2+1] = fmaf(__uint_as_float(rp[cj][w2] & 0xffff0000u), wreg[(2*w2+1)*9 + 6 + cj], acc[2*w2+1]);
            }
        }
        unsigned o[4];
        #pragma unroll
        for (int w2 = 0; w2 < 4; ++w2) {
            const unsigned lo = f2bf(silu_f(acc[2*w2+0]));
            const unsigned hi = f2bf(silu_f(acc[2*w2+1]));
            o[w2] = lo | (hi << 16);
        }
        *(uint4*)(xcbf + ((size_t)(b << 12) + (size_t)(i * 64 + j)) * INNER + d0) =
            make_uint4(o[0], o[1], o[2], o[3]);
        // shift window
        #pragma unroll
        for (int cj = 0; cj < 3; ++cj)
            #pragma unroll
            for (int w2 = 0; w2 < 4; ++w2) {
                rm[cj][w2] = r0[cj][w2];
                r0[cj][w2] = rp[cj][w2];
            }
    }
}

// ---------------------------------------------------------------------------
// dtv = softplus(dtraw + dt_bias[h]); cums = per-chunk inclusive prefix sum
// ---------------------------------------------------------------------------
__global__ __launch_bounds__(256)
void dtcums_kernel(const float* __restrict__ dtraw, const float* __restrict__ dt_bias,
                   const float* __restrict__ A_logs,
                   float* __restrict__ dtv, float* __restrict__ cums)
{
    const int w = blockIdx.x * 4 + (threadIdx.x >> 6);
    const int lane = threadIdx.x & 63;
    const int b = w / (NHEADS * NC);
    const int rem = w - b * (NHEADS * NC);
    const int h = rem / NC;
    const int c = rem - h * NC;
    const int k = h / NHK;
    const int hq = h - k * NHK;
    const int l = c * QC + lane;
    const float dtr = dtraw[(((size_t)b * LL + l) * 2 + k) * 6 + hq];
    const float xx = dtr + dt_bias[h];
    const float sp = (xx > 20.f) ? xx : log1pf(expf(xx));
    float s = -expf(A_logs[h]) * sp;
    #pragma unroll
    for (int d = 1; d < 64; d <<= 1) {
        const float o = __shfl_up(s, d);
        if (lane >= d) s += o;
    }
    dtv[((size_t)b * LL + l) * NHEADS + h] = sp;
    cums[((size_t)b * LL + l) * NHEADS + h] = s;
}

// ---------------------------------------------------------------------------
// Chunk states via bf16 MFMA: S_c[p,n] = sum_m (rs[m]*x[m][p]) * B[m][n]
// ---------------------------------------------------------------------------
__global__ __launch_bounds__(256)
void chunk_state_kernel(const unsigned short* __restrict__ xcbf, const unsigned short* __restrict__ BCbf,
                        const float* __restrict__ dtv, const float* __restrict__ cums,
                        unsigned short* __restrict__ SHb)
{
    __shared__ __align__(16) unsigned short Xb[PDIM][72];    // [p][m]  (X^T)
    __shared__ __align__(16) unsigned short Bsc[NSTATE][72]; // [n][m]  (rs[m]*B^T)
    __shared__ float cuS[QC], rs[QC];
    const int c = blockIdx.x, h = blockIdx.y, b = blockIdx.z;
    const int k = h / NHK;
    const int dch0 = (h - k * NHK) * PDIM;
    const int tid = threadIdx.x;
    const int lane = tid & 63;
    const int w = tid >> 6;

    #pragma unroll
    for (int r = 0; r < 16; ++r) {
        const int idx = tid + r * 256;
        const int m = idx >> 6, p = idx & 63;
        const int pos = (k == 0) ? (c * QC + m) : (m * QC + c);
        Xb[p][m] = xcbf[(((size_t)b << 12) + pos) * INNER + dch0 + p];
    }
    if (tid < QC)
        cuS[tid] = cums[((size_t)b * LL + c * QC + tid) * NHEADS + h];
    __syncthreads();
    if (tid < QC)
        rs[tid] = dtv[((size_t)b * LL + c * QC + tid) * NHEADS + h] * __expf(cuS[QC-1] - cuS[tid]);
    __syncthreads();
    #pragma unroll
    for (int r = 0; r < 8; ++r) {
        const int idx = tid + r * 256;
        const int m = idx >> 5, n = idx & 31;
        Bsc[n][m] = f2bf(rs[m] * bf2f(BCbf[(((size_t)b * LL + c * QC + m) * 2 + k) * 64 + n]));
    }
    __syncthreads();

    const int rowf = lane & 15;
    const int ko   = lane >> 4;
    f32x4 acc[2] = {{0.f,0.f,0.f,0.f},{0.f,0.f,0.f,0.f}};
    #pragma unroll
    for (int ks = 0; ks < 2; ++ks) {
        const short8 af = *(const short8*)&Xb[w * 16 + rowf][ks * 32 + ko * 8];
        #pragma unroll
        for (int nt = 0; nt < 2; ++nt) {
            const short8 bfr = *(const short8*)&Bsc[nt * 16 + rowf][ks * 32 + ko * 8];
            acc[nt] = __builtin_amdgcn_mfma_f32_16x16x32_bf16(af, bfr, acc[nt], 0, 0, 0);
        }
    }
    unsigned short* base = SHb + ((((size_t)b * NHEADS + h) * NC + c) * PDIM) * NSTATE;
    #pragma unroll
    for (int nt = 0; nt < 2; ++nt) {
        #pragma unroll
        for (int q = 0; q < 4; ++q) {
            const int p = w * 16 + ko * 4 + q;
            base[p * NSTATE + nt * 16 + rowf] = f2bf(acc[nt][q]);
        }
    }
}

// ---------------------------------------------------------------------------
// Sequential scan over chunks (in place, bf16 slots, f32 running state).
// 384 blocks x 64 threads: block = (b,h,quarter); 16 p-values per block.
// ---------------------------------------------------------------------------
__global__ __launch_bounds__(64)
void state_scan_kernel(unsigned short* __restrict__ SHb, const float* __restrict__ cums,
                       const float* __restrict__ init_states)
{
    __shared__ float decays[NC];
    const int g = blockIdx.x;
    const int bh = g >> 2;
    const int quarter = g & 3;
    const int b = bh / NHEADS;
    const int h = bh % NHEADS;
    const int tid = threadIdx.x;
    decays[tid] = __expf(cums[((size_t)b * LL + tid * QC + QC - 1) * NHEADS + h]);
    __syncthreads();
    const int p = quarter * 16 + (tid >> 2);
    const int nb = (tid & 3) * 8;
    float hs[8];
    {
        const float* is = init_states + ((size_t)h * PDIM + p) * NSTATE + nb;
        #pragma unroll
        for (int i = 0; i < 8; ++i) hs[i] = is[i];
    }
    unsigned short* base = SHb + (((size_t)b * NHEADS + h) * NC) * (PDIM * NSTATE) + p * NSTATE + nb;
    for (int c = 0; c < NC; ++c) {
        unsigned short* slot = base + (size_t)c * (PDIM * NSTATE);
        const uint4 sv = *(const uint4*)slot;
        const unsigned ua[4] = {sv.x, sv.y, sv.z, sv.w};
        unsigned o[4];
        #pragma unroll
        for (int w2 = 0; w2 < 4; ++w2)
            o[w2] = (unsigned)f2bf(hs[2*w2]) | ((unsigned)f2bf(hs[2*w2+1]) << 16);
        *(uint4*)slot = make_uint4(o[0], o[1], o[2], o[3]);
        const float dc = decays[c];
        #pragma unroll
        for (int w2 = 0; w2 < 4; ++w2) {
            hs[2*w2+0] = fmaf(dc, hs[2*w2+0], __uint_as_float(ua[w2] << 16));
            hs[2*w2+1] = fmaf(dc, hs[2*w2+1], __uint_as_float(ua[w2] & 0xffff0000u));
        }
    }
}

// ---------------------------------------------------------------------------
// Intra-chunk + inter-chunk + D term via bf16 MFMA.  grid (NC, NHEADS, BB).
// ---------------------------------------------------------------------------
__global__ __launch_bounds__(256)
void intra_kernel(const unsigned short* __restrict__ xcbf, const unsigned short* __restrict__ BCbf,
                  const float* __restrict__ dtv, const float* __restrict__ cums,
                  const unsigned short* __restrict__ SHb, const float* __restrict__ Ds,
                  unsigned short* __restrict__ y0, unsigned short* __restrict__ y1)
{
    __shared__ __align__(16) unsigned short Bs[QC][40];    // [m][n]
    __shared__ __align__(16) unsigned short Cs[QC][40];    // [i][n]
    __shared__ __align__(16) unsigned short Hs[PDIM][40];  // [p][n]
    __shared__ __align__(16) unsigned short Xb[PDIM][72];  // [p][m]  (X^T)
    __shared__ __align__(16) unsigned short Gb[QC][72];    // [i][m]
    __shared__ float cuS[QC], dtS[QC], Ei[QC];
    const int c = blockIdx.x, h = blockIdx.y, b = blockIdx.z;
    const int k = h / NHK;
    const int dch0 = (h - k * NHK) * PDIM;
    const int tid = threadIdx.x;
    const int lane = tid & 63;
    const int w = tid >> 6;

    #pragma unroll
    for (int r = 0; r < 16; ++r) {
        const int idx = tid + r * 256;
        const int m = idx >> 6, p = idx & 63;
        const int pos = (k == 0) ? (c * QC + m) : (m * QC + c);
        Xb[p][m] = xcbf[(((size_t)b << 12) + pos) * INNER + dch0 + p];
    }
    // B/C: vector copy from BCbf (b,l,2,64)
    #pragma unroll
    for (int r = 0; r < 2; ++r) {
        const int idx = tid + r * 256;
        const int i = idx >> 3, ch = idx & 7;
        const uint4 v = *(const uint4*)(BCbf + (((size_t)b * LL + c * QC + i) * 2 + k) * 64 + ch * 8);
        if (ch < 4) *(uint4*)&Bs[i][ch * 8] = v;
        else        *(uint4*)&Cs[i][(ch - 4) * 8] = v;
    }
    // H: vector copy
    {
        const int p = tid >> 2, ch = tid & 3;
        *(uint4*)&Hs[p][ch * 8] =
            *(const uint4*)(SHb + ((((size_t)b * NHEADS + h) * NC + c) * PDIM + p) * NSTATE + ch * 8);
    }
    if (tid < QC) {
        const size_t o = ((size_t)b * LL + c * QC + tid) * NHEADS + h;
        const float cu = cums[o];
        cuS[tid] = cu;
        dtS[tid] = dtv[o];
        Ei[tid]  = __expf(cu);
    }
    __syncthreads();

    const int rowf = lane & 15;
    const int ko   = lane >> 4;
    const short8 cfrag = *(const short8*)&Cs[w * 16 + rowf][ko * 8];

    // matmul1: G_raw tiles (it=w, mt=0..3)
    f32x4 graw[4];
    #pragma unroll
    for (int mt = 0; mt < 4; ++mt) {
        const short8 bfrag = *(const short8*)&Bs[mt * 16 + rowf][ko * 8];
        graw[mt] = __builtin_amdgcn_mfma_f32_16x16x32_bf16(cfrag, bfrag, (f32x4){0.f,0.f,0.f,0.f}, 0, 0, 0);
    }
    #pragma unroll
    for (int mt = 0; mt < 4; ++mt) {
        const int m = mt * 16 + rowf;
        const float cum = cuS[m];
        const float dtm = dtS[m];
        #pragma unroll
        for (int q = 0; q < 4; ++q) {
            const int i = w * 16 + ko * 4 + q;
            float g = 0.f;
            if (m <= i) g = __expf(fminf(cuS[i] - cum, 0.f)) * dtm * graw[mt][q];
            Gb[i][m] = f2bf(g);
        }
    }
    // matmul2: inter tiles (it=w, pt=0..3)
    f32x4 acc[4];
    #pragma unroll
    for (int pt = 0; pt < 4; ++pt) {
        const short8 hfrag = *(const short8*)&Hs[pt * 16 + rowf][ko * 8];
        acc[pt] = __builtin_amdgcn_mfma_f32_16x16x32_bf16(cfrag, hfrag, (f32x4){0.f,0.f,0.f,0.f}, 0, 0, 0);
    }
    const float Dh = Ds[h];
    #pragma unroll
    for (int pt = 0; pt < 4; ++pt) {
        const int p = pt * 16 + rowf;
        #pragma unroll
        for (int q = 0; q < 4; ++q) {
            const int i = w * 16 + ko * 4 + q;
            acc[pt][q] = acc[pt][q] * Ei[i] + Dh * bf2f(Xb[p][i]);
        }
    }
    // matmul3: acc += G·X  (wave w reads only its own Gb rows)
    #pragma unroll
    for (int ks = 0; ks < 2; ++ks) {
        const short8 gfrag = *(const short8*)&Gb[w * 16 + rowf][ks * 32 + ko * 8];
        #pragma unroll
        for (int pt = 0; pt < 4; ++pt) {
            const short8 xfrag = *(const short8*)&Xb[pt * 16 + rowf][ks * 32 + ko * 8];
            acc[pt] = __builtin_amdgcn_mfma_f32_16x16x32_bf16(gfrag, xfrag, acc[pt], 0, 0, 0);
        }
    }
    // epilogue: direct bf16 store (exactly one writer per element per direction)
    unsigned short* yk = (k == 0) ? y0 : y1;
    #pragma unroll
    for (int pt = 0; pt < 4; ++pt) {
        const int p = pt * 16 + rowf;
        #pragma unroll
        for (int q = 0; q < 4; ++q) {
            const int i = w * 16 + ko * 4 + q;
            const int pos = (k == 0) ? (c * QC + i) : (i * QC + c);
            yk[(((size_t)b << 12) + pos) * INNER + dch0 + p] = f2bf(acc[pt][q]);
        }
    }
}

// ---------------------------------------------------------------------------
// gate: yg_bf = bf16( (y0+y1) * silu(z) ), 8 elems/thread.
// ---------------------------------------------------------------------------
__global__ __launch_bounds__(256)
void gate_kernel(const unsigned short* __restrict__ y0, const unsigned short* __restrict__ y1,
                 const unsigned short* __restrict__ xlz, unsigned short* __restrict__ ygbf)
{
    const int t = blockIdx.x * 256 + threadIdx.x;   // < M*48
    const int dv = t % (INNER / 8);
    const int m  = t / (INNER / 8);
    const int d0 = dv * 8;
    const uint4 a = *(const uint4*)(y0 + (size_t)m * INNER + d0);
    const uint4 bv = *(const uint4*)(y1 + (size_t)m * INNER + d0);
    const uint4 zv = *(const uint4*)(xlz + (size_t)m * 768 + INNER + d0);
    const unsigned ua[4] = {a.x, a.y, a.z, a.w};
    const unsigned ub[4] = {bv.x, bv.y, bv.z, bv.w};
    const unsigned uz[4] = {zv.x, zv.y, zv.z, zv.w};
    unsigned o[4];
    #pragma unroll
    for (int w2 = 0; w2 < 4; ++w2) {
        const float ylo = __uint_as_float(ua[w2] << 16) + __uint_as_float(ub[w2] << 16);
        const float yhi = __uint_as_float(ua[w2] & 0xffff0000u) + __uint_as_float(ub[w2] & 0xffff0000u);
        const float zlo = __uint_as_float(uz[w2] << 16);
        const float zhi = __uint_as_float(uz[w2] & 0xffff0000u);
        o[w2] = (unsigned)f2bf(ylo * silu_f(zlo)) | ((unsigned)f2bf(yhi * silu_f(zhi)) << 16);
    }
    *(uint4*)(ygbf + (size_t)m * INNER + d0) = make_uint4(o[0], o[1], o[2], o[3]);
}

__global__ __launch_bounds__(256)
void report_ws_kernel(float* __restrict__ out, int n, float val)
{
    const int e = blockIdx.x * 256 + threadIdx.x;
    if (e < n) out[e] = val;
}

// ---------------------------------------------------------------------------
extern "C" void kernel_launch(void* const* d_in, const int* in_sizes, int n_in,
                              void* d_out, int out_size, void* d_ws, size_t ws_size,
                              hipStream_t stream)
{
    const float* x          = (const float*)d_in[0];
    const float* W_in       = (const float*)d_in[1];
    const float* conv_w     = (const float*)d_in[2];
    const float* conv_b     = (const float*)d_in[3];
    const float* xpw        = (const float*)d_in[4];
    const float* A_logs     = (const float*)d_in[5];
    const float* Ds         = (const float*)d_in[6];
    const float* dt_bias    = (const float*)d_in[7];
    const float* init_states= (const float*)d_in[8];
    const float* W_out      = (const float*)d_in[9];
    const float* W1         = (const float*)d_in[10];
    const float* b1         = (const float*)d_in[11];
    const float* W2         = (const float*)d_in[12];
    const float* b2         = (const float*)d_in[13];
    float* out = (float*)d_out;

    if (ws_size < (size_t)WS_REQ) {
        const float mib = (float)((double)ws_size / 1048576.0);
        report_ws_kernel<<<(out_size + 255) / 256, 256, 0, stream>>>(out, out_size, mib);
        return;
    }

    char* ws = (char*)d_ws;
    unsigned short* xlz   = (unsigned short*)(ws + WS_XLZ);
    unsigned short* xc_bf = (unsigned short*)(ws + WS_XC);
    unsigned short* y1    = (unsigned short*)(ws + WS_Y1);
    unsigned short* BCbf  = (unsigned short*)(ws + WS_BCBF);
    float* dtraw = (float*)(ws + WS_DTRAW);
    float* dtv   = (float*)(ws + WS_DTV);
    float* cums  = (float*)(ws + WS_CUMS);
    unsigned short* SHb   = (unsigned short*)(ws + WS_SHB);
    unsigned short* y0    = (unsigned short*)(ws + WS_Y0);
    unsigned short* x_bf  = (unsigned short*)(ws + WS_XBF);
    unsigned short* Winb  = (unsigned short*)(ws + WS_WINB);
    unsigned short* wpadb = (unsigned short*)(ws + WS_WPADB);
    unsigned short* Woutb = (unsigned short*)(ws + WS_WOUTB);
    unsigned short* W1b   = (unsigned short*)(ws + WS_W1B);
    unsigned short* W2b   = (unsigned short*)(ws + WS_W2B);
    unsigned short* yg_bf  = (unsigned short*)(ws + WS_XC);   // overlay: xc dead after intra
    unsigned short* out_bf = (unsigned short*)(ws + WS_BCBF); // overlay: BCbf dead after intra
    unsigned short* h1_bf  = (unsigned short*)(ws + WS_XLZ);  // overlay: xlz dead after gate

    const int M = BB * LL;  // 32768

    // 0) bf16 conversions: x (big) + all weights (one launch)
    cvt_kernel<<<(M * CIN + 255) / 256, 256, 0, stream>>>(x, x_bf, M * CIN);
    cvt_weights_kernel<<<(688128 + 255) / 256, 256, 0, stream>>>(W_in, W1, xpw, W_out, W2,
                                                                 Winb, W1b, wpadb, Woutb, W2b);

    // 1) xlz = bf16( x @ W_in^T )   (single N=768 GEMM: xl | z)
    gemm_bf16<4,0><<<dim3(M/128, HID/128), 256, 0, stream>>>(x_bf, Winb, nullptr, nullptr, nullptr, xlz, CIN, HID, HID);

    // 2) depthwise conv + bias + SiLU -> xc_bf  (rolling 8-row threads)
    conv_dw_kernel<<<196608 / 256, 256, 0, stream>>>(xlz, conv_w, conv_b, xc_bf);

    // 3) BCdt projection: split outputs (B/C -> bf16 BCbf, dt -> f32 dtraw)
    gemm_bf16<5,0><<<dim3(M/128, 1), 256, 0, stream>>>(xc_bf, wpadb, nullptr, nullptr, dtraw, BCbf, INNER, 0, CPROJ);
    gemm_bf16<5,1><<<dim3(M/128, 1), 256, 0, stream>>>(xc_bf, wpadb + 128 * INNER, nullptr, nullptr, dtraw + 6, BCbf + 64, INNER, 0, CPROJ);

    // 3b) dt softplus + per-chunk cumsum
    dtcums_kernel<<<(BB * NHEADS * NC) / 4, 256, 0, stream>>>(dtraw, dt_bias, A_logs, dtv, cums);

    // 4) chunked scan (no memset, no atomics)
    chunk_state_kernel<<<dim3(NC, NHEADS, BB), 256, 0, stream>>>(xc_bf, BCbf, dtv, cums, SHb);
    state_scan_kernel<<<BB * NHEADS * 4, 64, 0, stream>>>(SHb, cums, init_states);
    intra_kernel<<<dim3(NC, NHEADS, BB), 256, 0, stream>>>(xc_bf, BCbf, dtv, cums, SHb, Ds, y0, y1);

    // 5) gate: yg = (y0+y1) * silu(z)
    gate_kernel<<<(M * INNER / 8) / 256, 256, 0, stream>>>(y0, y1, xlz, yg_bf);

    // 5b) out = x + yg @ W_out^T   (dual write: f32 out + bf16 out_bf)
    gemm_bf16<3,0><<<dim3(M/128, 2), 256, 0, stream>>>(yg_bf, Woutb, nullptr, x, out, out_bf, INNER, CIN, CIN);

    // 6) MLP: h1_bf = bf16(silu(out @ W1^T + b1));  out += h1 @ W2^T + b2
    gemm_bf16<1,0><<<dim3(M/128, HID/128), 256, 0, stream>>>(out_bf, W1b, b1, nullptr, nullptr, h1_bf, CIN, HID, HID);
    gemm_bf16<2,0><<<dim3(M/128, 2), 256, 0, stream>>>(h1_bf, W2b, b2, out, out, nullptr, HID, CIN, CIN);
}